// Round 2
// baseline (4986.167 us; speedup 1.0000x reference)
//
#include <hip/hip_runtime.h>

#define T_TOK 4096
#define KTOP  2
#define HS    512
#define FFN   2048
#define NE    8
#define NA    (T_TOK*KTOP)   // 8192 assignments

#define BM 32                // assignment rows per block
#define BJ 128               // ffn panel width
#define CK 256               // k-chunk of X staged in LDS
#define XSTR (CK+4)          // 260: bank = (4r+i)%32 -> conflict-free
#define HSTR (BJ+4)          // 132: bank = (4r+j)%32 -> conflict-free

__device__ __forceinline__ float gelu_exact(float v) {
    // jax.nn.gelu(approximate=False): 0.5*x*(1+erf(x/sqrt(2)))
    return 0.5f * v * (1.0f + erff(v * 0.70710678118654752f));
}

__global__ void moe_init(int* cnt) {
    int i = threadIdx.x;
    if (i < NE) cnt[i] = 0;
}

__global__ void moe_scatter(const int* __restrict__ eidx, int* cnt, int* bucket) {
    int a = blockIdx.x * 256 + threadIdx.x;
    if (a < NA) {
        int e = eidx[a];
        int p = atomicAdd(&cnt[e], 1);
        bucket[e * NA + p] = a;   // order nondeterministic; per-assignment result isn't
    }
}

__global__ __launch_bounds__(256, 1) void moe_fused(
    const float* __restrict__ x,      // [T, HS]
    const float* __restrict__ w1,     // [NE, HS, FFN]
    const float* __restrict__ w2,     // [NE, FFN, HS]
    const int*   __restrict__ cnt,    // [NE]
    const int*   __restrict__ bucket, // [NE][NA]
    float*       __restrict__ ybuf)   // [NA, HS]
{
    const int bid = blockIdx.x;
    const int e   = bid & (NE - 1);   // expert -> XCD (bid%8) for L2 locality
    const int tr  = bid >> 3;
    const int n_e = cnt[e];
    const int rbase = tr * BM;
    if (rbase >= n_e) return;

    const int t = threadIdx.x;

    __shared__ __align__(16) float Xc[BM][XSTR];
    __shared__ __align__(16) float Hsh[BM][HSTR];
    __shared__ int rowa[BM];

    if (t < BM) {
        int r = rbase + t;
        rowa[t] = (r < n_e) ? bucket[e * NA + r] : -1;
    }
    __syncthreads();

    const int cg = t & 15;            // col group 0..15
    const int rg = t >> 4;            // row group 0..15
    const int r0 = rg * 2;            // 2 rows per thread

    float yac[2][32];                 // Y accumulator: 2 rows x 32 cols
    #pragma unroll
    for (int u = 0; u < 2; ++u)
        #pragma unroll
        for (int v = 0; v < 32; ++v) yac[u][v] = 0.0f;

    const float* w1e = w1 + (size_t)e * HS * FFN;
    const float* w2e = w2 + (size_t)e * FFN * HS;

    for (int jp = 0; jp < FFN; jp += BJ) {
        float hac[2][8];              // H accumulator: 2 rows x 8 cols
        #pragma unroll
        for (int u = 0; u < 2; ++u)
            #pragma unroll
            for (int v = 0; v < 8; ++v) hac[u][v] = 0.0f;

        for (int ic = 0; ic < HS; ic += CK) {
            __syncthreads();          // protects Hsh (prev GEMM2) and Xc (prev chunk)
            // stage Xc[32][256]: 2048 float4, 8 per thread (gathered rows)
            #pragma unroll
            for (int q = 0; q < (BM * CK / 4) / 256; ++q) {
                int id = t + 256 * q;
                int rr = id >> 6;     // 64 float4 per row
                int c4 = id & 63;
                int a  = rowa[rr];
                float4 val = make_float4(0.f, 0.f, 0.f, 0.f);
                if (a >= 0)
                    val = *reinterpret_cast<const float4*>(
                        x + (size_t)(a >> 1) * HS + ic + c4 * 4);
                *reinterpret_cast<float4*>(&Xc[rr][c4 * 4]) = val;
            }
            __syncthreads();

            const float* w1p = w1e + (size_t)ic * FFN + jp + cg * 8;
            #pragma unroll 2
            for (int i4 = 0; i4 < CK; i4 += 4) {
                float4 xa = *reinterpret_cast<const float4*>(&Xc[r0][i4]);
                float4 xb = *reinterpret_cast<const float4*>(&Xc[r0 + 1][i4]);
                const float* wr0 = w1p + (size_t)i4 * FFN;
                #pragma unroll
                for (int ii = 0; ii < 4; ++ii) {
                    float4 wa = *reinterpret_cast<const float4*>(wr0 + (size_t)ii * FFN);
                    float4 wb = *reinterpret_cast<const float4*>(wr0 + (size_t)ii * FFN + 4);
                    float x0 = (ii == 0) ? xa.x : (ii == 1) ? xa.y : (ii == 2) ? xa.z : xa.w;
                    float x1 = (ii == 0) ? xb.x : (ii == 1) ? xb.y : (ii == 2) ? xb.z : xb.w;
                    hac[0][0] = fmaf(x0, wa.x, hac[0][0]);
                    hac[0][1] = fmaf(x0, wa.y, hac[0][1]);
                    hac[0][2] = fmaf(x0, wa.z, hac[0][2]);
                    hac[0][3] = fmaf(x0, wa.w, hac[0][3]);
                    hac[0][4] = fmaf(x0, wb.x, hac[0][4]);
                    hac[0][5] = fmaf(x0, wb.y, hac[0][5]);
                    hac[0][6] = fmaf(x0, wb.z, hac[0][6]);
                    hac[0][7] = fmaf(x0, wb.w, hac[0][7]);
                    hac[1][0] = fmaf(x1, wa.x, hac[1][0]);
                    hac[1][1] = fmaf(x1, wa.y, hac[1][1]);
                    hac[1][2] = fmaf(x1, wa.z, hac[1][2]);
                    hac[1][3] = fmaf(x1, wa.w, hac[1][3]);
                    hac[1][4] = fmaf(x1, wb.x, hac[1][4]);
                    hac[1][5] = fmaf(x1, wb.y, hac[1][5]);
                    hac[1][6] = fmaf(x1, wb.z, hac[1][6]);
                    hac[1][7] = fmaf(x1, wb.w, hac[1][7]);
                }
            }
        }

        // gelu + write H panel to LDS
        #pragma unroll
        for (int u = 0; u < 2; ++u)
            #pragma unroll
            for (int v = 0; v < 8; ++v)
                Hsh[r0 + u][cg * 8 + v] = gelu_exact(hac[u][v]);
        __syncthreads();

        // GEMM2: Y[2][32] += H[2][BJ] @ w2[jp:jp+BJ][cg*32 .. +32]
        const float* w2p = w2e + (size_t)jp * HS + cg * 32;
        #pragma unroll 2
        for (int j = 0; j < BJ; ++j) {
            float h0 = Hsh[r0][j];
            float h1 = Hsh[r0 + 1][j];
            const float* wr = w2p + (size_t)j * HS;
            #pragma unroll
            for (int q = 0; q < 8; ++q) {
                float4 w4 = *reinterpret_cast<const float4*>(wr + q * 4);
                yac[0][q * 4 + 0] = fmaf(h0, w4.x, yac[0][q * 4 + 0]);
                yac[0][q * 4 + 1] = fmaf(h0, w4.y, yac[0][q * 4 + 1]);
                yac[0][q * 4 + 2] = fmaf(h0, w4.z, yac[0][q * 4 + 2]);
                yac[0][q * 4 + 3] = fmaf(h0, w4.w, yac[0][q * 4 + 3]);
                yac[1][q * 4 + 0] = fmaf(h1, w4.x, yac[1][q * 4 + 0]);
                yac[1][q * 4 + 1] = fmaf(h1, w4.y, yac[1][q * 4 + 1]);
                yac[1][q * 4 + 2] = fmaf(h1, w4.z, yac[1][q * 4 + 2]);
                yac[1][q * 4 + 3] = fmaf(h1, w4.w, yac[1][q * 4 + 3]);
            }
        }
    }

    // store per-assignment Y rows
    #pragma unroll
    for (int u = 0; u < 2; ++u) {
        int a = rowa[r0 + u];
        if (a >= 0) {
            float* yp = ybuf + (size_t)a * HS + cg * 32;
            #pragma unroll
            for (int q = 0; q < 8; ++q) {
                float4 o = make_float4(yac[u][q * 4 + 0], yac[u][q * 4 + 1],
                                       yac[u][q * 4 + 2], yac[u][q * 4 + 3]);
                *reinterpret_cast<float4*>(yp + q * 4) = o;
            }
        }
    }
}

__global__ void moe_combine(const float* __restrict__ ybuf,
                            const float* __restrict__ ew,
                            float* __restrict__ out)
{
    int i = blockIdx.x * 256 + threadIdx.x;   // over T*HS/4 float4s
    if (i >= T_TOK * HS / 4) return;
    int tk = i >> 7;                          // / (HS/4 = 128)
    int c4 = i & 127;
    float wA = ew[2 * tk];
    float wB = ew[2 * tk + 1];
    const float4* y4 = reinterpret_cast<const float4*>(ybuf);
    float4 a = y4[(size_t)(2 * tk) * (HS / 4) + c4];
    float4 b = y4[(size_t)(2 * tk + 1) * (HS / 4) + c4];
    float4 o;
    o.x = wA * a.x + wB * b.x;
    o.y = wA * a.y + wB * b.y;
    o.z = wA * a.z + wB * b.z;
    o.w = wA * a.w + wB * b.w;
    reinterpret_cast<float4*>(out)[i] = o;
}

extern "C" void kernel_launch(void* const* d_in, const int* in_sizes, int n_in,
                              void* d_out, int out_size, void* d_ws, size_t ws_size,
                              hipStream_t stream) {
    const float* x  = (const float*)d_in[0];   // [2048,2,512] fp32
    const float* ew = (const float*)d_in[1];   // [4096,2] fp32
    const int*   ei = (const int*)d_in[2];     // [4096,2] int32
    const float* w1 = (const float*)d_in[3];   // [8,512,2048] fp32
    const float* w2 = (const float*)d_in[4];   // [8,2048,512] fp32
    float* out = (float*)d_out;

    // workspace layout: cnt[8] @0 (256B pad) | bucket[8][8192] @256B (256KB) |
    //                   ybuf[8192][512] fp32 @512KB (16MB). Total ~16.5MB.
    int*   cnt    = (int*)d_ws;
    int*   bucket = cnt + 64;
    float* ybuf   = (float*)((char*)d_ws + (1 << 19));

    moe_init<<<1, 64, 0, stream>>>(cnt);
    moe_scatter<<<NA / 256, 256, 0, stream>>>(ei, cnt, bucket);
    moe_fused<<<NE * (NA / BM), 256, 0, stream>>>(x, w1, w2, cnt, bucket, ybuf);
    moe_combine<<<(T_TOK * HS / 4 + 255) / 256, 256, 0, stream>>>(ybuf, ew, out);
}

// Round 3
// 308.038 us; speedup vs baseline: 16.1869x; 16.1869x over previous
//
#include <hip/hip_runtime.h>
#include <stdint.h>

#define T_TOK 4096
#define KTOP  2
#define HS    512
#define FFN   2048
#define NE    8
#define NA    (T_TOK*KTOP)     // 8192 assignments
#define MT    128              // M-tile (rows per gemm block)
#define BK    32               // K-step
#define MT_MAX 72              // ceil((NA + NE*(MT-1))/MT)
#define SLOT_CAP (MT_MAX*MT)   // 9216

// ---------------- workspace layout (bytes) ----------------
#define WS_CNT   0u            // 8 ints
#define WS_CNT2  64u           // 8 ints
#define WS_OFF   128u          // 9 ints (off[8] = padded total)
#define WS_MEXP  256u          // MT_MAX ints
#define WS_SLOTS 1024u         // 9216 ints
#define WS_INV   40960u        // 8192 ints
#define MB_ (1024ull*1024ull)
#define WS_XH   (1*MB_)        // 4MB  bf16 [4096][512]
#define WS_XL   (5*MB_)        // 4MB
#define WS_W2TH (9*MB_)        // 16MB bf16 [8][512][2048]
#define WS_W2TL (25*MB_)       // 16MB
#define WS_HH   (41*MB_)       // 36MB bf16 [9216][2048]
#define WS_HL   (77*MB_)       // 36MB
#define WS_W1TH (113*MB_)      // 16MB bf16 [8][2048][512]   (dead after gemm1)
#define WS_W1TL (129*MB_)      // 16MB
#define WS_YP0  (113*MB_)      // 18MB f32 [9216][512]  (overlays W1T)
#define WS_YP1  (131*MB_)      // 18MB -> ends 149MB
#define WS_NEED (149*MB_)

typedef short bf16x8 __attribute__((ext_vector_type(8)));
typedef float f32x4  __attribute__((ext_vector_type(4)));

__device__ __forceinline__ unsigned short f2bf(float f) {
    unsigned u = __builtin_bit_cast(unsigned, f);
    u += 0x7fffu + ((u >> 16) & 1u);          // RNE
    return (unsigned short)(u >> 16);
}
__device__ __forceinline__ float bf2f(unsigned short h) {
    return __builtin_bit_cast(float, (unsigned)h << 16);
}
__device__ __forceinline__ float gelu_exact(float v) {
    return 0.5f * v * (1.0f + erff(v * 0.70710678118654752f));
}
__device__ __forceinline__ void gl_lds16(const void* g, void* l) {
    __builtin_amdgcn_global_load_lds(
        (const __attribute__((address_space(1))) unsigned int*)g,
        (__attribute__((address_space(3))) unsigned int*)l, 16, 0, 0);
}

// ---------------- routing prep ----------------
__global__ void moe_setup_init(int* cnt, int* cnt2, int* slots) {
    int gid = blockIdx.x * 256 + threadIdx.x;
    if (gid < NE) { cnt[gid] = 0; cnt2[gid] = 0; }
    if (gid < SLOT_CAP) slots[gid] = -1;
}

__global__ void moe_count(const int* __restrict__ eidx, int* cnt) {
    int a = blockIdx.x * 256 + threadIdx.x;
    if (a < NA) atomicAdd(&cnt[eidx[a]], 1);
}

__global__ void moe_offsets(const int* __restrict__ cnt, int* off, int* mexp) {
    if (threadIdx.x != 0 || blockIdx.x != 0) return;
    int run = 0;
    for (int e = 0; e < NE; ++e) {
        off[e] = run;
        int nt = (cnt[e] + MT - 1) / MT;
        for (int i = 0; i < nt; ++i) mexp[run / MT + i] = e;
        run += nt * MT;
    }
    off[NE] = run;
    for (int m = run / MT; m < MT_MAX; ++m) mexp[m] = 0;
}

__global__ void moe_fill(const int* __restrict__ eidx, const int* __restrict__ off,
                         int* cnt2, int* slots, int* inv) {
    int a = blockIdx.x * 256 + threadIdx.x;
    if (a < NA) {
        int e = eidx[a];
        int p = atomicAdd(&cnt2[e], 1);
        int s = off[e] + p;
        slots[s] = a;        // order nondeterministic; per-assignment result isn't
        inv[a] = s;
    }
}

// ---------------- precision prep ----------------
__global__ void split_x(const float* __restrict__ x,
                        unsigned short* __restrict__ xh, unsigned short* __restrict__ xl) {
    int i = blockIdx.x * 256 + threadIdx.x;       // over 2M/4 float4s
    if (i >= T_TOK * HS / 4) return;
    float4 v = reinterpret_cast<const float4*>(x)[i];
    unsigned short h0 = f2bf(v.x), h1 = f2bf(v.y), h2 = f2bf(v.z), h3 = f2bf(v.w);
    unsigned short l0 = f2bf(v.x - bf2f(h0)), l1 = f2bf(v.y - bf2f(h1));
    unsigned short l2 = f2bf(v.z - bf2f(h2)), l3 = f2bf(v.w - bf2f(h3));
    uint2 vh = { (unsigned)h0 | ((unsigned)h1 << 16), (unsigned)h2 | ((unsigned)h3 << 16) };
    uint2 vl = { (unsigned)l0 | ((unsigned)l1 << 16), (unsigned)l2 | ((unsigned)l3 << 16) };
    reinterpret_cast<uint2*>(xh)[i] = vh;
    reinterpret_cast<uint2*>(xl)[i] = vl;
}

// transpose [e][R][C] f32 -> [e][C][R] bf16 hi/lo
__global__ void transpose_split(const float* __restrict__ src,
                                unsigned short* __restrict__ dh,
                                unsigned short* __restrict__ dl, int R, int C) {
    __shared__ float tile[32][33];
    const int e = blockIdx.z, k0 = blockIdx.x * 32, n0 = blockIdx.y * 32;
    const int t = threadIdx.x;
    #pragma unroll
    for (int q = 0; q < 4; ++q) {
        int idx = t + q * 256, kk = idx >> 5, nn = idx & 31;
        tile[kk][nn] = src[((size_t)e * R + k0 + kk) * C + n0 + nn];
    }
    __syncthreads();
    #pragma unroll
    for (int q = 0; q < 4; ++q) {
        int idx = t + q * 256, nn = idx >> 5, kk = idx & 31;
        float v = tile[kk][nn];
        unsigned short h = f2bf(v);
        unsigned short l = f2bf(v - bf2f(h));
        size_t o = ((size_t)e * C + n0 + nn) * R + k0 + kk;
        dh[o] = h; dl[o] = l;
    }
}

// ---------------- grouped GEMM1: H = gelu(X @ W1), split to bf16 hi/lo ----------------
__global__ __launch_bounds__(256, 2) void moe_gemm1(
    const unsigned short* __restrict__ XH, const unsigned short* __restrict__ XL,
    const unsigned short* __restrict__ W1TH, const unsigned short* __restrict__ W1TL,
    const int* __restrict__ offp, const int* __restrict__ mexp,
    const int* __restrict__ slots,
    unsigned short* __restrict__ HHo, unsigned short* __restrict__ HLo)
{
    const int mt = blockIdx.x, nt = blockIdx.y;
    if (mt * MT >= offp[NE]) return;
    const int e = mexp[mt];
    const int t = threadIdx.x, lane = t & 63, wv = t >> 6;

    __shared__ __align__(16) short Ah[MT * BK], Al[MT * BK], Bh[MT * BK], Bl[MT * BK];
    __shared__ int srow[MT];
    if (t < MT) { int s = slots[mt * MT + t]; srow[t] = (s < 0) ? 0 : (s >> 1); }
    __syncthreads();

    // staging constants (2 global_load_lds per buffer per wave; 16 rows per inst)
    int baseA[2], baseB[2];
    #pragma unroll
    for (int q = 0; q < 2; ++q) {
        int i = 2 * wv + q;
        int row = i * 16 + (lane >> 2);
        int cg = (lane & 3) ^ ((row >> 1) & 3);          // XOR source swizzle
        baseA[q] = srow[row] * HS + cg * 8;
        baseB[q] = (e * FFN + nt * MT + row) * HS + cg * 8;
    }

    const int wm = wv >> 1, wn = wv & 1, q4 = lane >> 4, l15 = lane & 15;
    int offA[4], offB[4];
    #pragma unroll
    for (int m = 0; m < 4; ++m) {
        int r = wm * 64 + m * 16 + l15;
        offA[m] = r * 64 + ((q4 ^ ((r >> 1) & 3)) * 16);  // XOR read swizzle (same involution)
        int rb = wn * 64 + m * 16 + l15;
        offB[m] = rb * 64 + ((q4 ^ ((rb >> 1) & 3)) * 16);
    }

    f32x4 acc[4][4];
    #pragma unroll
    for (int m = 0; m < 4; ++m)
        #pragma unroll
        for (int n = 0; n < 4; ++n) { f32x4 z = {0.f, 0.f, 0.f, 0.f}; acc[m][n] = z; }

    for (int kk = 0; kk < HS; kk += BK) {
        __syncthreads();
        #pragma unroll
        for (int q = 0; q < 2; ++q) {
            int i = 2 * wv + q;
            gl_lds16(XH   + baseA[q] + kk, (char*)Ah + i * 1024);
            gl_lds16(XL   + baseA[q] + kk, (char*)Al + i * 1024);
            gl_lds16(W1TH + baseB[q] + kk, (char*)Bh + i * 1024);
            gl_lds16(W1TL + baseB[q] + kk, (char*)Bl + i * 1024);
        }
        __syncthreads();   // compiler drains vmcnt before barrier -> staged data ready

        bf16x8 ah[4], al[4], bh[4], bl[4];
        #pragma unroll
        for (int m = 0; m < 4; ++m) {
            ah[m] = *(const bf16x8*)((const char*)Ah + offA[m]);
            al[m] = *(const bf16x8*)((const char*)Al + offA[m]);
            bh[m] = *(const bf16x8*)((const char*)Bh + offB[m]);
            bl[m] = *(const bf16x8*)((const char*)Bl + offB[m]);
        }
        #pragma unroll
        for (int m = 0; m < 4; ++m)
            #pragma unroll
            for (int n = 0; n < 4; ++n) {
                acc[m][n] = __builtin_amdgcn_mfma_f32_16x16x32_bf16(ah[m], bh[n], acc[m][n], 0, 0, 0);
                acc[m][n] = __builtin_amdgcn_mfma_f32_16x16x32_bf16(ah[m], bl[n], acc[m][n], 0, 0, 0);
                acc[m][n] = __builtin_amdgcn_mfma_f32_16x16x32_bf16(al[m], bh[n], acc[m][n], 0, 0, 0);
            }
    }

    // epilogue: gelu + hi/lo split, store H (slot-indexed, pads harmless)
    const int grow0 = mt * MT + wm * 64, colg0 = nt * MT + wn * 64;
    #pragma unroll
    for (int m = 0; m < 4; ++m)
        #pragma unroll
        for (int n = 0; n < 4; ++n)
            #pragma unroll
            for (int j = 0; j < 4; ++j) {
                int grow = grow0 + m * 16 + q4 * 4 + j;
                int col  = colg0 + n * 16 + l15;
                float v = gelu_exact(acc[m][n][j]);
                unsigned short h = f2bf(v);
                size_t o = (size_t)grow * FFN + col;
                HHo[o] = h;
                HLo[o] = f2bf(v - bf2f(h));
            }
}

// ---------------- grouped GEMM2: Y = H @ W2, split-K=2 ----------------
__global__ __launch_bounds__(256, 2) void moe_gemm2(
    const unsigned short* __restrict__ HHi, const unsigned short* __restrict__ HLi,
    const unsigned short* __restrict__ W2TH, const unsigned short* __restrict__ W2TL,
    const int* __restrict__ offp, const int* __restrict__ mexp,
    float* __restrict__ YP0, float* __restrict__ YP1)
{
    const int mt = blockIdx.x;
    const int nt = blockIdx.y >> 1, ks = blockIdx.y & 1;
    if (mt * MT >= offp[NE]) return;
    const int e = mexp[mt];
    const int t = threadIdx.x, lane = t & 63, wv = t >> 6;

    __shared__ __align__(16) short Ah[MT * BK], Al[MT * BK], Bh[MT * BK], Bl[MT * BK];

    int baseA[2], baseB[2];
    #pragma unroll
    for (int q = 0; q < 2; ++q) {
        int i = 2 * wv + q;
        int row = i * 16 + (lane >> 2);
        int cg = (lane & 3) ^ ((row >> 1) & 3);
        baseA[q] = (mt * MT + row) * FFN + cg * 8;          // identity rows (slot order)
        baseB[q] = (e * HS + nt * MT + row) * FFN + cg * 8;
    }

    const int wm = wv >> 1, wn = wv & 1, q4 = lane >> 4, l15 = lane & 15;
    int offA[4], offB[4];
    #pragma unroll
    for (int m = 0; m < 4; ++m) {
        int r = wm * 64 + m * 16 + l15;
        offA[m] = r * 64 + ((q4 ^ ((r >> 1) & 3)) * 16);
        int rb = wn * 64 + m * 16 + l15;
        offB[m] = rb * 64 + ((q4 ^ ((rb >> 1) & 3)) * 16);
    }

    f32x4 acc[4][4];
    #pragma unroll
    for (int m = 0; m < 4; ++m)
        #pragma unroll
        for (int n = 0; n < 4; ++n) { f32x4 z = {0.f, 0.f, 0.f, 0.f}; acc[m][n] = z; }

    const int k0 = ks * (FFN / 2), k1 = k0 + FFN / 2;
    for (int kk = k0; kk < k1; kk += BK) {
        __syncthreads();
        #pragma unroll
        for (int q = 0; q < 2; ++q) {
            int i = 2 * wv + q;
            gl_lds16(HHi  + baseA[q] + kk, (char*)Ah + i * 1024);
            gl_lds16(HLi  + baseA[q] + kk, (char*)Al + i * 1024);
            gl_lds16(W2TH + baseB[q] + kk, (char*)Bh + i * 1024);
            gl_lds16(W2TL + baseB[q] + kk, (char*)Bl + i * 1024);
        }
        __syncthreads();

        bf16x8 ah[4], al[4], bh[4], bl[4];
        #pragma unroll
        for (int m = 0; m < 4; ++m) {
            ah[m] = *(const bf16x8*)((const char*)Ah + offA[m]);
            al[m] = *(const bf16x8*)((const char*)Al + offA[m]);
            bh[m] = *(const bf16x8*)((const char*)Bh + offB[m]);
            bl[m] = *(const bf16x8*)((const char*)Bl + offB[m]);
        }
        #pragma unroll
        for (int m = 0; m < 4; ++m)
            #pragma unroll
            for (int n = 0; n < 4; ++n) {
                acc[m][n] = __builtin_amdgcn_mfma_f32_16x16x32_bf16(ah[m], bh[n], acc[m][n], 0, 0, 0);
                acc[m][n] = __builtin_amdgcn_mfma_f32_16x16x32_bf16(ah[m], bl[n], acc[m][n], 0, 0, 0);
                acc[m][n] = __builtin_amdgcn_mfma_f32_16x16x32_bf16(al[m], bh[n], acc[m][n], 0, 0, 0);
            }
    }

    float* YP = ks ? YP1 : YP0;
    const int grow0 = mt * MT + wm * 64, colg0 = nt * MT + wn * 64;
    #pragma unroll
    for (int m = 0; m < 4; ++m)
        #pragma unroll
        for (int n = 0; n < 4; ++n)
            #pragma unroll
            for (int j = 0; j < 4; ++j) {
                int grow = grow0 + m * 16 + q4 * 4 + j;
                int col  = colg0 + n * 16 + l15;
                YP[(size_t)grow * HS + col] = acc[m][n][j];
            }
}

// ---------------- combine ----------------
__global__ void moe_combine2(const float* __restrict__ YP0, const float* __restrict__ YP1,
                             const int* __restrict__ inv, const float* __restrict__ ew,
                             float* __restrict__ out) {
    int i = blockIdx.x * 256 + threadIdx.x;      // over T*HS/4 float4s
    if (i >= T_TOK * HS / 4) return;
    int tk = i >> 7, c4 = i & 127;
    int s0 = inv[2 * tk], s1 = inv[2 * tk + 1];
    float w0 = ew[2 * tk], w1 = ew[2 * tk + 1];
    const float4* p0 = reinterpret_cast<const float4*>(YP0);
    const float4* p1 = reinterpret_cast<const float4*>(YP1);
    float4 a0 = p0[(size_t)s0 * 128 + c4], b0 = p1[(size_t)s0 * 128 + c4];
    float4 a1 = p0[(size_t)s1 * 128 + c4], b1 = p1[(size_t)s1 * 128 + c4];
    float4 o;
    o.x = w0 * (a0.x + b0.x) + w1 * (a1.x + b1.x);
    o.y = w0 * (a0.y + b0.y) + w1 * (a1.y + b1.y);
    o.z = w0 * (a0.z + b0.z) + w1 * (a1.z + b1.z);
    o.w = w0 * (a0.w + b0.w) + w1 * (a1.w + b1.w);
    reinterpret_cast<float4*>(out)[i] = o;
}

// ================= fallback VALU path (proven baseline) =================
#define FB_BM 32
#define FB_BJ 128
#define FB_CK 256
#define FB_XSTR (FB_CK+4)
#define FB_HSTR (FB_BJ+4)

__global__ void fb_init(int* cnt) { int i = threadIdx.x; if (i < NE) cnt[i] = 0; }

__global__ void fb_scatter(const int* __restrict__ eidx, int* cnt, int* bucket) {
    int a = blockIdx.x * 256 + threadIdx.x;
    if (a < NA) { int e = eidx[a]; int p = atomicAdd(&cnt[e], 1); bucket[e * NA + p] = a; }
}

__global__ __launch_bounds__(256, 1) void fb_fused(
    const float* __restrict__ x, const float* __restrict__ w1, const float* __restrict__ w2,
    const int* __restrict__ cnt, const int* __restrict__ bucket, float* __restrict__ ybuf)
{
    const int bid = blockIdx.x;
    const int e = bid & (NE - 1), tr = bid >> 3;
    const int n_e = cnt[e], rbase = tr * FB_BM;
    if (rbase >= n_e) return;
    const int t = threadIdx.x;
    __shared__ __align__(16) float Xc[FB_BM][FB_XSTR];
    __shared__ __align__(16) float Hsh[FB_BM][FB_HSTR];
    __shared__ int rowa[FB_BM];
    if (t < FB_BM) { int r = rbase + t; rowa[t] = (r < n_e) ? bucket[e * NA + r] : -1; }
    __syncthreads();
    const int cg = t & 15, rg = t >> 4, r0 = rg * 2;
    float yac[2][32];
    #pragma unroll
    for (int u = 0; u < 2; ++u)
        #pragma unroll
        for (int v = 0; v < 32; ++v) yac[u][v] = 0.0f;
    const float* w1e = w1 + (size_t)e * HS * FFN;
    const float* w2e = w2 + (size_t)e * FFN * HS;
    for (int jp = 0; jp < FFN; jp += FB_BJ) {
        float hac[2][8];
        #pragma unroll
        for (int u = 0; u < 2; ++u)
            #pragma unroll
            for (int v = 0; v < 8; ++v) hac[u][v] = 0.0f;
        for (int ic = 0; ic < HS; ic += FB_CK) {
            __syncthreads();
            #pragma unroll
            for (int q = 0; q < (FB_BM * FB_CK / 4) / 256; ++q) {
                int id = t + 256 * q, rr = id >> 6, c4 = id & 63;
                int a = rowa[rr];
                float4 val = make_float4(0.f, 0.f, 0.f, 0.f);
                if (a >= 0) val = *reinterpret_cast<const float4*>(x + (size_t)(a >> 1) * HS + ic + c4 * 4);
                *reinterpret_cast<float4*>(&Xc[rr][c4 * 4]) = val;
            }
            __syncthreads();
            const float* w1p = w1e + (size_t)ic * FFN + jp + cg * 8;
            #pragma unroll 2
            for (int i4 = 0; i4 < FB_CK; i4 += 4) {
                float4 xa = *reinterpret_cast<const float4*>(&Xc[r0][i4]);
                float4 xb = *reinterpret_cast<const float4*>(&Xc[r0 + 1][i4]);
                const float* wr0 = w1p + (size_t)i4 * FFN;
                #pragma unroll
                for (int ii = 0; ii < 4; ++ii) {
                    float4 wa = *reinterpret_cast<const float4*>(wr0 + (size_t)ii * FFN);
                    float4 wb = *reinterpret_cast<const float4*>(wr0 + (size_t)ii * FFN + 4);
                    float x0 = (ii == 0) ? xa.x : (ii == 1) ? xa.y : (ii == 2) ? xa.z : xa.w;
                    float x1 = (ii == 0) ? xb.x : (ii == 1) ? xb.y : (ii == 2) ? xb.z : xb.w;
                    hac[0][0] = fmaf(x0, wa.x, hac[0][0]); hac[0][1] = fmaf(x0, wa.y, hac[0][1]);
                    hac[0][2] = fmaf(x0, wa.z, hac[0][2]); hac[0][3] = fmaf(x0, wa.w, hac[0][3]);
                    hac[0][4] = fmaf(x0, wb.x, hac[0][4]); hac[0][5] = fmaf(x0, wb.y, hac[0][5]);
                    hac[0][6] = fmaf(x0, wb.z, hac[0][6]); hac[0][7] = fmaf(x0, wb.w, hac[0][7]);
                    hac[1][0] = fmaf(x1, wa.x, hac[1][0]); hac[1][1] = fmaf(x1, wa.y, hac[1][1]);
                    hac[1][2] = fmaf(x1, wa.z, hac[1][2]); hac[1][3] = fmaf(x1, wa.w, hac[1][3]);
                    hac[1][4] = fmaf(x1, wb.x, hac[1][4]); hac[1][5] = fmaf(x1, wb.y, hac[1][5]);
                    hac[1][6] = fmaf(x1, wb.z, hac[1][6]); hac[1][7] = fmaf(x1, wb.w, hac[1][7]);
                }
            }
        }
        #pragma unroll
        for (int u = 0; u < 2; ++u)
            #pragma unroll
            for (int v = 0; v < 8; ++v) Hsh[r0 + u][cg * 8 + v] = gelu_exact(hac[u][v]);
        __syncthreads();
        const float* w2p = w2e + (size_t)jp * HS + cg * 32;
        #pragma unroll 2
        for (int j = 0; j < FB_BJ; ++j) {
            float h0 = Hsh[r0][j], h1 = Hsh[r0 + 1][j];
            const float* wr = w2p + (size_t)j * HS;
            #pragma unroll
            for (int q = 0; q < 8; ++q) {
                float4 w4 = *reinterpret_cast<const float4*>(wr + q * 4);
                yac[0][q * 4 + 0] = fmaf(h0, w4.x, yac[0][q * 4 + 0]);
                yac[0][q * 4 + 1] = fmaf(h0, w4.y, yac[0][q * 4 + 1]);
                yac[0][q * 4 + 2] = fmaf(h0, w4.z, yac[0][q * 4 + 2]);
                yac[0][q * 4 + 3] = fmaf(h0, w4.w, yac[0][q * 4 + 3]);
                yac[1][q * 4 + 0] = fmaf(h1, w4.x, yac[1][q * 4 + 0]);
                yac[1][q * 4 + 1] = fmaf(h1, w4.y, yac[1][q * 4 + 1]);
                yac[1][q * 4 + 2] = fmaf(h1, w4.z, yac[1][q * 4 + 2]);
                yac[1][q * 4 + 3] = fmaf(h1, w4.w, yac[1][q * 4 + 3]);
            }
        }
    }
    #pragma unroll
    for (int u = 0; u < 2; ++u) {
        int a = rowa[r0 + u];
        if (a >= 0) {
            float* yp = ybuf + (size_t)a * HS + cg * 32;
            #pragma unroll
            for (int q = 0; q < 8; ++q) {
                float4 o = make_float4(yac[u][q * 4 + 0], yac[u][q * 4 + 1],
                                       yac[u][q * 4 + 2], yac[u][q * 4 + 3]);
                *reinterpret_cast<float4*>(yp + q * 4) = o;
            }
        }
    }
}

__global__ void fb_combine(const float* __restrict__ ybuf, const float* __restrict__ ew,
                           float* __restrict__ out) {
    int i = blockIdx.x * 256 + threadIdx.x;
    if (i >= T_TOK * HS / 4) return;
    int tk = i >> 7, c4 = i & 127;
    float wA = ew[2 * tk], wB = ew[2 * tk + 1];
    const float4* y4 = reinterpret_cast<const float4*>(ybuf);
    float4 a = y4[(size_t)(2 * tk) * (HS / 4) + c4];
    float4 b = y4[(size_t)(2 * tk + 1) * (HS / 4) + c4];
    float4 o;
    o.x = wA * a.x + wB * b.x; o.y = wA * a.y + wB * b.y;
    o.z = wA * a.z + wB * b.z; o.w = wA * a.w + wB * b.w;
    reinterpret_cast<float4*>(out)[i] = o;
}

// ================= launch =================
extern "C" void kernel_launch(void* const* d_in, const int* in_sizes, int n_in,
                              void* d_out, int out_size, void* d_ws, size_t ws_size,
                              hipStream_t stream) {
    const float* x  = (const float*)d_in[0];
    const float* ew = (const float*)d_in[1];
    const int*   ei = (const int*)d_in[2];
    const float* w1 = (const float*)d_in[3];
    const float* w2 = (const float*)d_in[4];
    float* out = (float*)d_out;
    char* W = (char*)d_ws;

    if (ws_size < WS_NEED) {
        // fallback: proven fp32 VALU path (16.5MB ws)
        int* cnt = (int*)d_ws;
        int* bucket = cnt + 64;
        float* ybuf = (float*)(W + (1 << 19));
        fb_init<<<1, 64, 0, stream>>>(cnt);
        fb_scatter<<<NA / 256, 256, 0, stream>>>(ei, cnt, bucket);
        fb_fused<<<NE * (NA / FB_BM), 256, 0, stream>>>(x, w1, w2, cnt, bucket, ybuf);
        fb_combine<<<(T_TOK * HS / 4 + 255) / 256, 256, 0, stream>>>(ybuf, ew, out);
        return;
    }

    int* cnt   = (int*)(W + WS_CNT);
    int* cnt2  = (int*)(W + WS_CNT2);
    int* offp  = (int*)(W + WS_OFF);
    int* mexp  = (int*)(W + WS_MEXP);
    int* slots = (int*)(W + WS_SLOTS);
    int* inv   = (int*)(W + WS_INV);
    unsigned short* XH   = (unsigned short*)(W + WS_XH);
    unsigned short* XL   = (unsigned short*)(W + WS_XL);
    unsigned short* W1TH = (unsigned short*)(W + WS_W1TH);
    unsigned short* W1TL = (unsigned short*)(W + WS_W1TL);
    unsigned short* W2TH = (unsigned short*)(W + WS_W2TH);
    unsigned short* W2TL = (unsigned short*)(W + WS_W2TL);
    unsigned short* HH   = (unsigned short*)(W + WS_HH);
    unsigned short* HL   = (unsigned short*)(W + WS_HL);
    float* YP0 = (float*)(W + WS_YP0);
    float* YP1 = (float*)(W + WS_YP1);

    moe_setup_init<<<(SLOT_CAP + 255) / 256, 256, 0, stream>>>(cnt, cnt2, slots);
    moe_count<<<NA / 256, 256, 0, stream>>>(ei, cnt);
    moe_offsets<<<1, 64, 0, stream>>>(cnt, offp, mexp);
    moe_fill<<<NA / 256, 256, 0, stream>>>(ei, offp, cnt2, slots, inv);

    split_x<<<(T_TOK * HS / 4) / 256, 256, 0, stream>>>(x, XH, XL);
    transpose_split<<<dim3(HS / 32, FFN / 32, NE), 256, 0, stream>>>(w1, W1TH, W1TL, HS, FFN);
    transpose_split<<<dim3(FFN / 32, HS / 32, NE), 256, 0, stream>>>(w2, W2TH, W2TL, FFN, HS);

    moe_gemm1<<<dim3(MT_MAX, FFN / MT), 256, 0, stream>>>(XH, XL, W1TH, W1TL, offp, mexp, slots, HH, HL);
    moe_gemm2<<<dim3(MT_MAX, (HS / MT) * 2), 256, 0, stream>>>(HH, HL, W2TH, W2TL, offp, mexp, YP0, YP1);
    moe_combine2<<<(T_TOK * HS / 4) / 256, 256, 0, stream>>>(YP0, YP1, inv, ew, out);
}

// Round 4
// 277.787 us; speedup vs baseline: 17.9496x; 1.1089x over previous
//
#include <hip/hip_runtime.h>
#include <stdint.h>

#define T_TOK 4096
#define KTOP  2
#define HS    512
#define FFN   2048
#define NE    8
#define NA    (T_TOK*KTOP)     // 8192 assignments
#define MT    128              // M-tile (rows per gemm block)
#define BK    32               // K-step
#define MT_MAX 72              // ceil((NA + NE*(MT-1))/MT) = 9 groups of 8
#define SLOT_CAP (MT_MAX*MT)   // 9216

// ---------------- workspace layout (bytes) ----------------
#define WS_CNT   0u            // 8 ints
#define WS_CNT2  64u           // 8 ints
#define WS_OFF   128u          // 9 ints (off[8] = padded total)
#define WS_MEXP  256u          // MT_MAX ints
#define WS_SLOTS 1024u         // 9216 ints
#define WS_INV   40960u        // 8192 ints
#define MB_ (1024ull*1024ull)
#define WS_XH   (1*MB_)        // 4MB  bf16 [4096][512]
#define WS_XL   (5*MB_)        // 4MB
#define WS_W2TH (9*MB_)        // 16MB bf16 [8][512][2048]
#define WS_W2TL (25*MB_)       // 16MB
#define WS_HH   (41*MB_)       // 36MB bf16 [9216][2048]
#define WS_HL   (77*MB_)       // 36MB
#define WS_W1TH (113*MB_)      // 16MB bf16 [8][2048][512]   (dead after gemm1)
#define WS_W1TL (129*MB_)      // 16MB
#define WS_YP0  (113*MB_)      // 18MB f32 [9216][512]  (overlays W1T)
#define WS_YP1  (131*MB_)      // 18MB -> ends 149MB
#define WS_NEED (149*MB_)

typedef short bf16x8 __attribute__((ext_vector_type(8)));
typedef float f32x4  __attribute__((ext_vector_type(4)));

__device__ __forceinline__ unsigned short f2bf(float f) {
    unsigned u = __builtin_bit_cast(unsigned, f);
    u += 0x7fffu + ((u >> 16) & 1u);          // RNE
    return (unsigned short)(u >> 16);
}
__device__ __forceinline__ float bf2f(unsigned short h) {
    return __builtin_bit_cast(float, (unsigned)h << 16);
}
__device__ __forceinline__ float gelu_exact(float v) {
    return 0.5f * v * (1.0f + erff(v * 0.70710678118654752f));
}
__device__ __forceinline__ void gl_lds16(const void* g, void* l) {
    __builtin_amdgcn_global_load_lds(
        (const __attribute__((address_space(1))) unsigned int*)g,
        (__attribute__((address_space(3))) unsigned int*)l, 16, 0, 0);
}

// ---------------- routing prep ----------------
__global__ void moe_setup_init(int* cnt, int* cnt2, int* slots) {
    int gid = blockIdx.x * 256 + threadIdx.x;
    if (gid < NE) { cnt[gid] = 0; cnt2[gid] = 0; }
    if (gid < SLOT_CAP) slots[gid] = -1;
}

__global__ void moe_count(const int* __restrict__ eidx, int* cnt) {
    int a = blockIdx.x * 256 + threadIdx.x;
    if (a < NA) atomicAdd(&cnt[eidx[a]], 1);
}

__global__ void moe_offsets(const int* __restrict__ cnt, int* off, int* mexp) {
    if (threadIdx.x != 0 || blockIdx.x != 0) return;
    int run = 0;
    for (int e = 0; e < NE; ++e) {
        off[e] = run;
        int nt = (cnt[e] + MT - 1) / MT;
        for (int i = 0; i < nt; ++i) mexp[run / MT + i] = e;
        run += nt * MT;
    }
    off[NE] = run;
    for (int m = run / MT; m < MT_MAX; ++m) mexp[m] = 0;
}

__global__ void moe_fill(const int* __restrict__ eidx, const int* __restrict__ off,
                         int* cnt2, int* slots, int* inv) {
    int a = blockIdx.x * 256 + threadIdx.x;
    if (a < NA) {
        int e = eidx[a];
        int p = atomicAdd(&cnt2[e], 1);
        int s = off[e] + p;
        slots[s] = a;        // order nondeterministic; per-assignment result isn't
        inv[a] = s;
    }
}

// ---------------- precision prep ----------------
__global__ void split_x(const float* __restrict__ x,
                        unsigned short* __restrict__ xh, unsigned short* __restrict__ xl) {
    int i = blockIdx.x * 256 + threadIdx.x;       // over 2M/4 float4s
    if (i >= T_TOK * HS / 4) return;
    float4 v = reinterpret_cast<const float4*>(x)[i];
    unsigned short h0 = f2bf(v.x), h1 = f2bf(v.y), h2 = f2bf(v.z), h3 = f2bf(v.w);
    unsigned short l0 = f2bf(v.x - bf2f(h0)), l1 = f2bf(v.y - bf2f(h1));
    unsigned short l2 = f2bf(v.z - bf2f(h2)), l3 = f2bf(v.w - bf2f(h3));
    uint2 vh = { (unsigned)h0 | ((unsigned)h1 << 16), (unsigned)h2 | ((unsigned)h3 << 16) };
    uint2 vl = { (unsigned)l0 | ((unsigned)l1 << 16), (unsigned)l2 | ((unsigned)l3 << 16) };
    reinterpret_cast<uint2*>(xh)[i] = vh;
    reinterpret_cast<uint2*>(xl)[i] = vl;
}

// transpose [e][R][C] f32 -> [e][C][R] bf16 hi/lo
__global__ void transpose_split(const float* __restrict__ src,
                                unsigned short* __restrict__ dh,
                                unsigned short* __restrict__ dl, int R, int C) {
    __shared__ float tile[32][33];
    const int e = blockIdx.z, k0 = blockIdx.x * 32, n0 = blockIdx.y * 32;
    const int t = threadIdx.x;
    #pragma unroll
    for (int q = 0; q < 4; ++q) {
        int idx = t + q * 256, kk = idx >> 5, nn = idx & 31;
        tile[kk][nn] = src[((size_t)e * R + k0 + kk) * C + n0 + nn];
    }
    __syncthreads();
    #pragma unroll
    for (int q = 0; q < 4; ++q) {
        int idx = t + q * 256, nn = idx >> 5, kk = idx & 31;
        float v = tile[kk][nn];
        unsigned short h = f2bf(v);
        unsigned short l = f2bf(v - bf2f(h));
        size_t o = ((size_t)e * C + n0 + nn) * R + k0 + kk;
        dh[o] = h; dl[o] = l;
    }
}

// ---------------- grouped GEMM1: H = gelu(X @ W1), split to bf16 hi/lo ----------------
// Grid: 1-D, NB1 = (MT_MAX/8)*8*16 = 1152 blocks.
// XCD-affinity decode: all 16 nt-blocks of one mt are consecutive slots on ONE XCD
// (assumes HW round-robins blockIdx.x across the 8 XCDs) -> A-panel L2 reuse.
__global__ __launch_bounds__(256, 3) void moe_gemm1(
    const unsigned short* __restrict__ XH, const unsigned short* __restrict__ XL,
    const unsigned short* __restrict__ W1TH, const unsigned short* __restrict__ W1TL,
    const int* __restrict__ offp, const int* __restrict__ mexp,
    const int* __restrict__ slots,
    unsigned short* __restrict__ HHo, unsigned short* __restrict__ HLo)
{
    const int xcd = blockIdx.x & 7;
    const int r_  = blockIdx.x >> 3;      // 0..143
    const int mtg = r_ >> 4;              // 0..8
    const int nt  = r_ & 15;              // 0..15
    const int mt  = mtg * 8 + xcd;        // 0..71
    if (mt * MT >= offp[NE]) return;
    const int e = mexp[mt];
    const int t = threadIdx.x, lane = t & 63, wv = t >> 6;

    __shared__ __align__(16) short Ah[MT * BK], Al[MT * BK], Bh[MT * BK], Bl[MT * BK];
    __shared__ int srow[MT];
    if (t < MT) { int s = slots[mt * MT + t]; srow[t] = (s < 0) ? 0 : (s >> 1); }
    __syncthreads();

    // staging constants (2 global_load_lds per buffer per wave; 16 rows per inst)
    int baseA[2], baseB[2];
    #pragma unroll
    for (int q = 0; q < 2; ++q) {
        int i = 2 * wv + q;
        int row = i * 16 + (lane >> 2);
        int cg = (lane & 3) ^ ((row >> 1) & 3);          // XOR source swizzle
        baseA[q] = srow[row] * HS + cg * 8;
        baseB[q] = (e * FFN + nt * MT + row) * HS + cg * 8;
    }

    const int wm = wv >> 1, wn = wv & 1, q4 = lane >> 4, l15 = lane & 15;
    int offA[4], offB[4];
    #pragma unroll
    for (int m = 0; m < 4; ++m) {
        int r = wm * 64 + m * 16 + l15;
        offA[m] = r * 64 + ((q4 ^ ((r >> 1) & 3)) * 16);  // XOR read swizzle (same involution)
        int rb = wn * 64 + m * 16 + l15;
        offB[m] = rb * 64 + ((q4 ^ ((rb >> 1) & 3)) * 16);
    }

    f32x4 acc[4][4];
    #pragma unroll
    for (int m = 0; m < 4; ++m)
        #pragma unroll
        for (int n = 0; n < 4; ++n) { f32x4 z = {0.f, 0.f, 0.f, 0.f}; acc[m][n] = z; }

    for (int kk = 0; kk < HS; kk += BK) {
        __syncthreads();
        #pragma unroll
        for (int q = 0; q < 2; ++q) {
            int i = 2 * wv + q;
            gl_lds16(XH   + baseA[q] + kk, (char*)Ah + i * 1024);
            gl_lds16(XL   + baseA[q] + kk, (char*)Al + i * 1024);
            gl_lds16(W1TH + baseB[q] + kk, (char*)Bh + i * 1024);
            gl_lds16(W1TL + baseB[q] + kk, (char*)Bl + i * 1024);
        }
        __syncthreads();   // compiler drains vmcnt before barrier -> staged data ready

        bf16x8 ah[4], al[4], bh[4], bl[4];
        #pragma unroll
        for (int m = 0; m < 4; ++m) {
            ah[m] = *(const bf16x8*)((const char*)Ah + offA[m]);
            al[m] = *(const bf16x8*)((const char*)Al + offA[m]);
            bh[m] = *(const bf16x8*)((const char*)Bh + offB[m]);
            bl[m] = *(const bf16x8*)((const char*)Bl + offB[m]);
        }
        #pragma unroll
        for (int m = 0; m < 4; ++m)
            #pragma unroll
            for (int n = 0; n < 4; ++n) {
                acc[m][n] = __builtin_amdgcn_mfma_f32_16x16x32_bf16(ah[m], bh[n], acc[m][n], 0, 0, 0);
                acc[m][n] = __builtin_amdgcn_mfma_f32_16x16x32_bf16(ah[m], bl[n], acc[m][n], 0, 0, 0);
                acc[m][n] = __builtin_amdgcn_mfma_f32_16x16x32_bf16(al[m], bh[n], acc[m][n], 0, 0, 0);
            }
    }

    // epilogue: gelu + hi/lo split, store H (slot-indexed, pads harmless)
    const int grow0 = mt * MT + wm * 64, colg0 = nt * MT + wn * 64;
    #pragma unroll
    for (int m = 0; m < 4; ++m)
        #pragma unroll
        for (int n = 0; n < 4; ++n)
            #pragma unroll
            for (int j = 0; j < 4; ++j) {
                int grow = grow0 + m * 16 + q4 * 4 + j;
                int col  = colg0 + n * 16 + l15;
                float v = gelu_exact(acc[m][n][j]);
                unsigned short h = f2bf(v);
                size_t o = (size_t)grow * FFN + col;
                HHo[o] = h;
                HLo[o] = f2bf(v - bf2f(h));
            }
}

// ---------------- grouped GEMM2: Y = H @ W2, split-K=2 ----------------
// Grid: 1-D, NB2 = (MT_MAX/8)*8*8 = 576 blocks; same XCD-affinity decode:
// the 8 (nt,ks) blocks of one mt are consecutive slots on ONE XCD.
__global__ __launch_bounds__(256, 3) void moe_gemm2(
    const unsigned short* __restrict__ HHi, const unsigned short* __restrict__ HLi,
    const unsigned short* __restrict__ W2TH, const unsigned short* __restrict__ W2TL,
    const int* __restrict__ offp, const int* __restrict__ mexp,
    float* __restrict__ YP0, float* __restrict__ YP1)
{
    const int xcd = blockIdx.x & 7;
    const int r_  = blockIdx.x >> 3;      // 0..71
    const int mtg = r_ >> 3;              // 0..8
    const int sub = r_ & 7;               // 0..7
    const int mt  = mtg * 8 + xcd;        // 0..71
    const int nt  = sub >> 1, ks = sub & 1;
    if (mt * MT >= offp[NE]) return;
    const int e = mexp[mt];
    const int t = threadIdx.x, lane = t & 63, wv = t >> 6;

    __shared__ __align__(16) short Ah[MT * BK], Al[MT * BK], Bh[MT * BK], Bl[MT * BK];

    int baseA[2], baseB[2];
    #pragma unroll
    for (int q = 0; q < 2; ++q) {
        int i = 2 * wv + q;
        int row = i * 16 + (lane >> 2);
        int cg = (lane & 3) ^ ((row >> 1) & 3);
        baseA[q] = (mt * MT + row) * FFN + cg * 8;          // identity rows (slot order)
        baseB[q] = (e * HS + nt * MT + row) * FFN + cg * 8;
    }

    const int wm = wv >> 1, wn = wv & 1, q4 = lane >> 4, l15 = lane & 15;
    int offA[4], offB[4];
    #pragma unroll
    for (int m = 0; m < 4; ++m) {
        int r = wm * 64 + m * 16 + l15;
        offA[m] = r * 64 + ((q4 ^ ((r >> 1) & 3)) * 16);
        int rb = wn * 64 + m * 16 + l15;
        offB[m] = rb * 64 + ((q4 ^ ((rb >> 1) & 3)) * 16);
    }

    f32x4 acc[4][4];
    #pragma unroll
    for (int m = 0; m < 4; ++m)
        #pragma unroll
        for (int n = 0; n < 4; ++n) { f32x4 z = {0.f, 0.f, 0.f, 0.f}; acc[m][n] = z; }

    const int k0 = ks * (FFN / 2), k1 = k0 + FFN / 2;
    for (int kk = k0; kk < k1; kk += BK) {
        __syncthreads();
        #pragma unroll
        for (int q = 0; q < 2; ++q) {
            int i = 2 * wv + q;
            gl_lds16(HHi  + baseA[q] + kk, (char*)Ah + i * 1024);
            gl_lds16(HLi  + baseA[q] + kk, (char*)Al + i * 1024);
            gl_lds16(W2TH + baseB[q] + kk, (char*)Bh + i * 1024);
            gl_lds16(W2TL + baseB[q] + kk, (char*)Bl + i * 1024);
        }
        __syncthreads();

        bf16x8 ah[4], al[4], bh[4], bl[4];
        #pragma unroll
        for (int m = 0; m < 4; ++m) {
            ah[m] = *(const bf16x8*)((const char*)Ah + offA[m]);
            al[m] = *(const bf16x8*)((const char*)Al + offA[m]);
            bh[m] = *(const bf16x8*)((const char*)Bh + offB[m]);
            bl[m] = *(const bf16x8*)((const char*)Bl + offB[m]);
        }
        #pragma unroll
        for (int m = 0; m < 4; ++m)
            #pragma unroll
            for (int n = 0; n < 4; ++n) {
                acc[m][n] = __builtin_amdgcn_mfma_f32_16x16x32_bf16(ah[m], bh[n], acc[m][n], 0, 0, 0);
                acc[m][n] = __builtin_amdgcn_mfma_f32_16x16x32_bf16(ah[m], bl[n], acc[m][n], 0, 0, 0);
                acc[m][n] = __builtin_amdgcn_mfma_f32_16x16x32_bf16(al[m], bh[n], acc[m][n], 0, 0, 0);
            }
    }

    float* YP = ks ? YP1 : YP0;
    const int grow0 = mt * MT + wm * 64, colg0 = nt * MT + wn * 64;
    #pragma unroll
    for (int m = 0; m < 4; ++m)
        #pragma unroll
        for (int n = 0; n < 4; ++n)
            #pragma unroll
            for (int j = 0; j < 4; ++j) {
                int grow = grow0 + m * 16 + q4 * 4 + j;
                int col  = colg0 + n * 16 + l15;
                YP[(size_t)grow * HS + col] = acc[m][n][j];
            }
}

// ---------------- combine ----------------
__global__ void moe_combine2(const float* __restrict__ YP0, const float* __restrict__ YP1,
                             const int* __restrict__ inv, const float* __restrict__ ew,
                             float* __restrict__ out) {
    int i = blockIdx.x * 256 + threadIdx.x;      // over T*HS/4 float4s
    if (i >= T_TOK * HS / 4) return;
    int tk = i >> 7, c4 = i & 127;
    int s0 = inv[2 * tk], s1 = inv[2 * tk + 1];
    float w0 = ew[2 * tk], w1 = ew[2 * tk + 1];
    const float4* p0 = reinterpret_cast<const float4*>(YP0);
    const float4* p1 = reinterpret_cast<const float4*>(YP1);
    float4 a0 = p0[(size_t)s0 * 128 + c4], b0 = p1[(size_t)s0 * 128 + c4];
    float4 a1 = p0[(size_t)s1 * 128 + c4], b1 = p1[(size_t)s1 * 128 + c4];
    float4 o;
    o.x = w0 * (a0.x + b0.x) + w1 * (a1.x + b1.x);
    o.y = w0 * (a0.y + b0.y) + w1 * (a1.y + b1.y);
    o.z = w0 * (a0.z + b0.z) + w1 * (a1.z + b1.z);
    o.w = w0 * (a0.w + b0.w) + w1 * (a1.w + b1.w);
    reinterpret_cast<float4*>(out)[i] = o;
}

// ================= fallback VALU path (proven baseline) =================
#define FB_BM 32
#define FB_BJ 128
#define FB_CK 256
#define FB_XSTR (FB_CK+4)
#define FB_HSTR (FB_BJ+4)

__global__ void fb_init(int* cnt) { int i = threadIdx.x; if (i < NE) cnt[i] = 0; }

__global__ void fb_scatter(const int* __restrict__ eidx, int* cnt, int* bucket) {
    int a = blockIdx.x * 256 + threadIdx.x;
    if (a < NA) { int e = eidx[a]; int p = atomicAdd(&cnt[e], 1); bucket[e * NA + p] = a; }
}

__global__ __launch_bounds__(256, 1) void fb_fused(
    const float* __restrict__ x, const float* __restrict__ w1, const float* __restrict__ w2,
    const int* __restrict__ cnt, const int* __restrict__ bucket, float* __restrict__ ybuf)
{
    const int bid = blockIdx.x;
    const int e = bid & (NE - 1), tr = bid >> 3;
    const int n_e = cnt[e], rbase = tr * FB_BM;
    if (rbase >= n_e) return;
    const int t = threadIdx.x;
    __shared__ __align__(16) float Xc[FB_BM][FB_XSTR];
    __shared__ __align__(16) float Hsh[FB_BM][FB_HSTR];
    __shared__ int rowa[FB_BM];
    if (t < FB_BM) { int r = rbase + t; rowa[t] = (r < n_e) ? bucket[e * NA + r] : -1; }
    __syncthreads();
    const int cg = t & 15, rg = t >> 4, r0 = rg * 2;
    float yac[2][32];
    #pragma unroll
    for (int u = 0; u < 2; ++u)
        #pragma unroll
        for (int v = 0; v < 32; ++v) yac[u][v] = 0.0f;
    const float* w1e = w1 + (size_t)e * HS * FFN;
    const float* w2e = w2 + (size_t)e * FFN * HS;
    for (int jp = 0; jp < FFN; jp += FB_BJ) {
        float hac[2][8];
        #pragma unroll
        for (int u = 0; u < 2; ++u)
            #pragma unroll
            for (int v = 0; v < 8; ++v) hac[u][v] = 0.0f;
        for (int ic = 0; ic < HS; ic += FB_CK) {
            __syncthreads();
            #pragma unroll
            for (int q = 0; q < (FB_BM * FB_CK / 4) / 256; ++q) {
                int id = t + 256 * q, rr = id >> 6, c4 = id & 63;
                int a = rowa[rr];
                float4 val = make_float4(0.f, 0.f, 0.f, 0.f);
                if (a >= 0) val = *reinterpret_cast<const float4*>(x + (size_t)(a >> 1) * HS + ic + c4 * 4);
                *reinterpret_cast<float4*>(&Xc[rr][c4 * 4]) = val;
            }
            __syncthreads();
            const float* w1p = w1e + (size_t)ic * FFN + jp + cg * 8;
            #pragma unroll 2
            for (int i4 = 0; i4 < FB_CK; i4 += 4) {
                float4 xa = *reinterpret_cast<const float4*>(&Xc[r0][i4]);
                float4 xb = *reinterpret_cast<const float4*>(&Xc[r0 + 1][i4]);
                const float* wr0 = w1p + (size_t)i4 * FFN;
                #pragma unroll
                for (int ii = 0; ii < 4; ++ii) {
                    float4 wa = *reinterpret_cast<const float4*>(wr0 + (size_t)ii * FFN);
                    float4 wb = *reinterpret_cast<const float4*>(wr0 + (size_t)ii * FFN + 4);
                    float x0 = (ii == 0) ? xa.x : (ii == 1) ? xa.y : (ii == 2) ? xa.z : xa.w;
                    float x1 = (ii == 0) ? xb.x : (ii == 1) ? xb.y : (ii == 2) ? xb.z : xb.w;
                    hac[0][0] = fmaf(x0, wa.x, hac[0][0]); hac[0][1] = fmaf(x0, wa.y, hac[0][1]);
                    hac[0][2] = fmaf(x0, wa.z, hac[0][2]); hac[0][3] = fmaf(x0, wa.w, hac[0][3]);
                    hac[0][4] = fmaf(x0, wb.x, hac[0][4]); hac[0][5] = fmaf(x0, wb.y, hac[0][5]);
                    hac[0][6] = fmaf(x0, wb.z, hac[0][6]); hac[0][7] = fmaf(x0, wb.w, hac[0][7]);
                    hac[1][0] = fmaf(x1, wa.x, hac[1][0]); hac[1][1] = fmaf(x1, wa.y, hac[1][1]);
                    hac[1][2] = fmaf(x1, wa.z, hac[1][2]); hac[1][3] = fmaf(x1, wa.w, hac[1][3]);
                    hac[1][4] = fmaf(x1, wb.x, hac[1][4]); hac[1][5] = fmaf(x1, wb.y, hac[1][5]);
                    hac[1][6] = fmaf(x1, wb.z, hac[1][6]); hac[1][7] = fmaf(x1, wb.w, hac[1][7]);
                }
            }
        }
        #pragma unroll
        for (int u = 0; u < 2; ++u)
            #pragma unroll
            for (int v = 0; v < 8; ++v) Hsh[r0 + u][cg * 8 + v] = gelu_exact(hac[u][v]);
        __syncthreads();
        const float* w2p = w2e + (size_t)jp * HS + cg * 32;
        #pragma unroll 2
        for (int j = 0; j < FB_BJ; ++j) {
            float h0 = Hsh[r0][j], h1 = Hsh[r0 + 1][j];
            const float* wr = w2p + (size_t)j * HS;
            #pragma unroll
            for (int q = 0; q < 8; ++q) {
                float4 w4 = *reinterpret_cast<const float4*>(wr + q * 4);
                yac[0][q * 4 + 0] = fmaf(h0, w4.x, yac[0][q * 4 + 0]);
                yac[0][q * 4 + 1] = fmaf(h0, w4.y, yac[0][q * 4 + 1]);
                yac[0][q * 4 + 2] = fmaf(h0, w4.z, yac[0][q * 4 + 2]);
                yac[0][q * 4 + 3] = fmaf(h0, w4.w, yac[0][q * 4 + 3]);
                yac[1][q * 4 + 0] = fmaf(h1, w4.x, yac[1][q * 4 + 0]);
                yac[1][q * 4 + 1] = fmaf(h1, w4.y, yac[1][q * 4 + 1]);
                yac[1][q * 4 + 2] = fmaf(h1, w4.z, yac[1][q * 4 + 2]);
                yac[1][q * 4 + 3] = fmaf(h1, w4.w, yac[1][q * 4 + 3]);
            }
        }
    }
    #pragma unroll
    for (int u = 0; u < 2; ++u) {
        int a = rowa[r0 + u];
        if (a >= 0) {
            float* yp = ybuf + (size_t)a * HS + cg * 32;
            #pragma unroll
            for (int q = 0; q < 8; ++q) {
                float4 o = make_float4(yac[u][q * 4 + 0], yac[u][q * 4 + 1],
                                       yac[u][q * 4 + 2], yac[u][q * 4 + 3]);
                *reinterpret_cast<float4*>(yp + q * 4) = o;
            }
        }
    }
}

__global__ void fb_combine(const float* __restrict__ ybuf, const float* __restrict__ ew,
                           float* __restrict__ out) {
    int i = blockIdx.x * 256 + threadIdx.x;
    if (i >= T_TOK * HS / 4) return;
    int tk = i >> 7, c4 = i & 127;
    float wA = ew[2 * tk], wB = ew[2 * tk + 1];
    const float4* y4 = reinterpret_cast<const float4*>(ybuf);
    float4 a = y4[(size_t)(2 * tk) * (HS / 4) + c4];
    float4 b = y4[(size_t)(2 * tk + 1) * (HS / 4) + c4];
    float4 o;
    o.x = wA * a.x + wB * b.x; o.y = wA * a.y + wB * b.y;
    o.z = wA * a.z + wB * b.z; o.w = wA * a.w + wB * b.w;
    reinterpret_cast<float4*>(out)[i] = o;
}

// ================= launch =================
extern "C" void kernel_launch(void* const* d_in, const int* in_sizes, int n_in,
                              void* d_out, int out_size, void* d_ws, size_t ws_size,
                              hipStream_t stream) {
    const float* x  = (const float*)d_in[0];
    const float* ew = (const float*)d_in[1];
    const int*   ei = (const int*)d_in[2];
    const float* w1 = (const float*)d_in[3];
    const float* w2 = (const float*)d_in[4];
    float* out = (float*)d_out;
    char* W = (char*)d_ws;

    if (ws_size < WS_NEED) {
        // fallback: proven fp32 VALU path (16.5MB ws)
        int* cnt = (int*)d_ws;
        int* bucket = cnt + 64;
        float* ybuf = (float*)(W + (1 << 19));
        fb_init<<<1, 64, 0, stream>>>(cnt);
        fb_scatter<<<NA / 256, 256, 0, stream>>>(ei, cnt, bucket);
        fb_fused<<<NE * (NA / FB_BM), 256, 0, stream>>>(x, w1, w2, cnt, bucket, ybuf);
        fb_combine<<<(T_TOK * HS / 4 + 255) / 256, 256, 0, stream>>>(ybuf, ew, out);
        return;
    }

    int* cnt   = (int*)(W + WS_CNT);
    int* cnt2  = (int*)(W + WS_CNT2);
    int* offp  = (int*)(W + WS_OFF);
    int* mexp  = (int*)(W + WS_MEXP);
    int* slots = (int*)(W + WS_SLOTS);
    int* inv   = (int*)(W + WS_INV);
    unsigned short* XH   = (unsigned short*)(W + WS_XH);
    unsigned short* XL   = (unsigned short*)(W + WS_XL);
    unsigned short* W1TH = (unsigned short*)(W + WS_W1TH);
    unsigned short* W1TL = (unsigned short*)(W + WS_W1TL);
    unsigned short* W2TH = (unsigned short*)(W + WS_W2TH);
    unsigned short* W2TL = (unsigned short*)(W + WS_W2TL);
    unsigned short* HH   = (unsigned short*)(W + WS_HH);
    unsigned short* HL   = (unsigned short*)(W + WS_HL);
    float* YP0 = (float*)(W + WS_YP0);
    float* YP1 = (float*)(W + WS_YP1);

    moe_setup_init<<<(SLOT_CAP + 255) / 256, 256, 0, stream>>>(cnt, cnt2, slots);
    moe_count<<<NA / 256, 256, 0, stream>>>(ei, cnt);
    moe_offsets<<<1, 64, 0, stream>>>(cnt, offp, mexp);
    moe_fill<<<NA / 256, 256, 0, stream>>>(ei, offp, cnt2, slots, inv);

    split_x<<<(T_TOK * HS / 4) / 256, 256, 0, stream>>>(x, XH, XL);
    transpose_split<<<dim3(HS / 32, FFN / 32, NE), 256, 0, stream>>>(w1, W1TH, W1TL, HS, FFN);
    transpose_split<<<dim3(FFN / 32, HS / 32, NE), 256, 0, stream>>>(w2, W2TH, W2TL, FFN, HS);

    // XCD-affinity 1-D grids (see decode in kernels)
    moe_gemm1<<<(MT_MAX / 8) * 8 * 16, 256, 0, stream>>>(XH, XL, W1TH, W1TL, offp, mexp, slots, HH, HL);
    moe_gemm2<<<(MT_MAX / 8) * 8 * 8, 256, 0, stream>>>(HH, HL, W2TH, W2TL, offp, mexp, YP0, YP1);
    moe_combine2<<<(T_TOK * HS / 4) / 256, 256, 0, stream>>>(YP0, YP1, inv, ew, out);
}

// Round 6
// 221.748 us; speedup vs baseline: 22.4858x; 1.2527x over previous
//
#include <hip/hip_runtime.h>
#include <stdint.h>

#define T_TOK 4096
#define KTOP  2
#define HS    512
#define FFN   2048
#define NE    8
#define NA    (T_TOK*KTOP)     // 8192 assignments
#define MT    128              // M-tile (rows per gemm block)
#define BK    32               // K-step
#define MT_MAX 72              // 8 XCD chunks x 9
#define SLOT_CAP (MT_MAX*MT)   // 9216
#define PSTR 68                // epilogue LDS f32 stride (16B rows, <=2-way banks)

// ---------------- workspace layout (bytes) ----------------
#define WS_CNT2  64u
#define WS_OFF   128u
#define WS_MEXP  256u
#define WS_SLOTS 1024u
#define WS_INV   40960u
#define MB_ (1024ull*1024ull)
#define WS_XH   (1*MB_)
#define WS_XL   (5*MB_)
#define WS_W2TH (9*MB_)
#define WS_W2TL (25*MB_)
#define WS_HH   (41*MB_)
#define WS_HL   (77*MB_)
#define WS_W1TH (113*MB_)
#define WS_W1TL (129*MB_)
#define WS_YP0  (113*MB_)      // overlays W1T (dead after gemm1)
#define WS_YP1  (131*MB_)
#define WS_NEED (149*MB_)

typedef short bf16x8 __attribute__((ext_vector_type(8)));
typedef float f32x4  __attribute__((ext_vector_type(4)));

__device__ __forceinline__ unsigned short f2bf(float f) {
    unsigned u = __builtin_bit_cast(unsigned, f);
    u += 0x7fffu + ((u >> 16) & 1u);          // RNE
    return (unsigned short)(u >> 16);
}
__device__ __forceinline__ float bf2f(unsigned short h) {
    return __builtin_bit_cast(float, (unsigned)h << 16);
}
__device__ __forceinline__ float gelu_exact(float v) {
    return 0.5f * v * (1.0f + erff(v * 0.70710678118654752f));
}
__device__ __forceinline__ void gl_lds16(const void* g, void* l) {
    __builtin_amdgcn_global_load_lds(
        (const __attribute__((address_space(1))) unsigned int*)g,
        (__attribute__((address_space(3))) unsigned int*)l, 16, 0, 0);
}

// ---------------- merged prep: split_x + w1T-split + w2T-split + slots-init ----------------
// grid ranges: [0,2048) split_x | [2048,10240) w1T | [10240,18432) w2T | [18432,18468) slots=-1
// NO intra-kernel producer/consumer: every range writes disjoint data consumed
// only by LATER kernels (stream-ordered). (R5's init/count race is gone.)
__device__ __forceinline__ void transpose_split_body(
    const float* __restrict__ src, unsigned short* __restrict__ dh,
    unsigned short* __restrict__ dl, int R, int C, int e, int kb, int nb, int t,
    float (*tile)[33])
{
    const int k0 = kb * 32, n0 = nb * 32;
    #pragma unroll
    for (int q = 0; q < 4; ++q) {
        int idx = t + q * 256, kk = idx >> 5, nn = idx & 31;
        tile[kk][nn] = src[((size_t)e * R + k0 + kk) * C + n0 + nn];
    }
    __syncthreads();
    #pragma unroll
    for (int q = 0; q < 4; ++q) {
        int idx = t + q * 256, nn = idx >> 5, kk = idx & 31;
        float v = tile[kk][nn];
        unsigned short h = f2bf(v);
        unsigned short l = f2bf(v - bf2f(h));
        size_t o = ((size_t)e * C + n0 + nn) * R + k0 + kk;
        dh[o] = h; dl[o] = l;
    }
}

__global__ void moe_prep(int* slots,
                         const float* __restrict__ x,
                         unsigned short* __restrict__ xh, unsigned short* __restrict__ xl,
                         const float* __restrict__ w1,
                         unsigned short* __restrict__ w1th, unsigned short* __restrict__ w1tl,
                         const float* __restrict__ w2,
                         unsigned short* __restrict__ w2th, unsigned short* __restrict__ w2tl)
{
    __shared__ float tile[32][33];
    const int bid = blockIdx.x, t = threadIdx.x;
    if (bid < 2048) {                         // split_x over T*HS/4 float4s
        int i = bid * 256 + t;
        float4 v = reinterpret_cast<const float4*>(x)[i];
        unsigned short h0 = f2bf(v.x), h1 = f2bf(v.y), h2 = f2bf(v.z), h3 = f2bf(v.w);
        unsigned short l0 = f2bf(v.x - bf2f(h0)), l1 = f2bf(v.y - bf2f(h1));
        unsigned short l2 = f2bf(v.z - bf2f(h2)), l3 = f2bf(v.w - bf2f(h3));
        uint2 vh = { (unsigned)h0 | ((unsigned)h1 << 16), (unsigned)h2 | ((unsigned)h3 << 16) };
        uint2 vl = { (unsigned)l0 | ((unsigned)l1 << 16), (unsigned)l2 | ((unsigned)l3 << 16) };
        reinterpret_cast<uint2*>(xh)[i] = vh;
        reinterpret_cast<uint2*>(xl)[i] = vl;
    } else if (bid < 10240) {                 // w1 [e][HS][FFN] -> [e][FFN][HS]
        int lin = bid - 2048, e = lin >> 10, rem = lin & 1023;
        transpose_split_body(w1, w1th, w1tl, HS, FFN, e, rem & 15, rem >> 4, t, tile);
    } else if (bid < 18432) {                 // w2 [e][FFN][HS] -> [e][HS][FFN]
        int lin = bid - 10240, e = lin >> 10, rem = lin & 1023;
        transpose_split_body(w2, w2th, w2tl, FFN, HS, e, rem & 63, rem >> 6, t, tile);
    } else {                                  // slots = -1 (poison-safe each call)
        int gid = (bid - 18432) * 256 + t;
        if (gid < SLOT_CAP) slots[gid] = -1;
    }
}

// single block: histogram (LDS atomics) + offsets + mexp + zero cnt2
__global__ void moe_offsets(const int* __restrict__ eidx, int* off, int* mexp, int* cnt2) {
    __shared__ int h[NE];
    const int t = threadIdx.x;
    if (t < NE) h[t] = 0;
    __syncthreads();
    for (int a = t; a < NA; a += 256) atomicAdd(&h[eidx[a]], 1);
    __syncthreads();
    if (t < NE) cnt2[t] = 0;
    if (t == 0) {
        int run = 0;
        for (int e = 0; e < NE; ++e) {
            off[e] = run;
            int nt = (h[e] + MT - 1) / MT;
            for (int i = 0; i < nt; ++i) mexp[run / MT + i] = e;
            run += nt * MT;
        }
        off[NE] = run;
        for (int m = run / MT; m < MT_MAX; ++m) mexp[m] = 0;
    }
}

__global__ void moe_fill(const int* __restrict__ eidx, const int* __restrict__ off,
                         int* cnt2, int* slots, int* inv) {
    int a = blockIdx.x * 256 + threadIdx.x;
    if (a < NA) {
        int e = eidx[a];
        int p = atomicAdd(&cnt2[e], 1);
        int s = off[e] + p;
        slots[s] = a;        // order nondeterministic; per-assignment result isn't
        inv[a] = s;
    }
}

// ---------------- grouped GEMM1: H = gelu(X @ W1) -> bf16 hi/lo ----------------
// Grid 1152. Chunked XCD affinity: xcd = bid&7 owns mt in [xcd*9, xcd*9+9) ->
// same-expert W1T panels stay in one XCD's L2; mtg-fast order shares B panels.
__global__ __launch_bounds__(256, 4) void moe_gemm1(
    const unsigned short* __restrict__ XH, const unsigned short* __restrict__ XL,
    const unsigned short* __restrict__ W1TH, const unsigned short* __restrict__ W1TL,
    const int* __restrict__ offp, const int* __restrict__ mexp,
    const int* __restrict__ slots,
    unsigned short* __restrict__ HHo, unsigned short* __restrict__ HLo)
{
    const int xcd = blockIdx.x & 7;
    const int part = blockIdx.x >> 3;     // 0..143
    const int mtg = part % 9;             // fast -> concurrent blocks share nt (B panel)
    const int nt  = part / 9;             // 0..15
    const int mt  = xcd * 9 + mtg;        // 0..71 contiguous per XCD
    if (mt * MT >= offp[NE]) return;
    const int e = mexp[mt];
    const int t = threadIdx.x, lane = t & 63, wv = t >> 6;

    __shared__ __align__(16) char POOL[MT * PSTR * 4];   // 34816B: staging (32KB) U epilogue f32
    __shared__ int srow[MT];
    short* Ah = (short*)POOL;
    short* Al = (short*)(POOL + 8192);
    short* Bh = (short*)(POOL + 16384);
    short* Bl = (short*)(POOL + 24576);
    float* Pf = (float*)POOL;

    if (t < MT) { int s = slots[mt * MT + t]; srow[t] = (s < 0) ? 0 : (s >> 1); }
    __syncthreads();

    int baseA[2], baseB[2];
    #pragma unroll
    for (int q = 0; q < 2; ++q) {
        int i = 2 * wv + q;
        int row = i * 16 + (lane >> 2);
        int cg = (lane & 3) ^ ((row >> 1) & 3);          // XOR source swizzle
        baseA[q] = srow[row] * HS + cg * 8;
        baseB[q] = (e * FFN + nt * MT + row) * HS + cg * 8;
    }

    const int wm = wv >> 1, wn = wv & 1, q4 = lane >> 4, l15 = lane & 15;
    int offA[4], offB[4];
    #pragma unroll
    for (int m = 0; m < 4; ++m) {
        int r = wm * 64 + m * 16 + l15;
        offA[m] = r * 64 + ((q4 ^ ((r >> 1) & 3)) * 16);  // XOR read swizzle (same involution)
        int rb = wn * 64 + m * 16 + l15;
        offB[m] = rb * 64 + ((q4 ^ ((rb >> 1) & 3)) * 16);
    }

    f32x4 acc[4][4];
    #pragma unroll
    for (int m = 0; m < 4; ++m)
        #pragma unroll
        for (int n = 0; n < 4; ++n) { f32x4 z = {0.f, 0.f, 0.f, 0.f}; acc[m][n] = z; }

    for (int kk = 0; kk < HS; kk += BK) {
        __syncthreads();
        #pragma unroll
        for (int q = 0; q < 2; ++q) {
            int i = 2 * wv + q;
            gl_lds16(XH   + baseA[q] + kk, (char*)Ah + i * 1024);
            gl_lds16(XL   + baseA[q] + kk, (char*)Al + i * 1024);
            gl_lds16(W1TH + baseB[q] + kk, (char*)Bh + i * 1024);
            gl_lds16(W1TL + baseB[q] + kk, (char*)Bl + i * 1024);
        }
        __syncthreads();   // compiler drains vmcnt before barrier -> staged data ready

        bf16x8 ah[4], al[4], bh[4], bl[4];
        #pragma unroll
        for (int m = 0; m < 4; ++m) {
            ah[m] = *(const bf16x8*)((const char*)Ah + offA[m]);
            al[m] = *(const bf16x8*)((const char*)Al + offA[m]);
            bh[m] = *(const bf16x8*)((const char*)Bh + offB[m]);
            bl[m] = *(const bf16x8*)((const char*)Bl + offB[m]);
        }
        #pragma unroll
        for (int m = 0; m < 4; ++m)
            #pragma unroll
            for (int n = 0; n < 4; ++n) {
                acc[m][n] = __builtin_amdgcn_mfma_f32_16x16x32_bf16(ah[m], bh[n], acc[m][n], 0, 0, 0);
                acc[m][n] = __builtin_amdgcn_mfma_f32_16x16x32_bf16(ah[m], bl[n], acc[m][n], 0, 0, 0);
                acc[m][n] = __builtin_amdgcn_mfma_f32_16x16x32_bf16(al[m], bh[n], acc[m][n], 0, 0, 0);
            }
    }

    // epilogue: LDS-transpose to coalesced bf16x8 stores; gelu+split in read phase
    #pragma unroll
    for (int half = 0; half < 2; ++half) {
        __syncthreads();
        if (wn == half) {
            #pragma unroll
            for (int m = 0; m < 4; ++m)
                #pragma unroll
                for (int n = 0; n < 4; ++n)
                    #pragma unroll
                    for (int j = 0; j < 4; ++j)
                        Pf[(wm * 64 + m * 16 + q4 * 4 + j) * PSTR + n * 16 + l15] = acc[m][n][j];
        }
        __syncthreads();
        #pragma unroll
        for (int q = 0; q < 4; ++q) {
            int seg = q * 256 + t;                 // 1024 segs: 128 rows x 8
            int row = seg >> 3, c8 = (seg & 7) << 3;
            const float* p = Pf + row * PSTR + c8;
            float4 a = *(const float4*)p, b = *(const float4*)(p + 4);
            float va[8] = {a.x, a.y, a.z, a.w, b.x, b.y, b.z, b.w};
            bf16x8 ph, pl;
            #pragma unroll
            for (int i = 0; i < 8; ++i) {
                float g = gelu_exact(va[i]);
                unsigned short h = f2bf(g);
                ph[i] = (short)h;
                pl[i] = (short)f2bf(g - bf2f(h));
            }
            size_t o = (size_t)(mt * MT + row) * FFN + nt * MT + half * 64 + c8;
            *(bf16x8*)(HHo + o) = ph;
            *(bf16x8*)(HLo + o) = pl;
        }
    }
}

// ---------------- grouped GEMM2: Y = H @ W2, split-K=2 ----------------
// Grid 576; same chunked-XCD decode (mtg fast -> shared (nt,ks) B panel per XCD).
__global__ __launch_bounds__(256, 4) void moe_gemm2(
    const unsigned short* __restrict__ HHi, const unsigned short* __restrict__ HLi,
    const unsigned short* __restrict__ W2TH, const unsigned short* __restrict__ W2TL,
    const int* __restrict__ offp, const int* __restrict__ mexp,
    float* __restrict__ YP0, float* __restrict__ YP1)
{
    const int xcd = blockIdx.x & 7;
    const int part = blockIdx.x >> 3;     // 0..71
    const int mtg = part % 9;
    const int sub = part / 9;             // 0..7
    const int mt  = xcd * 9 + mtg;
    const int nt  = sub >> 1, ks = sub & 1;
    if (mt * MT >= offp[NE]) return;
    const int e = mexp[mt];
    const int t = threadIdx.x, lane = t & 63, wv = t >> 6;

    __shared__ __align__(16) char POOL[MT * PSTR * 4];
    short* Ah = (short*)POOL;
    short* Al = (short*)(POOL + 8192);
    short* Bh = (short*)(POOL + 16384);
    short* Bl = (short*)(POOL + 24576);
    float* Pf = (float*)POOL;

    int baseA[2], baseB[2];
    #pragma unroll
    for (int q = 0; q < 2; ++q) {
        int i = 2 * wv + q;
        int row = i * 16 + (lane >> 2);
        int cg = (lane & 3) ^ ((row >> 1) & 3);
        baseA[q] = (mt * MT + row) * FFN + cg * 8;
        baseB[q] = (e * HS + nt * MT + row) * FFN + cg * 8;
    }

    const int wm = wv >> 1, wn = wv & 1, q4 = lane >> 4, l15 = lane & 15;
    int offA[4], offB[4];
    #pragma unroll
    for (int m = 0; m < 4; ++m) {
        int r = wm * 64 + m * 16 + l15;
        offA[m] = r * 64 + ((q4 ^ ((r >> 1) & 3)) * 16);
        int rb = wn * 64 + m * 16 + l15;
        offB[m] = rb * 64 + ((q4 ^ ((rb >> 1) & 3)) * 16);
    }

    f32x4 acc[4][4];
    #pragma unroll
    for (int m = 0; m < 4; ++m)
        #pragma unroll
        for (int n = 0; n < 4; ++n) { f32x4 z = {0.f, 0.f, 0.f, 0.f}; acc[m][n] = z; }

    const int k0 = ks * (FFN / 2), k1 = k0 + FFN / 2;
    for (int kk = k0; kk < k1; kk += BK) {
        __syncthreads();
        #pragma unroll
        for (int q = 0; q < 2; ++q) {
            int i = 2 * wv + q;
            gl_lds16(HHi  + baseA[q] + kk, (char*)Ah + i * 1024);
            gl_lds16(HLi  + baseA[q] + kk, (char*)Al + i * 1024);
            gl_lds16(W2TH + baseB[q] + kk, (char*)Bh + i * 1024);
            gl_lds16(W2TL + baseB[q] + kk, (char*)Bl + i * 1024);
        }
        __syncthreads();

        bf16x8 ah[4], al[4], bh[4], bl[4];
        #pragma unroll
        for (int m = 0; m < 4; ++m) {
            ah[m] = *(const bf16x8*)((const char*)Ah + offA[m]);
            al[m] = *(const bf16x8*)((const char*)Al + offA[m]);
            bh[m] = *(const bf16x8*)((const char*)Bh + offB[m]);
            bl[m] = *(const bf16x8*)((const char*)Bl + offB[m]);
        }
        #pragma unroll
        for (int m = 0; m < 4; ++m)
            #pragma unroll
            for (int n = 0; n < 4; ++n) {
                acc[m][n] = __builtin_amdgcn_mfma_f32_16x16x32_bf16(ah[m], bh[n], acc[m][n], 0, 0, 0);
                acc[m][n] = __builtin_amdgcn_mfma_f32_16x16x32_bf16(ah[m], bl[n], acc[m][n], 0, 0, 0);
                acc[m][n] = __builtin_amdgcn_mfma_f32_16x16x32_bf16(al[m], bh[n], acc[m][n], 0, 0, 0);
            }
    }

    float* YP = ks ? YP1 : YP0;
    #pragma unroll
    for (int half = 0; half < 2; ++half) {
        __syncthreads();
        if (wn == half) {
            #pragma unroll
            for (int m = 0; m < 4; ++m)
                #pragma unroll
                for (int n = 0; n < 4; ++n)
                    #pragma unroll
                    for (int j = 0; j < 4; ++j)
                        Pf[(wm * 64 + m * 16 + q4 * 4 + j) * PSTR + n * 16 + l15] = acc[m][n][j];
        }
        __syncthreads();
        #pragma unroll
        for (int q = 0; q < 4; ++q) {
            int seg = q * 256 + t;
            int row = seg >> 3, c8 = (seg & 7) << 3;
            const float* p = Pf + row * PSTR + c8;
            float4 a = *(const float4*)p, b = *(const float4*)(p + 4);
            float* d = YP + (size_t)(mt * MT + row) * HS + nt * MT + half * 64 + c8;
            *(float4*)d = a;
            *(float4*)(d + 4) = b;
        }
    }
}

// ---------------- combine ----------------
__global__ void moe_combine2(const float* __restrict__ YP0, const float* __restrict__ YP1,
                             const int* __restrict__ inv, const float* __restrict__ ew,
                             float* __restrict__ out) {
    int i = blockIdx.x * 256 + threadIdx.x;      // over T*HS/4 float4s
    if (i >= T_TOK * HS / 4) return;
    int tk = i >> 7, c4 = i & 127;
    int s0 = inv[2 * tk], s1 = inv[2 * tk + 1];
    float w0 = ew[2 * tk], w1 = ew[2 * tk + 1];
    const float4* p0 = reinterpret_cast<const float4*>(YP0);
    const float4* p1 = reinterpret_cast<const float4*>(YP1);
    float4 a0 = p0[(size_t)s0 * 128 + c4], b0 = p1[(size_t)s0 * 128 + c4];
    float4 a1 = p0[(size_t)s1 * 128 + c4], b1 = p1[(size_t)s1 * 128 + c4];
    float4 o;
    o.x = w0 * (a0.x + b0.x) + w1 * (a1.x + b1.x);
    o.y = w0 * (a0.y + b0.y) + w1 * (a1.y + b1.y);
    o.z = w0 * (a0.z + b0.z) + w1 * (a1.z + b1.z);
    o.w = w0 * (a0.w + b0.w) + w1 * (a1.w + b1.w);
    reinterpret_cast<float4*>(out)[i] = o;
}

// ================= fallback VALU path (proven baseline) =================
#define FB_BM 32
#define FB_BJ 128
#define FB_CK 256
#define FB_XSTR (FB_CK+4)
#define FB_HSTR (FB_BJ+4)

__global__ void fb_init(int* cnt) { int i = threadIdx.x; if (i < NE) cnt[i] = 0; }

__global__ void fb_scatter(const int* __restrict__ eidx, int* cnt, int* bucket) {
    int a = blockIdx.x * 256 + threadIdx.x;
    if (a < NA) { int e = eidx[a]; int p = atomicAdd(&cnt[e], 1); bucket[e * NA + p] = a; }
}

__global__ __launch_bounds__(256, 1) void fb_fused(
    const float* __restrict__ x, const float* __restrict__ w1, const float* __restrict__ w2,
    const int* __restrict__ cnt, const int* __restrict__ bucket, float* __restrict__ ybuf)
{
    const int bid = blockIdx.x;
    const int e = bid & (NE - 1), tr = bid >> 3;
    const int n_e = cnt[e], rbase = tr * FB_BM;
    if (rbase >= n_e) return;
    const int t = threadIdx.x;
    __shared__ __align__(16) float Xc[FB_BM][FB_XSTR];
    __shared__ __align__(16) float Hsh[FB_BM][FB_HSTR];
    __shared__ int rowa[FB_BM];
    if (t < FB_BM) { int r = rbase + t; rowa[t] = (r < n_e) ? bucket[e * NA + r] : -1; }
    __syncthreads();
    const int cg = t & 15, rg = t >> 4, r0 = rg * 2;
    float yac[2][32];
    #pragma unroll
    for (int u = 0; u < 2; ++u)
        #pragma unroll
        for (int v = 0; v < 32; ++v) yac[u][v] = 0.0f;
    const float* w1e = w1 + (size_t)e * HS * FFN;
    const float* w2e = w2 + (size_t)e * FFN * HS;
    for (int jp = 0; jp < FFN; jp += FB_BJ) {
        float hac[2][8];
        #pragma unroll
        for (int u = 0; u < 2; ++u)
            #pragma unroll
            for (int v = 0; v < 8; ++v) hac[u][v] = 0.0f;
        for (int ic = 0; ic < HS; ic += FB_CK) {
            __syncthreads();
            #pragma unroll
            for (int q = 0; q < (FB_BM * FB_CK / 4) / 256; ++q) {
                int id = t + 256 * q, rr = id >> 6, c4 = id & 63;
                int a = rowa[rr];
                float4 val = make_float4(0.f, 0.f, 0.f, 0.f);
                if (a >= 0) val = *reinterpret_cast<const float4*>(x + (size_t)(a >> 1) * HS + ic + c4 * 4);
                *reinterpret_cast<float4*>(&Xc[rr][c4 * 4]) = val;
            }
            __syncthreads();
            const float* w1p = w1e + (size_t)ic * FFN + jp + cg * 8;
            #pragma unroll 2
            for (int i4 = 0; i4 < FB_CK; i4 += 4) {
                float4 xa = *reinterpret_cast<const float4*>(&Xc[r0][i4]);
                float4 xb = *reinterpret_cast<const float4*>(&Xc[r0 + 1][i4]);
                const float* wr0 = w1p + (size_t)i4 * FFN;
                #pragma unroll
                for (int ii = 0; ii < 4; ++ii) {
                    float4 wa = *reinterpret_cast<const float4*>(wr0 + (size_t)ii * FFN);
                    float4 wb = *reinterpret_cast<const float4*>(wr0 + (size_t)ii * FFN + 4);
                    float x0 = (ii == 0) ? xa.x : (ii == 1) ? xa.y : (ii == 2) ? xa.z : xa.w;
                    float x1 = (ii == 0) ? xb.x : (ii == 1) ? xb.y : (ii == 2) ? xb.z : xb.w;
                    hac[0][0] = fmaf(x0, wa.x, hac[0][0]); hac[0][1] = fmaf(x0, wa.y, hac[0][1]);
                    hac[0][2] = fmaf(x0, wa.z, hac[0][2]); hac[0][3] = fmaf(x0, wa.w, hac[0][3]);
                    hac[0][4] = fmaf(x0, wb.x, hac[0][4]); hac[0][5] = fmaf(x0, wb.y, hac[0][5]);
                    hac[0][6] = fmaf(x0, wb.z, hac[0][6]); hac[0][7] = fmaf(x0, wb.w, hac[0][7]);
                    hac[1][0] = fmaf(x1, wa.x, hac[1][0]); hac[1][1] = fmaf(x1, wa.y, hac[1][1]);
                    hac[1][2] = fmaf(x1, wa.z, hac[1][2]); hac[1][3] = fmaf(x1, wa.w, hac[1][3]);
                    hac[1][4] = fmaf(x1, wb.x, hac[1][4]); hac[1][5] = fmaf(x1, wb.y, hac[1][5]);
                    hac[1][6] = fmaf(x1, wb.z, hac[1][6]); hac[1][7] = fmaf(x1, wb.w, hac[1][7]);
                }
            }
        }
        #pragma unroll
        for (int u = 0; u < 2; ++u)
            #pragma unroll
            for (int v = 0; v < 8; ++v) Hsh[r0 + u][cg * 8 + v] = gelu_exact(hac[u][v]);
        __syncthreads();
        const float* w2p = w2e + (size_t)jp * HS + cg * 32;
        #pragma unroll 2
        for (int j = 0; j < FB_BJ; ++j) {
            float h0 = Hsh[r0][j], h1 = Hsh[r0 + 1][j];
            const float* wr = w2p + (size_t)j * HS;
            #pragma unroll
            for (int q = 0; q < 8; ++q) {
                float4 w4 = *reinterpret_cast<const float4*>(wr + q * 4);
                yac[0][q * 4 + 0] = fmaf(h0, w4.x, yac[0][q * 4 + 0]);
                yac[0][q * 4 + 1] = fmaf(h0, w4.y, yac[0][q * 4 + 1]);
                yac[0][q * 4 + 2] = fmaf(h0, w4.z, yac[0][q * 4 + 2]);
                yac[0][q * 4 + 3] = fmaf(h0, w4.w, yac[0][q * 4 + 3]);
                yac[1][q * 4 + 0] = fmaf(h1, w4.x, yac[1][q * 4 + 0]);
                yac[1][q * 4 + 1] = fmaf(h1, w4.y, yac[1][q * 4 + 1]);
                yac[1][q * 4 + 2] = fmaf(h1, w4.z, yac[1][q * 4 + 2]);
                yac[1][q * 4 + 3] = fmaf(h1, w4.w, yac[1][q * 4 + 3]);
            }
        }
    }
    #pragma unroll
    for (int u = 0; u < 2; ++u) {
        int a = rowa[r0 + u];
        if (a >= 0) {
            float* yp = ybuf + (size_t)a * HS + cg * 32;
            #pragma unroll
            for (int q = 0; q < 8; ++q) {
                float4 o = make_float4(yac[u][q * 4 + 0], yac[u][q * 4 + 1],
                                       yac[u][q * 4 + 2], yac[u][q * 4 + 3]);
                *reinterpret_cast<float4*>(yp + q * 4) = o;
            }
        }
    }
}

__global__ void fb_combine(const float* __restrict__ ybuf, const float* __restrict__ ew,
                           float* __restrict__ out) {
    int i = blockIdx.x * 256 + threadIdx.x;
    if (i >= T_TOK * HS / 4) return;
    int tk = i >> 7, c4 = i & 127;
    float wA = ew[2 * tk], wB = ew[2 * tk + 1];
    const float4* y4 = reinterpret_cast<const float4*>(ybuf);
    float4 a = y4[(size_t)(2 * tk) * (HS / 4) + c4];
    float4 b = y4[(size_t)(2 * tk + 1) * (HS / 4) + c4];
    float4 o;
    o.x = wA * a.x + wB * b.x; o.y = wA * a.y + wB * b.y;
    o.z = wA * a.z + wB * b.z; o.w = wA * a.w + wB * b.w;
    reinterpret_cast<float4*>(out)[i] = o;
}

// ================= launch =================
extern "C" void kernel_launch(void* const* d_in, const int* in_sizes, int n_in,
                              void* d_out, int out_size, void* d_ws, size_t ws_size,
                              hipStream_t stream) {
    const float* x  = (const float*)d_in[0];
    const float* ew = (const float*)d_in[1];
    const int*   ei = (const int*)d_in[2];
    const float* w1 = (const float*)d_in[3];
    const float* w2 = (const float*)d_in[4];
    float* out = (float*)d_out;
    char* W = (char*)d_ws;

    if (ws_size < WS_NEED) {
        int* cnt = (int*)d_ws;
        int* bucket = cnt + 64;
        float* ybuf = (float*)(W + (1 << 19));
        fb_init<<<1, 64, 0, stream>>>(cnt);
        fb_scatter<<<NA / 256, 256, 0, stream>>>(ei, cnt, bucket);
        fb_fused<<<NE * (NA / FB_BM), 256, 0, stream>>>(x, w1, w2, cnt, bucket, ybuf);
        fb_combine<<<(T_TOK * HS / 4 + 255) / 256, 256, 0, stream>>>(ybuf, ew, out);
        return;
    }

    int* cnt2  = (int*)(W + WS_CNT2);
    int* offp  = (int*)(W + WS_OFF);
    int* mexp  = (int*)(W + WS_MEXP);
    int* slots = (int*)(W + WS_SLOTS);
    int* inv   = (int*)(W + WS_INV);
    unsigned short* XH   = (unsigned short*)(W + WS_XH);
    unsigned short* XL   = (unsigned short*)(W + WS_XL);
    unsigned short* W1TH = (unsigned short*)(W + WS_W1TH);
    unsigned short* W1TL = (unsigned short*)(W + WS_W1TL);
    unsigned short* W2TH = (unsigned short*)(W + WS_W2TH);
    unsigned short* W2TL = (unsigned short*)(W + WS_W2TL);
    unsigned short* HH   = (unsigned short*)(W + WS_HH);
    unsigned short* HL   = (unsigned short*)(W + WS_HL);
    float* YP0 = (float*)(W + WS_YP0);
    float* YP1 = (float*)(W + WS_YP1);

    moe_prep<<<18468, 256, 0, stream>>>(slots, x, XH, XL, w1, W1TH, W1TL, w2, W2TH, W2TL);
    moe_offsets<<<1, 256, 0, stream>>>(ei, offp, mexp, cnt2);
    moe_fill<<<NA / 256, 256, 0, stream>>>(ei, offp, cnt2, slots, inv);
    moe_gemm1<<<8 * 9 * 16, 256, 0, stream>>>(XH, XL, W1TH, W1TL, offp, mexp, slots, HH, HL);
    moe_gemm2<<<8 * 9 * 8, 256, 0, stream>>>(HH, HL, W2TH, W2TL, offp, mexp, YP0, YP1);
    moe_combine2<<<(T_TOK * HS / 4) / 256, 256, 0, stream>>>(YP0, YP1, inv, ew, out);
}

// Round 7
// 144.287 us; speedup vs baseline: 34.5573x; 1.5368x over previous
//
#include <hip/hip_runtime.h>
#include <stdint.h>

#define T_TOK 4096
#define KTOP  2
#define HS    512
#define FFN   2048
#define NE    8
#define NA    (T_TOK*KTOP)     // 8192 assignments
#define MT    128              // M-tile
#define BK    64               // K-step (doubled: fewer barriers)
#define MT_MAX 72              // 8 XCD chunks x 9
#define SLOT_CAP (MT_MAX*MT)   // 9216
#define PSTR 68                // epilogue LDS f32 stride

// ---------------- workspace layout (bytes) ----------------
#define MB_ (1024ull*1024ull)
#define WS_CNT2  64u
#define WS_OFF   128u
#define WS_MEXP  256u
#define WS_SLOTS 1024u
#define WS_INV   40960u
#define WS_XB   (1*MB_)        // 4MB  bf16 [4096][512]
#define WS_W1T  (5*MB_)        // 16MB bf16 [8][2048][512]  (n-major, k=hs minor)
#define WS_W2T  (21*MB_)       // 16MB bf16 [8][512][2048]  (n-major, k=ffn minor)
#define WS_HB   (37*MB_)       // 36MB bf16 [9216][2048]
#define WS_YP0  (73*MB_)       // 18MB f32 [9216][512]
#define WS_YP1  (91*MB_)       // 18MB
#define WS_NEED (109*MB_)

typedef short bf16x8 __attribute__((ext_vector_type(8)));
typedef float f32x4  __attribute__((ext_vector_type(4)));

__device__ __forceinline__ unsigned short f2bf(float f) {
    unsigned u = __builtin_bit_cast(unsigned, f);
    u += 0x7fffu + ((u >> 16) & 1u);          // RNE
    return (unsigned short)(u >> 16);
}
__device__ __forceinline__ float gelu_exact(float v) {
    return 0.5f * v * (1.0f + erff(v * 0.70710678118654752f));
}
__device__ __forceinline__ void gl_lds16(const void* g, void* l) {
    __builtin_amdgcn_global_load_lds(
        (const __attribute__((address_space(1))) unsigned int*)g,
        (__attribute__((address_space(3))) unsigned int*)l, 16, 0, 0);
}

// ---------------- merged prep: cvt_x + w1T + w2T + slots-init ----------------
// ranges: [0,2048) x->bf16 | [2048,10240) w1T | [10240,18432) w2T | [18432,18468) slots=-1
// No intra-kernel producer/consumer (R5 lesson): all consumers are later kernels.
__device__ __forceinline__ void transpose_cvt_body(
    const float* __restrict__ src, unsigned short* __restrict__ dh,
    int R, int C, int e, int kb, int nb, int t, float (*tile)[33])
{
    const int k0 = kb * 32, n0 = nb * 32;
    #pragma unroll
    for (int q = 0; q < 4; ++q) {
        int idx = t + q * 256, kk = idx >> 5, nn = idx & 31;
        tile[kk][nn] = src[((size_t)e * R + k0 + kk) * C + n0 + nn];
    }
    __syncthreads();
    #pragma unroll
    for (int q = 0; q < 4; ++q) {
        int idx = t + q * 256, nn = idx >> 5, kk = idx & 31;
        dh[((size_t)e * C + n0 + nn) * R + k0 + kk] = f2bf(tile[kk][nn]);
    }
}

__global__ void moe_prep(int* slots,
                         const float* __restrict__ x, unsigned short* __restrict__ xb,
                         const float* __restrict__ w1, unsigned short* __restrict__ w1t,
                         const float* __restrict__ w2, unsigned short* __restrict__ w2t)
{
    __shared__ float tile[32][33];
    const int bid = blockIdx.x, t = threadIdx.x;
    if (bid < 2048) {                         // x -> bf16, float4-in uint2-out
        int i = bid * 256 + t;
        float4 v = reinterpret_cast<const float4*>(x)[i];
        uint2 p = { (unsigned)f2bf(v.x) | ((unsigned)f2bf(v.y) << 16),
                    (unsigned)f2bf(v.z) | ((unsigned)f2bf(v.w) << 16) };
        reinterpret_cast<uint2*>(xb)[i] = p;
    } else if (bid < 10240) {                 // w1 [e][HS][FFN] -> [e][FFN][HS]
        int lin = bid - 2048, e = lin >> 10, rem = lin & 1023;
        transpose_cvt_body(w1, w1t, HS, FFN, e, rem & 15, rem >> 4, t, tile);
    } else if (bid < 18432) {                 // w2 [e][FFN][HS] -> [e][HS][FFN]
        int lin = bid - 10240, e = lin >> 10, rem = lin & 1023;
        transpose_cvt_body(w2, w2t, FFN, HS, e, rem & 63, rem >> 6, t, tile);
    } else {                                  // slots = -1 (poison-safe each call)
        int gid = (bid - 18432) * 256 + t;
        if (gid < SLOT_CAP) slots[gid] = -1;
    }
}

// single block: histogram + offsets + mexp + zero cnt2 (stream-ordered w.r.t. fill)
__global__ void moe_offsets(const int* __restrict__ eidx, int* off, int* mexp, int* cnt2) {
    __shared__ int h[NE];
    const int t = threadIdx.x;
    if (t < NE) h[t] = 0;
    __syncthreads();
    for (int a = t; a < NA; a += 256) atomicAdd(&h[eidx[a]], 1);
    __syncthreads();
    if (t < NE) cnt2[t] = 0;
    if (t == 0) {
        int run = 0;
        for (int e = 0; e < NE; ++e) {
            off[e] = run;
            int nt = (h[e] + MT - 1) / MT;
            for (int i = 0; i < nt; ++i) mexp[run / MT + i] = e;
            run += nt * MT;
        }
        off[NE] = run;
        for (int m = run / MT; m < MT_MAX; ++m) mexp[m] = 0;
    }
}

__global__ void moe_fill(const int* __restrict__ eidx, const int* __restrict__ off,
                         int* cnt2, int* slots, int* inv) {
    int a = blockIdx.x * 256 + threadIdx.x;
    if (a < NA) {
        int e = eidx[a];
        int p = atomicAdd(&cnt2[e], 1);
        int s = off[e] + p;
        slots[s] = a;        // order nondeterministic; per-assignment result isn't
        inv[a] = s;
    }
}

// ---------------- grouped GEMM1: H = gelu(X @ W1), single-pass bf16 ----------------
// Grid 1152, chunked XCD affinity (mt = xcd*9 + part%9): expert weights stay in
// one XCD's L2 (R6: FETCH 149->49MB). BK=64: 32 MFMA per barrier pair.
__global__ __launch_bounds__(256, 4) void moe_gemm1(
    const unsigned short* __restrict__ XB, const unsigned short* __restrict__ W1T,
    const int* __restrict__ offp, const int* __restrict__ mexp,
    const int* __restrict__ slots, unsigned short* __restrict__ HB)
{
    const int xcd = blockIdx.x & 7;
    const int part = blockIdx.x >> 3;     // 0..143
    const int mtg = part % 9;
    const int nt  = part / 9;             // 0..15
    const int mt  = xcd * 9 + mtg;        // contiguous per XCD
    if (mt * MT >= offp[NE]) return;
    const int e = mexp[mt];
    const int t = threadIdx.x, lane = t & 63, wv = t >> 6;

    __shared__ __align__(16) char POOL[MT * PSTR * 4];   // 34816B >= 32KB staging
    __shared__ int srow[MT];
    short* As = (short*)POOL;                 // 16KB: [128][64] bf16, 8-group XOR swz
    short* Bs = (short*)(POOL + 16384);       // 16KB
    float* Pf = (float*)POOL;                 // epilogue overlay

    if (t < MT) { int s = slots[mt * MT + t]; srow[t] = (s < 0) ? 0 : (s >> 1); }
    __syncthreads();

    // staging: 4 insts/wave/operand; inst i covers rows [i*8, i*8+8)
    // source col-group pre-swizzled sg = (lane&7)^(row&7)  [rule 21: both sides]
    int baseA[4], baseB[4];
    #pragma unroll
    for (int q = 0; q < 4; ++q) {
        int i = wv * 4 + q;
        int row = i * 8 + (lane >> 3);
        int sg = (lane & 7) ^ (row & 7);
        baseA[q] = srow[row] * HS + sg * 8;
        baseB[q] = (e * FFN + nt * MT + row) * HS + sg * 8;
    }

    const int wm = wv >> 1, wn = wv & 1, q4 = lane >> 4, l15 = lane & 15;
    int offA[2][4], offB[2][4];
    #pragma unroll
    for (int m = 0; m < 4; ++m) {
        int r  = wm * 64 + m * 16 + l15;
        int rb = wn * 64 + m * 16 + l15;
        #pragma unroll
        for (int ks = 0; ks < 2; ++ks) {
            offA[ks][m] = r  * 128 + ((((ks << 2) | q4) ^ (r  & 7)) << 4);
            offB[ks][m] = rb * 128 + ((((ks << 2) | q4) ^ (rb & 7)) << 4);
        }
    }

    f32x4 acc[4][4];
    #pragma unroll
    for (int m = 0; m < 4; ++m)
        #pragma unroll
        for (int n = 0; n < 4; ++n) { f32x4 z = {0.f, 0.f, 0.f, 0.f}; acc[m][n] = z; }

    for (int kk = 0; kk < HS; kk += BK) {
        __syncthreads();
        #pragma unroll
        for (int q = 0; q < 4; ++q) {
            int i = wv * 4 + q;
            gl_lds16(XB  + baseA[q] + kk, (char*)As + i * 1024);
            gl_lds16(W1T + baseB[q] + kk, (char*)Bs + i * 1024);
        }
        __syncthreads();
        #pragma unroll
        for (int ks = 0; ks < 2; ++ks) {
            bf16x8 a[4], b[4];
            #pragma unroll
            for (int m = 0; m < 4; ++m) {
                a[m] = *(const bf16x8*)((const char*)As + offA[ks][m]);
                b[m] = *(const bf16x8*)((const char*)Bs + offB[ks][m]);
            }
            #pragma unroll
            for (int m = 0; m < 4; ++m)
                #pragma unroll
                for (int n = 0; n < 4; ++n)
                    acc[m][n] = __builtin_amdgcn_mfma_f32_16x16x32_bf16(a[m], b[n], acc[m][n], 0, 0, 0);
        }
    }

    // epilogue: LDS transpose -> coalesced bf16x8 stores (gelu in read phase)
    #pragma unroll
    for (int half = 0; half < 2; ++half) {
        __syncthreads();
        if (wn == half) {
            #pragma unroll
            for (int m = 0; m < 4; ++m)
                #pragma unroll
                for (int n = 0; n < 4; ++n)
                    #pragma unroll
                    for (int j = 0; j < 4; ++j)
                        Pf[(wm * 64 + m * 16 + q4 * 4 + j) * PSTR + n * 16 + l15] = acc[m][n][j];
        }
        __syncthreads();
        #pragma unroll
        for (int q = 0; q < 4; ++q) {
            int seg = q * 256 + t, row = seg >> 3, c8 = (seg & 7) << 3;
            const float* p = Pf + row * PSTR + c8;
            float4 a = *(const float4*)p, b = *(const float4*)(p + 4);
            float va[8] = {a.x, a.y, a.z, a.w, b.x, b.y, b.z, b.w};
            bf16x8 ph;
            #pragma unroll
            for (int i = 0; i < 8; ++i) ph[i] = (short)f2bf(gelu_exact(va[i]));
            *(bf16x8*)(HB + (size_t)(mt * MT + row) * FFN + nt * MT + half * 64 + c8) = ph;
        }
    }
}

// ---------------- grouped GEMM2: Y = H @ W2, split-K=2, single-pass bf16 ----------------
__global__ __launch_bounds__(256, 4) void moe_gemm2(
    const unsigned short* __restrict__ HB, const unsigned short* __restrict__ W2T,
    const int* __restrict__ offp, const int* __restrict__ mexp,
    float* __restrict__ YP0, float* __restrict__ YP1)
{
    const int xcd = blockIdx.x & 7;
    const int part = blockIdx.x >> 3;     // 0..71
    const int mtg = part % 9;
    const int sub = part / 9;             // 0..7
    const int mt  = xcd * 9 + mtg;
    const int nt  = sub >> 1, kpart = sub & 1;
    if (mt * MT >= offp[NE]) return;
    const int e = mexp[mt];
    const int t = threadIdx.x, lane = t & 63, wv = t >> 6;

    __shared__ __align__(16) char POOL[MT * PSTR * 4];
    short* As = (short*)POOL;
    short* Bs = (short*)(POOL + 16384);
    float* Pf = (float*)POOL;

    int baseA[4], baseB[4];
    #pragma unroll
    for (int q = 0; q < 4; ++q) {
        int i = wv * 4 + q;
        int row = i * 8 + (lane >> 3);
        int sg = (lane & 7) ^ (row & 7);
        baseA[q] = (mt * MT + row) * FFN + sg * 8;
        baseB[q] = (e * HS + nt * MT + row) * FFN + sg * 8;
    }

    const int wm = wv >> 1, wn = wv & 1, q4 = lane >> 4, l15 = lane & 15;
    int offA[2][4], offB[2][4];
    #pragma unroll
    for (int m = 0; m < 4; ++m) {
        int r  = wm * 64 + m * 16 + l15;
        int rb = wn * 64 + m * 16 + l15;
        #pragma unroll
        for (int ks = 0; ks < 2; ++ks) {
            offA[ks][m] = r  * 128 + ((((ks << 2) | q4) ^ (r  & 7)) << 4);
            offB[ks][m] = rb * 128 + ((((ks << 2) | q4) ^ (rb & 7)) << 4);
        }
    }

    f32x4 acc[4][4];
    #pragma unroll
    for (int m = 0; m < 4; ++m)
        #pragma unroll
        for (int n = 0; n < 4; ++n) { f32x4 z = {0.f, 0.f, 0.f, 0.f}; acc[m][n] = z; }

    const int k0 = kpart * (FFN / 2), k1 = k0 + FFN / 2;
    for (int kk = k0; kk < k1; kk += BK) {
        __syncthreads();
        #pragma unroll
        for (int q = 0; q < 4; ++q) {
            int i = wv * 4 + q;
            gl_lds16(HB  + baseA[q] + kk, (char*)As + i * 1024);
            gl_lds16(W2T + baseB[q] + kk, (char*)Bs + i * 1024);
        }
        __syncthreads();
        #pragma unroll
        for (int ks = 0; ks < 2; ++ks) {
            bf16x8 a[4], b[4];
            #pragma unroll
            for (int m = 0; m < 4; ++m) {
                a[m] = *(const bf16x8*)((const char*)As + offA[ks][m]);
                b[m] = *(const bf16x8*)((const char*)Bs + offB[ks][m]);
            }
            #pragma unroll
            for (int m = 0; m < 4; ++m)
                #pragma unroll
                for (int n = 0; n < 4; ++n)
                    acc[m][n] = __builtin_amdgcn_mfma_f32_16x16x32_bf16(a[m], b[n], acc[m][n], 0, 0, 0);
        }
    }

    float* YP = kpart ? YP1 : YP0;
    #pragma unroll
    for (int half = 0; half < 2; ++half) {
        __syncthreads();
        if (wn == half) {
            #pragma unroll
            for (int m = 0; m < 4; ++m)
                #pragma unroll
                for (int n = 0; n < 4; ++n)
                    #pragma unroll
                    for (int j = 0; j < 4; ++j)
                        Pf[(wm * 64 + m * 16 + q4 * 4 + j) * PSTR + n * 16 + l15] = acc[m][n][j];
        }
        __syncthreads();
        #pragma unroll
        for (int q = 0; q < 4; ++q) {
            int seg = q * 256 + t, row = seg >> 3, c8 = (seg & 7) << 3;
            const float* p = Pf + row * PSTR + c8;
            float4 a = *(const float4*)p, b = *(const float4*)(p + 4);
            float* d = YP + (size_t)(mt * MT + row) * HS + nt * MT + half * 64 + c8;
            *(float4*)d = a;
            *(float4*)(d + 4) = b;
        }
    }
}

// ---------------- combine ----------------
__global__ void moe_combine2(const float* __restrict__ YP0, const float* __restrict__ YP1,
                             const int* __restrict__ inv, const float* __restrict__ ew,
                             float* __restrict__ out) {
    int i = blockIdx.x * 256 + threadIdx.x;      // over T*HS/4 float4s
    if (i >= T_TOK * HS / 4) return;
    int tk = i >> 7, c4 = i & 127;
    int s0 = inv[2 * tk], s1 = inv[2 * tk + 1];
    float w0 = ew[2 * tk], w1 = ew[2 * tk + 1];
    const float4* p0 = reinterpret_cast<const float4*>(YP0);
    const float4* p1 = reinterpret_cast<const float4*>(YP1);
    float4 a0 = p0[(size_t)s0 * 128 + c4], b0 = p1[(size_t)s0 * 128 + c4];
    float4 a1 = p0[(size_t)s1 * 128 + c4], b1 = p1[(size_t)s1 * 128 + c4];
    float4 o;
    o.x = w0 * (a0.x + b0.x) + w1 * (a1.x + b1.x);
    o.y = w0 * (a0.y + b0.y) + w1 * (a1.y + b1.y);
    o.z = w0 * (a0.z + b0.z) + w1 * (a1.z + b1.z);
    o.w = w0 * (a0.w + b0.w) + w1 * (a1.w + b1.w);
    reinterpret_cast<float4*>(out)[i] = o;
}

// ================= fallback VALU path (proven baseline) =================
#define FB_BM 32
#define FB_BJ 128
#define FB_CK 256
#define FB_XSTR (FB_CK+4)
#define FB_HSTR (FB_BJ+4)

__device__ __forceinline__ float fb_gelu(float v) {
    return 0.5f * v * (1.0f + erff(v * 0.70710678118654752f));
}

__global__ void fb_init(int* cnt) { int i = threadIdx.x; if (i < NE) cnt[i] = 0; }

__global__ void fb_scatter(const int* __restrict__ eidx, int* cnt, int* bucket) {
    int a = blockIdx.x * 256 + threadIdx.x;
    if (a < NA) { int e = eidx[a]; int p = atomicAdd(&cnt[e], 1); bucket[e * NA + p] = a; }
}

__global__ __launch_bounds__(256, 1) void fb_fused(
    const float* __restrict__ x, const float* __restrict__ w1, const float* __restrict__ w2,
    const int* __restrict__ cnt, const int* __restrict__ bucket, float* __restrict__ ybuf)
{
    const int bid = blockIdx.x;
    const int e = bid & (NE - 1), tr = bid >> 3;
    const int n_e = cnt[e], rbase = tr * FB_BM;
    if (rbase >= n_e) return;
    const int t = threadIdx.x;
    __shared__ __align__(16) float Xc[FB_BM][FB_XSTR];
    __shared__ __align__(16) float Hsh[FB_BM][FB_HSTR];
    __shared__ int rowa[FB_BM];
    if (t < FB_BM) { int r = rbase + t; rowa[t] = (r < n_e) ? bucket[e * NA + r] : -1; }
    __syncthreads();
    const int cg = t & 15, rg = t >> 4, r0 = rg * 2;
    float yac[2][32];
    #pragma unroll
    for (int u = 0; u < 2; ++u)
        #pragma unroll
        for (int v = 0; v < 32; ++v) yac[u][v] = 0.0f;
    const float* w1e = w1 + (size_t)e * HS * FFN;
    const float* w2e = w2 + (size_t)e * FFN * HS;
    for (int jp = 0; jp < FFN; jp += FB_BJ) {
        float hac[2][8];
        #pragma unroll
        for (int u = 0; u < 2; ++u)
            #pragma unroll
            for (int v = 0; v < 8; ++v) hac[u][v] = 0.0f;
        for (int ic = 0; ic < HS; ic += FB_CK) {
            __syncthreads();
            #pragma unroll
            for (int q = 0; q < (FB_BM * FB_CK / 4) / 256; ++q) {
                int id = t + 256 * q, rr = id >> 6, c4 = id & 63;
                int a = rowa[rr];
                float4 val = make_float4(0.f, 0.f, 0.f, 0.f);
                if (a >= 0) val = *reinterpret_cast<const float4*>(x + (size_t)(a >> 1) * HS + ic + c4 * 4);
                *reinterpret_cast<float4*>(&Xc[rr][c4 * 4]) = val;
            }
            __syncthreads();
            const float* w1p = w1e + (size_t)ic * FFN + jp + cg * 8;
            #pragma unroll 2
            for (int i4 = 0; i4 < FB_CK; i4 += 4) {
                float4 xa = *reinterpret_cast<const float4*>(&Xc[r0][i4]);
                float4 xb = *reinterpret_cast<const float4*>(&Xc[r0 + 1][i4]);
                const float* wr0 = w1p + (size_t)i4 * FFN;
                #pragma unroll
                for (int ii = 0; ii < 4; ++ii) {
                    float4 wa = *reinterpret_cast<const float4*>(wr0 + (size_t)ii * FFN);
                    float4 wb = *reinterpret_cast<const float4*>(wr0 + (size_t)ii * FFN + 4);
                    float x0 = (ii == 0) ? xa.x : (ii == 1) ? xa.y : (ii == 2) ? xa.z : xa.w;
                    float x1 = (ii == 0) ? xb.x : (ii == 1) ? xb.y : (ii == 2) ? xb.z : xb.w;
                    hac[0][0] = fmaf(x0, wa.x, hac[0][0]); hac[0][1] = fmaf(x0, wa.y, hac[0][1]);
                    hac[0][2] = fmaf(x0, wa.z, hac[0][2]); hac[0][3] = fmaf(x0, wa.w, hac[0][3]);
                    hac[0][4] = fmaf(x0, wb.x, hac[0][4]); hac[0][5] = fmaf(x0, wb.y, hac[0][5]);
                    hac[0][6] = fmaf(x0, wb.z, hac[0][6]); hac[0][7] = fmaf(x0, wb.w, hac[0][7]);
                    hac[1][0] = fmaf(x1, wa.x, hac[1][0]); hac[1][1] = fmaf(x1, wa.y, hac[1][1]);
                    hac[1][2] = fmaf(x1, wa.z, hac[1][2]); hac[1][3] = fmaf(x1, wa.w, hac[1][3]);
                    hac[1][4] = fmaf(x1, wb.x, hac[1][4]); hac[1][5] = fmaf(x1, wb.y, hac[1][5]);
                    hac[1][6] = fmaf(x1, wb.z, hac[1][6]); hac[1][7] = fmaf(x1, wb.w, hac[1][7]);
                }
            }
        }
        #pragma unroll
        for (int u = 0; u < 2; ++u)
            #pragma unroll
            for (int v = 0; v < 8; ++v) Hsh[r0 + u][cg * 8 + v] = fb_gelu(hac[u][v]);
        __syncthreads();
        const float* w2p = w2e + (size_t)jp * HS + cg * 32;
        #pragma unroll 2
        for (int j = 0; j < FB_BJ; ++j) {
            float h0 = Hsh[r0][j], h1 = Hsh[r0 + 1][j];
            const float* wr = w2p + (size_t)j * HS;
            #pragma unroll
            for (int q = 0; q < 8; ++q) {
                float4 w4 = *reinterpret_cast<const float4*>(wr + q * 4);
                yac[0][q * 4 + 0] = fmaf(h0, w4.x, yac[0][q * 4 + 0]);
                yac[0][q * 4 + 1] = fmaf(h0, w4.y, yac[0][q * 4 + 1]);
                yac[0][q * 4 + 2] = fmaf(h0, w4.z, yac[0][q * 4 + 2]);
                yac[0][q * 4 + 3] = fmaf(h0, w4.w, yac[0][q * 4 + 3]);
                yac[1][q * 4 + 0] = fmaf(h1, w4.x, yac[1][q * 4 + 0]);
                yac[1][q * 4 + 1] = fmaf(h1, w4.y, yac[1][q * 4 + 1]);
                yac[1][q * 4 + 2] = fmaf(h1, w4.z, yac[1][q * 4 + 2]);
                yac[1][q * 4 + 3] = fmaf(h1, w4.w, yac[1][q * 4 + 3]);
            }
        }
    }
    #pragma unroll
    for (int u = 0; u < 2; ++u) {
        int a = rowa[r0 + u];
        if (a >= 0) {
            float* yp = ybuf + (size_t)a * HS + cg * 32;
            #pragma unroll
            for (int q = 0; q < 8; ++q) {
                float4 o = make_float4(yac[u][q * 4 + 0], yac[u][q * 4 + 1],
                                       yac[u][q * 4 + 2], yac[u][q * 4 + 3]);
                *reinterpret_cast<float4*>(yp + q * 4) = o;
            }
        }
    }
}

__global__ void fb_combine(const float* __restrict__ ybuf, const float* __restrict__ ew,
                           float* __restrict__ out) {
    int i = blockIdx.x * 256 + threadIdx.x;
    if (i >= T_TOK * HS / 4) return;
    int tk = i >> 7, c4 = i & 127;
    float wA = ew[2 * tk], wB = ew[2 * tk + 1];
    const float4* y4 = reinterpret_cast<const float4*>(ybuf);
    float4 a = y4[(size_t)(2 * tk) * (HS / 4) + c4];
    float4 b = y4[(size_t)(2 * tk + 1) * (HS / 4) + c4];
    float4 o;
    o.x = wA * a.x + wB * b.x; o.y = wA * a.y + wB * b.y;
    o.z = wA * a.z + wB * b.z; o.w = wA * a.w + wB * b.w;
    reinterpret_cast<float4*>(out)[i] = o;
}

// ================= launch =================
extern "C" void kernel_launch(void* const* d_in, const int* in_sizes, int n_in,
                              void* d_out, int out_size, void* d_ws, size_t ws_size,
                              hipStream_t stream) {
    const float* x  = (const float*)d_in[0];
    const float* ew = (const float*)d_in[1];
    const int*   ei = (const int*)d_in[2];
    const float* w1 = (const float*)d_in[3];
    const float* w2 = (const float*)d_in[4];
    float* out = (float*)d_out;
    char* W = (char*)d_ws;

    if (ws_size < WS_NEED) {
        int* cnt = (int*)d_ws;
        int* bucket = cnt + 64;
        float* ybuf = (float*)(W + (1 << 19));
        fb_init<<<1, 64, 0, stream>>>(cnt);
        fb_scatter<<<NA / 256, 256, 0, stream>>>(ei, cnt, bucket);
        fb_fused<<<NE * (NA / FB_BM), 256, 0, stream>>>(x, w1, w2, cnt, bucket, ybuf);
        fb_combine<<<(T_TOK * HS / 4 + 255) / 256, 256, 0, stream>>>(ybuf, ew, out);
        return;
    }

    int* cnt2  = (int*)(W + WS_CNT2);
    int* offp  = (int*)(W + WS_OFF);
    int* mexp  = (int*)(W + WS_MEXP);
    int* slots = (int*)(W + WS_SLOTS);
    int* inv   = (int*)(W + WS_INV);
    unsigned short* XB  = (unsigned short*)(W + WS_XB);
    unsigned short* W1T = (unsigned short*)(W + WS_W1T);
    unsigned short* W2T = (unsigned short*)(W + WS_W2T);
    unsigned short* HB  = (unsigned short*)(W + WS_HB);
    float* YP0 = (float*)(W + WS_YP0);
    float* YP1 = (float*)(W + WS_YP1);

    moe_prep<<<18468, 256, 0, stream>>>(slots, x, XB, w1, W1T, w2, W2T);
    moe_offsets<<<1, 256, 0, stream>>>(ei, offp, mexp, cnt2);
    moe_fill<<<NA / 256, 256, 0, stream>>>(ei, offp, cnt2, slots, inv);
    moe_gemm1<<<8 * 9 * 16, 256, 0, stream>>>(XB, W1T, offp, mexp, slots, HB);
    moe_gemm2<<<8 * 9 * 8, 256, 0, stream>>>(HB, W2T, offp, mexp, YP0, YP1);
    moe_combine2<<<(T_TOK * HS / 4) / 256, 256, 0, stream>>>(YP0, YP1, inv, ew, out);
}

// Round 8
// 130.358 us; speedup vs baseline: 38.2497x; 1.1068x over previous
//
#include <hip/hip_runtime.h>
#include <stdint.h>

#define T_TOK 4096
#define KTOP  2
#define HS    512
#define FFN   2048
#define NE    8
#define NA    (T_TOK*KTOP)     // 8192 assignments
#define MT    128              // M-tile
#define BK    64               // K-step
#define MT_MAX 72              // 8 XCD chunks x 9
#define SLOT_CAP (MT_MAX*MT)   // 9216
#define PSTR 68                // epilogue LDS f32 stride

// ---------------- workspace layout (bytes) ----------------
#define MB_ (1024ull*1024ull)
#define WS_CNT2  64u
#define WS_OFF   128u
#define WS_MEXP  256u
#define WS_SLOTS 1024u
#define WS_INV   40960u
#define WS_XB   (1*MB_)        // 4MB  bf16 [4096][512]
#define WS_W1T  (5*MB_)        // 16MB bf16 [8][2048][512]
#define WS_W2T  (21*MB_)       // 16MB bf16 [8][512][2048]
#define WS_HB   (37*MB_)       // 36MB bf16 [9216][2048]
#define WS_YPB0 (73*MB_)       // 9MB bf16 [9216][512]
#define WS_YPB1 (82*MB_)       // 9MB
#define WS_NEED (91*MB_)

typedef short bf16x8 __attribute__((ext_vector_type(8)));
typedef float f32x4  __attribute__((ext_vector_type(4)));

__device__ __forceinline__ unsigned short f2bf(float f) {
    unsigned u = __builtin_bit_cast(unsigned, f);
    u += 0x7fffu + ((u >> 16) & 1u);          // RNE
    return (unsigned short)(u >> 16);
}
__device__ __forceinline__ float bf2f(unsigned short h) {
    return __builtin_bit_cast(float, (unsigned)h << 16);
}
// tanh-approx gelu (~10 VALU ops vs erff ~30; |err| <= ~3e-3).
// g = x - x/(1+E), E = exp(1.5957691(x + 0.044715 x^3)); inf-safe both tails.
__device__ __forceinline__ float gelu_fast(float x) {
    float x2 = x * x;
    float inner = fmaf(0.044715f * x2, x, x);
    float E = __expf(1.5957691216057308f * inner);
    return x - x / (1.0f + E);
}
__device__ __forceinline__ void gl_lds16(const void* g, void* l) {
    __builtin_amdgcn_global_load_lds(
        (const __attribute__((address_space(1))) unsigned int*)g,
        (__attribute__((address_space(3))) unsigned int*)l, 16, 0, 0);
}

// ---------------- merged prep: cvt_x + w1T + w2T + slots/cnt2-init ----------------
// ranges: [0,2048) x->bf16 | [2048,10240) w1T | [10240,18432) w2T | [18432,18468) init
// No intra-kernel producer/consumer (R5 lesson): all consumers are later kernels.
__device__ __forceinline__ void transpose_cvt_body(
    const float* __restrict__ src, unsigned short* __restrict__ dh,
    int R, int C, int e, int kb, int nb, int t, float (*tile)[33])
{
    const int k0 = kb * 32, n0 = nb * 32;
    #pragma unroll
    for (int q = 0; q < 4; ++q) {
        int idx = t + q * 256, kk = idx >> 5, nn = idx & 31;
        tile[kk][nn] = src[((size_t)e * R + k0 + kk) * C + n0 + nn];
    }
    __syncthreads();
    #pragma unroll
    for (int q = 0; q < 4; ++q) {
        int idx = t + q * 256, nn = idx >> 5, kk = idx & 31;
        dh[((size_t)e * C + n0 + nn) * R + k0 + kk] = f2bf(tile[kk][nn]);
    }
}

__global__ void moe_prep(int* slots, int* cnt2,
                         const float* __restrict__ x, unsigned short* __restrict__ xb,
                         const float* __restrict__ w1, unsigned short* __restrict__ w1t,
                         const float* __restrict__ w2, unsigned short* __restrict__ w2t)
{
    __shared__ float tile[32][33];
    const int bid = blockIdx.x, t = threadIdx.x;
    if (bid < 2048) {                         // x -> bf16
        int i = bid * 256 + t;
        float4 v = reinterpret_cast<const float4*>(x)[i];
        uint2 p = { (unsigned)f2bf(v.x) | ((unsigned)f2bf(v.y) << 16),
                    (unsigned)f2bf(v.z) | ((unsigned)f2bf(v.w) << 16) };
        reinterpret_cast<uint2*>(xb)[i] = p;
    } else if (bid < 10240) {                 // w1 [e][HS][FFN] -> [e][FFN][HS]
        int lin = bid - 2048, e = lin >> 10, rem = lin & 1023;
        transpose_cvt_body(w1, w1t, HS, FFN, e, rem & 15, rem >> 4, t, tile);
    } else if (bid < 18432) {                 // w2 [e][FFN][HS] -> [e][HS][FFN]
        int lin = bid - 10240, e = lin >> 10, rem = lin & 1023;
        transpose_cvt_body(w2, w2t, FFN, HS, e, rem & 63, rem >> 6, t, tile);
    } else {                                  // slots=-1 + cnt2=0 (poison-safe)
        int gid = (bid - 18432) * 256 + t;
        if (gid < SLOT_CAP) slots[gid] = -1;
        if (gid < NE) cnt2[gid] = 0;
    }
}

// fill + offsets merged: each of 32 blocks recomputes the 8-bin histogram
// (8192 coalesced reads, trivial) and derives identical offsets in LDS;
// block 0 publishes offp/mexp (sole writer); all blocks scatter their 256
// assignments via global atomics on cnt2 (zeroed by prep, stream-ordered).
__global__ void moe_fill(const int* __restrict__ eidx, int* cnt2, int* slots, int* inv,
                         int* offp, int* mexp) {
    __shared__ int h[NE];
    __shared__ int off_l[NE + 1];
    const int t = threadIdx.x;
    if (t < NE) h[t] = 0;
    __syncthreads();
    for (int a = t; a < NA; a += 256) atomicAdd(&h[eidx[a]], 1);
    __syncthreads();
    if (t == 0) {
        int run = 0;
        for (int e = 0; e < NE; ++e) { off_l[e] = run; run += ((h[e] + MT - 1) / MT) * MT; }
        off_l[NE] = run;
    }
    __syncthreads();
    if (blockIdx.x == 0) {
        if (t <= NE) offp[t] = off_l[t];
        if (t < MT_MAX) {                     // mexp[t]: expert owning tile t
            int m0 = t * MT, e = 0;
            #pragma unroll
            for (int q = 0; q < NE; ++q)
                if (m0 >= off_l[q] && m0 < off_l[q + 1]) e = q;
            mexp[t] = e;
        }
    }
    int a = blockIdx.x * 256 + t;
    if (a < NA) {
        int e = eidx[a];
        int p = atomicAdd(&cnt2[e], 1);
        int s = off_l[e] + p;
        slots[s] = a;        // order nondeterministic; per-assignment result isn't
        inv[a] = s;
    }
}

// ---------------- grouped GEMM1: H = gelu(X @ W1), single-pass bf16 ----------------
// Grid 1152, chunked XCD affinity (mt = xcd*9 + part%9) -> expert weights L2-resident.
__global__ __launch_bounds__(256, 4) void moe_gemm1(
    const unsigned short* __restrict__ XB, const unsigned short* __restrict__ W1T,
    const int* __restrict__ offp, const int* __restrict__ mexp,
    const int* __restrict__ slots, unsigned short* __restrict__ HB)
{
    const int xcd = blockIdx.x & 7;
    const int part = blockIdx.x >> 3;     // 0..143
    const int mtg = part % 9;
    const int nt  = part / 9;             // 0..15
    const int mt  = xcd * 9 + mtg;
    if (mt * MT >= offp[NE]) return;
    const int e = mexp[mt];
    const int t = threadIdx.x, lane = t & 63, wv = t >> 6;

    __shared__ __align__(16) char POOL[MT * PSTR * 4];
    __shared__ int srow[MT];
    short* As = (short*)POOL;                 // 16KB [128][64] bf16, 8-group XOR swz
    short* Bs = (short*)(POOL + 16384);       // 16KB
    float* Pf = (float*)POOL;                 // epilogue overlay

    if (t < MT) { int s = slots[mt * MT + t]; srow[t] = (s < 0) ? 0 : (s >> 1); }
    __syncthreads();

    int baseA[4], baseB[4];
    #pragma unroll
    for (int q = 0; q < 4; ++q) {
        int i = wv * 4 + q;
        int row = i * 8 + (lane >> 3);
        int sg = (lane & 7) ^ (row & 7);      // source swz [rule 21: both sides]
        baseA[q] = srow[row] * HS + sg * 8;
        baseB[q] = (e * FFN + nt * MT + row) * HS + sg * 8;
    }

    const int wm = wv >> 1, wn = wv & 1, q4 = lane >> 4, l15 = lane & 15;
    int offA[2][4], offB[2][4];
    #pragma unroll
    for (int m = 0; m < 4; ++m) {
        int r  = wm * 64 + m * 16 + l15;
        int rb = wn * 64 + m * 16 + l15;
        #pragma unroll
        for (int ks = 0; ks < 2; ++ks) {
            offA[ks][m] = r  * 128 + ((((ks << 2) | q4) ^ (r  & 7)) << 4);
            offB[ks][m] = rb * 128 + ((((ks << 2) | q4) ^ (rb & 7)) << 4);
        }
    }

    f32x4 acc[4][4];
    #pragma unroll
    for (int m = 0; m < 4; ++m)
        #pragma unroll
        for (int n = 0; n < 4; ++n) { f32x4 z = {0.f, 0.f, 0.f, 0.f}; acc[m][n] = z; }

    for (int kk = 0; kk < HS; kk += BK) {
        __syncthreads();
        #pragma unroll
        for (int q = 0; q < 4; ++q) {
            int i = wv * 4 + q;
            gl_lds16(XB  + baseA[q] + kk, (char*)As + i * 1024);
            gl_lds16(W1T + baseB[q] + kk, (char*)Bs + i * 1024);
        }
        __syncthreads();
        #pragma unroll
        for (int ks = 0; ks < 2; ++ks) {
            bf16x8 a[4], b[4];
            #pragma unroll
            for (int m = 0; m < 4; ++m) {
                a[m] = *(const bf16x8*)((const char*)As + offA[ks][m]);
                b[m] = *(const bf16x8*)((const char*)Bs + offB[ks][m]);
            }
            #pragma unroll
            for (int m = 0; m < 4; ++m)
                #pragma unroll
                for (int n = 0; n < 4; ++n)
                    acc[m][n] = __builtin_amdgcn_mfma_f32_16x16x32_bf16(a[m], b[n], acc[m][n], 0, 0, 0);
        }
    }

    // epilogue: LDS transpose -> coalesced bf16x8 stores (fast gelu in read phase)
    #pragma unroll
    for (int half = 0; half < 2; ++half) {
        __syncthreads();
        if (wn == half) {
            #pragma unroll
            for (int m = 0; m < 4; ++m)
                #pragma unroll
                for (int n = 0; n < 4; ++n)
                    #pragma unroll
                    for (int j = 0; j < 4; ++j)
                        Pf[(wm * 64 + m * 16 + q4 * 4 + j) * PSTR + n * 16 + l15] = acc[m][n][j];
        }
        __syncthreads();
        #pragma unroll
        for (int q = 0; q < 4; ++q) {
            int seg = q * 256 + t, row = seg >> 3, c8 = (seg & 7) << 3;
            const float* p = Pf + row * PSTR + c8;
            float4 a = *(const float4*)p, b = *(const float4*)(p + 4);
            float va[8] = {a.x, a.y, a.z, a.w, b.x, b.y, b.z, b.w};
            bf16x8 ph;
            #pragma unroll
            for (int i = 0; i < 8; ++i) ph[i] = (short)f2bf(gelu_fast(va[i]));
            *(bf16x8*)(HB + (size_t)(mt * MT + row) * FFN + nt * MT + half * 64 + c8) = ph;
        }
    }
}

// ---------------- grouped GEMM2: Y = H @ W2, split-K=2, bf16 partials ----------------
__global__ __launch_bounds__(256, 4) void moe_gemm2(
    const unsigned short* __restrict__ HB, const unsigned short* __restrict__ W2T,
    const int* __restrict__ offp, const int* __restrict__ mexp,
    unsigned short* __restrict__ YPB0, unsigned short* __restrict__ YPB1)
{
    const int xcd = blockIdx.x & 7;
    const int part = blockIdx.x >> 3;     // 0..71
    const int mtg = part % 9;
    const int sub = part / 9;             // 0..7
    const int mt  = xcd * 9 + mtg;
    const int nt  = sub >> 1, kpart = sub & 1;
    if (mt * MT >= offp[NE]) return;
    const int e = mexp[mt];
    const int t = threadIdx.x, lane = t & 63, wv = t >> 6;

    __shared__ __align__(16) char POOL[MT * PSTR * 4];
    short* As = (short*)POOL;
    short* Bs = (short*)(POOL + 16384);
    float* Pf = (float*)POOL;

    int baseA[4], baseB[4];
    #pragma unroll
    for (int q = 0; q < 4; ++q) {
        int i = wv * 4 + q;
        int row = i * 8 + (lane >> 3);
        int sg = (lane & 7) ^ (row & 7);
        baseA[q] = (mt * MT + row) * FFN + sg * 8;
        baseB[q] = (e * HS + nt * MT + row) * FFN + sg * 8;
    }

    const int wm = wv >> 1, wn = wv & 1, q4 = lane >> 4, l15 = lane & 15;
    int offA[2][4], offB[2][4];
    #pragma unroll
    for (int m = 0; m < 4; ++m) {
        int r  = wm * 64 + m * 16 + l15;
        int rb = wn * 64 + m * 16 + l15;
        #pragma unroll
        for (int ks = 0; ks < 2; ++ks) {
            offA[ks][m] = r  * 128 + ((((ks << 2) | q4) ^ (r  & 7)) << 4);
            offB[ks][m] = rb * 128 + ((((ks << 2) | q4) ^ (rb & 7)) << 4);
        }
    }

    f32x4 acc[4][4];
    #pragma unroll
    for (int m = 0; m < 4; ++m)
        #pragma unroll
        for (int n = 0; n < 4; ++n) { f32x4 z = {0.f, 0.f, 0.f, 0.f}; acc[m][n] = z; }

    const int k0 = kpart * (FFN / 2), k1 = k0 + FFN / 2;
    for (int kk = k0; kk < k1; kk += BK) {
        __syncthreads();
        #pragma unroll
        for (int q = 0; q < 4; ++q) {
            int i = wv * 4 + q;
            gl_lds16(HB  + baseA[q] + kk, (char*)As + i * 1024);
            gl_lds16(W2T + baseB[q] + kk, (char*)Bs + i * 1024);
        }
        __syncthreads();
        #pragma unroll
        for (int ks = 0; ks < 2; ++ks) {
            bf16x8 a[4], b[4];
            #pragma unroll
            for (int m = 0; m < 4; ++m) {
                a[m] = *(const bf16x8*)((const char*)As + offA[ks][m]);
                b[m] = *(const bf16x8*)((const char*)Bs + offB[ks][m]);
            }
            #pragma unroll
            for (int m = 0; m < 4; ++m)
                #pragma unroll
                for (int n = 0; n < 4; ++n)
                    acc[m][n] = __builtin_amdgcn_mfma_f32_16x16x32_bf16(a[m], b[n], acc[m][n], 0, 0, 0);
        }
    }

    unsigned short* YP = kpart ? YPB1 : YPB0;
    #pragma unroll
    for (int half = 0; half < 2; ++half) {
        __syncthreads();
        if (wn == half) {
            #pragma unroll
            for (int m = 0; m < 4; ++m)
                #pragma unroll
                for (int n = 0; n < 4; ++n)
                    #pragma unroll
                    for (int j = 0; j < 4; ++j)
                        Pf[(wm * 64 + m * 16 + q4 * 4 + j) * PSTR + n * 16 + l15] = acc[m][n][j];
        }
        __syncthreads();
        #pragma unroll
        for (int q = 0; q < 4; ++q) {
            int seg = q * 256 + t, row = seg >> 3, c8 = (seg & 7) << 3;
            const float* p = Pf + row * PSTR + c8;
            float4 a = *(const float4*)p, b = *(const float4*)(p + 4);
            float va[8] = {a.x, a.y, a.z, a.w, b.x, b.y, b.z, b.w};
            bf16x8 ph;
            #pragma unroll
            for (int i = 0; i < 8; ++i) ph[i] = (short)f2bf(va[i]);
            *(bf16x8*)(YP + (size_t)(mt * MT + row) * HS + nt * MT + half * 64 + c8) = ph;
        }
    }
}

// ---------------- combine (bf16 partials) ----------------
__global__ void moe_combine2(const unsigned short* __restrict__ YPB0,
                             const unsigned short* __restrict__ YPB1,
                             const int* __restrict__ inv, const float* __restrict__ ew,
                             float* __restrict__ out) {
    int i = blockIdx.x * 256 + threadIdx.x;      // over T*HS/8 groups of 8
    if (i >= T_TOK * HS / 8) return;
    int tk = i >> 6, c8 = (i & 63) << 3;
    int s0 = inv[2 * tk], s1 = inv[2 * tk + 1];
    float w0 = ew[2 * tk], w1 = ew[2 * tk + 1];
    bf16x8 a0 = *(const bf16x8*)(YPB0 + (size_t)s0 * HS + c8);
    bf16x8 b0 = *(const bf16x8*)(YPB1 + (size_t)s0 * HS + c8);
    bf16x8 a1 = *(const bf16x8*)(YPB0 + (size_t)s1 * HS + c8);
    bf16x8 b1 = *(const bf16x8*)(YPB1 + (size_t)s1 * HS + c8);
    float o[8];
    #pragma unroll
    for (int j = 0; j < 8; ++j)
        o[j] = w0 * (bf2f((unsigned short)a0[j]) + bf2f((unsigned short)b0[j]))
             + w1 * (bf2f((unsigned short)a1[j]) + bf2f((unsigned short)b1[j]));
    float4* d = reinterpret_cast<float4*>(out + (size_t)i * 8);
    d[0] = make_float4(o[0], o[1], o[2], o[3]);
    d[1] = make_float4(o[4], o[5], o[6], o[7]);
}

// ================= fallback VALU path (proven baseline) =================
#define FB_BM 32
#define FB_BJ 128
#define FB_CK 256
#define FB_XSTR (FB_CK+4)
#define FB_HSTR (FB_BJ+4)

__device__ __forceinline__ float fb_gelu(float v) {
    return 0.5f * v * (1.0f + erff(v * 0.70710678118654752f));
}

__global__ void fb_init(int* cnt) { int i = threadIdx.x; if (i < NE) cnt[i] = 0; }

__global__ void fb_scatter(const int* __restrict__ eidx, int* cnt, int* bucket) {
    int a = blockIdx.x * 256 + threadIdx.x;
    if (a < NA) { int e = eidx[a]; int p = atomicAdd(&cnt[e], 1); bucket[e * NA + p] = a; }
}

__global__ __launch_bounds__(256, 1) void fb_fused(
    const float* __restrict__ x, const float* __restrict__ w1, const float* __restrict__ w2,
    const int* __restrict__ cnt, const int* __restrict__ bucket, float* __restrict__ ybuf)
{
    const int bid = blockIdx.x;
    const int e = bid & (NE - 1), tr = bid >> 3;
    const int n_e = cnt[e], rbase = tr * FB_BM;
    if (rbase >= n_e) return;
    const int t = threadIdx.x;
    __shared__ __align__(16) float Xc[FB_BM][FB_XSTR];
    __shared__ __align__(16) float Hsh[FB_BM][FB_HSTR];
    __shared__ int rowa[FB_BM];
    if (t < FB_BM) { int r = rbase + t; rowa[t] = (r < n_e) ? bucket[e * NA + r] : -1; }
    __syncthreads();
    const int cg = t & 15, rg = t >> 4, r0 = rg * 2;
    float yac[2][32];
    #pragma unroll
    for (int u = 0; u < 2; ++u)
        #pragma unroll
        for (int v = 0; v < 32; ++v) yac[u][v] = 0.0f;
    const float* w1e = w1 + (size_t)e * HS * FFN;
    const float* w2e = w2 + (size_t)e * FFN * HS;
    for (int jp = 0; jp < FFN; jp += FB_BJ) {
        float hac[2][8];
        #pragma unroll
        for (int u = 0; u < 2; ++u)
            #pragma unroll
            for (int v = 0; v < 8; ++v) hac[u][v] = 0.0f;
        for (int ic = 0; ic < HS; ic += FB_CK) {
            __syncthreads();
            #pragma unroll
            for (int q = 0; q < (FB_BM * FB_CK / 4) / 256; ++q) {
                int id = t + 256 * q, rr = id >> 6, c4 = id & 63;
                int a = rowa[rr];
                float4 val = make_float4(0.f, 0.f, 0.f, 0.f);
                if (a >= 0) val = *reinterpret_cast<const float4*>(x + (size_t)(a >> 1) * HS + ic + c4 * 4);
                *reinterpret_cast<float4*>(&Xc[rr][c4 * 4]) = val;
            }
            __syncthreads();
            const float* w1p = w1e + (size_t)ic * FFN + jp + cg * 8;
            #pragma unroll 2
            for (int i4 = 0; i4 < FB_CK; i4 += 4) {
                float4 xa = *reinterpret_cast<const float4*>(&Xc[r0][i4]);
                float4 xb = *reinterpret_cast<const float4*>(&Xc[r0 + 1][i4]);
                const float* wr0 = w1p + (size_t)i4 * FFN;
                #pragma unroll
                for (int ii = 0; ii < 4; ++ii) {
                    float4 wa = *reinterpret_cast<const float4*>(wr0 + (size_t)ii * FFN);
                    float4 wb = *reinterpret_cast<const float4*>(wr0 + (size_t)ii * FFN + 4);
                    float x0 = (ii == 0) ? xa.x : (ii == 1) ? xa.y : (ii == 2) ? xa.z : xa.w;
                    float x1 = (ii == 0) ? xb.x : (ii == 1) ? xb.y : (ii == 2) ? xb.z : xb.w;
                    hac[0][0] = fmaf(x0, wa.x, hac[0][0]); hac[0][1] = fmaf(x0, wa.y, hac[0][1]);
                    hac[0][2] = fmaf(x0, wa.z, hac[0][2]); hac[0][3] = fmaf(x0, wa.w, hac[0][3]);
                    hac[0][4] = fmaf(x0, wb.x, hac[0][4]); hac[0][5] = fmaf(x0, wb.y, hac[0][5]);
                    hac[0][6] = fmaf(x0, wb.z, hac[0][6]); hac[0][7] = fmaf(x0, wb.w, hac[0][7]);
                    hac[1][0] = fmaf(x1, wa.x, hac[1][0]); hac[1][1] = fmaf(x1, wa.y, hac[1][1]);
                    hac[1][2] = fmaf(x1, wa.z, hac[1][2]); hac[1][3] = fmaf(x1, wa.w, hac[1][3]);
                    hac[1][4] = fmaf(x1, wb.x, hac[1][4]); hac[1][5] = fmaf(x1, wb.y, hac[1][5]);
                    hac[1][6] = fmaf(x1, wb.z, hac[1][6]); hac[1][7] = fmaf(x1, wb.w, hac[1][7]);
                }
            }
        }
        #pragma unroll
        for (int u = 0; u < 2; ++u)
            #pragma unroll
            for (int v = 0; v < 8; ++v) Hsh[r0 + u][cg * 8 + v] = fb_gelu(hac[u][v]);
        __syncthreads();
        const float* w2p = w2e + (size_t)jp * HS + cg * 32;
        #pragma unroll 2
        for (int j = 0; j < FB_BJ; ++j) {
            float h0 = Hsh[r0][j], h1 = Hsh[r0 + 1][j];
            const float* wr = w2p + (size_t)j * HS;
            #pragma unroll
            for (int q = 0; q < 8; ++q) {
                float4 w4 = *reinterpret_cast<const float4*>(wr + q * 4);
                yac[0][q * 4 + 0] = fmaf(h0, w4.x, yac[0][q * 4 + 0]);
                yac[0][q * 4 + 1] = fmaf(h0, w4.y, yac[0][q * 4 + 1]);
                yac[0][q * 4 + 2] = fmaf(h0, w4.z, yac[0][q * 4 + 2]);
                yac[0][q * 4 + 3] = fmaf(h0, w4.w, yac[0][q * 4 + 3]);
                yac[1][q * 4 + 0] = fmaf(h1, w4.x, yac[1][q * 4 + 0]);
                yac[1][q * 4 + 1] = fmaf(h1, w4.y, yac[1][q * 4 + 1]);
                yac[1][q * 4 + 2] = fmaf(h1, w4.z, yac[1][q * 4 + 2]);
                yac[1][q * 4 + 3] = fmaf(h1, w4.w, yac[1][q * 4 + 3]);
            }
        }
    }
    #pragma unroll
    for (int u = 0; u < 2; ++u) {
        int a = rowa[r0 + u];
        if (a >= 0) {
            float* yp = ybuf + (size_t)a * HS + cg * 32;
            #pragma unroll
            for (int q = 0; q < 8; ++q) {
                float4 o = make_float4(yac[u][q * 4 + 0], yac[u][q * 4 + 1],
                                       yac[u][q * 4 + 2], yac[u][q * 4 + 3]);
                *reinterpret_cast<float4*>(yp + q * 4) = o;
            }
        }
    }
}

__global__ void fb_combine(const float* __restrict__ ybuf, const float* __restrict__ ew,
                           float* __restrict__ out) {
    int i = blockIdx.x * 256 + threadIdx.x;
    if (i >= T_TOK * HS / 4) return;
    int tk = i >> 7, c4 = i & 127;
    float wA = ew[2 * tk], wB = ew[2 * tk + 1];
    const float4* y4 = reinterpret_cast<const float4*>(ybuf);
    float4 a = y4[(size_t)(2 * tk) * (HS / 4) + c4];
    float4 b = y4[(size_t)(2 * tk + 1) * (HS / 4) + c4];
    float4 o;
    o.x = wA * a.x + wB * b.x; o.y = wA * a.y + wB * b.y;
    o.z = wA * a.z + wB * b.z; o.w = wA * a.w + wB * b.w;
    reinterpret_cast<float4*>(out)[i] = o;
}

// ================= launch =================
extern "C" void kernel_launch(void* const* d_in, const int* in_sizes, int n_in,
                              void* d_out, int out_size, void* d_ws, size_t ws_size,
                              hipStream_t stream) {
    const float* x  = (const float*)d_in[0];
    const float* ew = (const float*)d_in[1];
    const int*   ei = (const int*)d_in[2];
    const float* w1 = (const float*)d_in[3];
    const float* w2 = (const float*)d_in[4];
    float* out = (float*)d_out;
    char* W = (char*)d_ws;

    if (ws_size < WS_NEED) {
        int* cnt = (int*)d_ws;
        int* bucket = cnt + 64;
        float* ybuf = (float*)(W + (1 << 19));
        fb_init<<<1, 64, 0, stream>>>(cnt);
        fb_scatter<<<NA / 256, 256, 0, stream>>>(ei, cnt, bucket);
        fb_fused<<<NE * (NA / FB_BM), 256, 0, stream>>>(x, w1, w2, cnt, bucket, ybuf);
        fb_combine<<<(T_TOK * HS / 4 + 255) / 256, 256, 0, stream>>>(ybuf, ew, out);
        return;
    }

    int* cnt2  = (int*)(W + WS_CNT2);
    int* offp  = (int*)(W + WS_OFF);
    int* mexp  = (int*)(W + WS_MEXP);
    int* slots = (int*)(W + WS_SLOTS);
    int* inv   = (int*)(W + WS_INV);
    unsigned short* XB   = (unsigned short*)(W + WS_XB);
    unsigned short* W1T  = (unsigned short*)(W + WS_W1T);
    unsigned short* W2T  = (unsigned short*)(W + WS_W2T);
    unsigned short* HB   = (unsigned short*)(W + WS_HB);
    unsigned short* YPB0 = (unsigned short*)(W + WS_YPB0);
    unsigned short* YPB1 = (unsigned short*)(W + WS_YPB1);

    moe_prep<<<18468, 256, 0, stream>>>(slots, cnt2, x, XB, w1, W1T, w2, W2T);
    moe_fill<<<NA / 256, 256, 0, stream>>>(ei, cnt2, slots, inv, offp, mexp);
    moe_gemm1<<<8 * 9 * 16, 256, 0, stream>>>(XB, W1T, offp, mexp, slots, HB);
    moe_gemm2<<<8 * 9 * 8, 256, 0, stream>>>(HB, W2T, offp, mexp, YPB0, YPB1);
    moe_combine2<<<(T_TOK * HS / 8) / 256, 256, 0, stream>>>(YPB0, YPB1, inv, ew, out);
}

// Round 9
// 101.465 us; speedup vs baseline: 49.1415x; 1.2848x over previous
//
#include <hip/hip_runtime.h>
#include <stdint.h>

#define T_TOK 4096
#define KTOP  2
#define HS    512
#define FFN   2048
#define NE    8
#define NA    (T_TOK*KTOP)     // 8192 assignments
#define MT    128              // M-tile
#define BK    64               // K-step
#define MT_MAX 72              // 8 XCD chunks x 9
#define SLOT_CAP (MT_MAX*MT)   // 9216
#define PSTR 68                // epilogue LDS f32 stride
#define CPAD 32                // cnt2 padding: 1 counter per 128B line

// ---------------- workspace layout (bytes) ----------------
#define MB_ (1024ull*1024ull)
#define WS_CNT2  0u            // 8*32 ints (padded counters), [0,1024)
#define WS_OFF   1024u         // 9 ints
#define WS_MEXP  1088u         // 72 ints
#define WS_SLOTS 2048u         // 9216 ints -> [2048,38912)
#define WS_INV   40960u        // 8192 ints -> [40960,73728)
#define WS_XB   (1*MB_)        // 4MB  bf16 [4096][512]
#define WS_W1T  (5*MB_)        // 16MB bf16 [8][2048][512]
#define WS_W2T  (21*MB_)       // 16MB bf16 [8][512][2048]
#define WS_HB   (37*MB_)       // 36MB bf16 [9216][2048]
#define WS_YPB0 (73*MB_)       // 9MB bf16 [9216][512]
#define WS_YPB1 (82*MB_)       // 9MB
#define WS_NEED (91*MB_)

typedef short bf16x8 __attribute__((ext_vector_type(8)));
typedef float f32x4  __attribute__((ext_vector_type(4)));

__device__ __forceinline__ unsigned short f2bf(float f) {
    unsigned u = __builtin_bit_cast(unsigned, f);
    u += 0x7fffu + ((u >> 16) & 1u);          // RNE
    return (unsigned short)(u >> 16);
}
__device__ __forceinline__ float bf2f(unsigned short h) {
    return __builtin_bit_cast(float, (unsigned)h << 16);
}
// tanh-approx gelu (~10 VALU ops vs erff ~30; |err| <= ~3e-3; inf-safe both tails)
__device__ __forceinline__ float gelu_fast(float x) {
    float x2 = x * x;
    float inner = fmaf(0.044715f * x2, x, x);
    float E = __expf(1.5957691216057308f * inner);
    return x - x / (1.0f + E);
}
__device__ __forceinline__ void gl_lds16(const void* g, void* l) {
    __builtin_amdgcn_global_load_lds(
        (const __attribute__((address_space(1))) unsigned int*)g,
        (__attribute__((address_space(3))) unsigned int*)l, 16, 0, 0);
}

// ---------------- merged prep: cvt_x + w1T + w2T + slots/cnt2-init ----------------
// ranges: [0,2048) x->bf16 | [2048,10240) w1T | [10240,18432) w2T | [18432,18468) init
// No intra-kernel producer/consumer (R5 lesson): all consumers are later kernels.
__device__ __forceinline__ void transpose_cvt_body(
    const float* __restrict__ src, unsigned short* __restrict__ dh,
    int R, int C, int e, int kb, int nb, int t, float (*tile)[33])
{
    const int k0 = kb * 32, n0 = nb * 32;
    #pragma unroll
    for (int q = 0; q < 4; ++q) {
        int idx = t + q * 256, kk = idx >> 5, nn = idx & 31;
        tile[kk][nn] = src[((size_t)e * R + k0 + kk) * C + n0 + nn];
    }
    __syncthreads();
    #pragma unroll
    for (int q = 0; q < 4; ++q) {
        int idx = t + q * 256, nn = idx >> 5, kk = idx & 31;
        dh[((size_t)e * C + n0 + nn) * R + k0 + kk] = f2bf(tile[kk][nn]);
    }
}

__global__ void moe_prep(int* slots, int* cnt2,
                         const float* __restrict__ x, unsigned short* __restrict__ xb,
                         const float* __restrict__ w1, unsigned short* __restrict__ w1t,
                         const float* __restrict__ w2, unsigned short* __restrict__ w2t)
{
    __shared__ float tile[32][33];
    const int bid = blockIdx.x, t = threadIdx.x;
    if (bid < 2048) {                         // x -> bf16
        int i = bid * 256 + t;
        float4 v = reinterpret_cast<const float4*>(x)[i];
        uint2 p = { (unsigned)f2bf(v.x) | ((unsigned)f2bf(v.y) << 16),
                    (unsigned)f2bf(v.z) | ((unsigned)f2bf(v.w) << 16) };
        reinterpret_cast<uint2*>(xb)[i] = p;
    } else if (bid < 10240) {                 // w1 [e][HS][FFN] -> [e][FFN][HS]
        int lin = bid - 2048, e = lin >> 10, rem = lin & 1023;
        transpose_cvt_body(w1, w1t, HS, FFN, e, rem & 15, rem >> 4, t, tile);
    } else if (bid < 18432) {                 // w2 [e][FFN][HS] -> [e][HS][FFN]
        int lin = bid - 10240, e = lin >> 10, rem = lin & 1023;
        transpose_cvt_body(w2, w2t, FFN, HS, e, rem & 63, rem >> 6, t, tile);
    } else {                                  // slots=-1 + padded cnt2=0 (poison-safe)
        int gid = (bid - 18432) * 256 + t;
        if (gid < SLOT_CAP) slots[gid] = -1;
        if (gid < NE * CPAD) cnt2[gid] = 0;
    }
}

// fill: two-level rank reservation.
// Each block: full 8-bin histogram (LDS atomics, cheap) -> identical off_l;
// within-block ranks via LDS atomicAdd; ONE padded global atomicAdd per
// (block,expert) reserves a chunk (256 global atomics total vs 8192 same-line
// before -- the R8 45us stall). Block 0 publishes offp/mexp (sole writer).
__global__ void moe_fill(const int* __restrict__ eidx, int* cnt2, int* slots, int* inv,
                         int* offp, int* mexp) {
    __shared__ int h[NE];
    __shared__ int hloc[NE];
    __shared__ int bl[NE];
    __shared__ int off_l[NE + 1];
    const int t = threadIdx.x;
    if (t < NE) { h[t] = 0; hloc[t] = 0; }
    __syncthreads();
    for (int a2 = t; a2 < NA; a2 += 256) atomicAdd(&h[eidx[a2]], 1);
    const int a = blockIdx.x * 256 + t;       // NA % 256 == 0 -> always valid
    const int e = eidx[a];
    const int rank = atomicAdd(&hloc[e], 1);  // within-block rank (LDS, fast)
    __syncthreads();
    if (t == 0) {
        int run = 0;
        for (int q = 0; q < NE; ++q) { off_l[q] = run; run += ((h[q] + MT - 1) / MT) * MT; }
        off_l[NE] = run;
    }
    __syncthreads();
    if (t < NE) bl[t] = atomicAdd(&cnt2[t * CPAD], hloc[t]);  // chunk reservation
    if (blockIdx.x == 0) {
        if (t <= NE) offp[t] = off_l[t];
        if (t < MT_MAX) {                     // mexp[t]: expert owning tile t
            int m0 = t * MT, ee = 0;
            #pragma unroll
            for (int q = 0; q < NE; ++q)
                if (m0 >= off_l[q] && m0 < off_l[q + 1]) ee = q;
            mexp[t] = ee;
        }
    }
    __syncthreads();
    int s = off_l[e] + bl[e] + rank;
    slots[s] = a;        // order nondeterministic; per-assignment result isn't
    inv[a] = s;
}

// ---------------- grouped GEMM1: H = gelu(X @ W1), single-pass bf16 ----------------
// Grid 1152, chunked XCD affinity (mt = xcd*9 + part%9) -> expert weights L2-resident.
__global__ __launch_bounds__(256, 4) void moe_gemm1(
    const unsigned short* __restrict__ XB, const unsigned short* __restrict__ W1T,
    const int* __restrict__ offp, const int* __restrict__ mexp,
    const int* __restrict__ slots, unsigned short* __restrict__ HB)
{
    const int xcd = blockIdx.x & 7;
    const int part = blockIdx.x >> 3;     // 0..143
    const int mtg = part % 9;
    const int nt  = part / 9;             // 0..15
    const int mt  = xcd * 9 + mtg;
    if (mt * MT >= offp[NE]) return;
    const int e = mexp[mt];
    const int t = threadIdx.x, lane = t & 63, wv = t >> 6;

    __shared__ __align__(16) char POOL[MT * PSTR * 4];
    __shared__ int srow[MT];
    short* As = (short*)POOL;                 // 16KB [128][64] bf16, 8-group XOR swz
    short* Bs = (short*)(POOL + 16384);       // 16KB
    float* Pf = (float*)POOL;                 // epilogue overlay

    if (t < MT) { int s = slots[mt * MT + t]; srow[t] = (s < 0) ? 0 : (s >> 1); }
    __syncthreads();

    int baseA[4], baseB[4];
    #pragma unroll
    for (int q = 0; q < 4; ++q) {
        int i = wv * 4 + q;
        int row = i * 8 + (lane >> 3);
        int sg = (lane & 7) ^ (row & 7);      // source swz [rule 21: both sides]
        baseA[q] = srow[row] * HS + sg * 8;
        baseB[q] = (e * FFN + nt * MT + row) * HS + sg * 8;
    }

    const int wm = wv >> 1, wn = wv & 1, q4 = lane >> 4, l15 = lane & 15;
    int offA[2][4], offB[2][4];
    #pragma unroll
    for (int m = 0; m < 4; ++m) {
        int r  = wm * 64 + m * 16 + l15;
        int rb = wn * 64 + m * 16 + l15;
        #pragma unroll
        for (int ks = 0; ks < 2; ++ks) {
            offA[ks][m] = r  * 128 + ((((ks << 2) | q4) ^ (r  & 7)) << 4);
            offB[ks][m] = rb * 128 + ((((ks << 2) | q4) ^ (rb & 7)) << 4);
        }
    }

    f32x4 acc[4][4];
    #pragma unroll
    for (int m = 0; m < 4; ++m)
        #pragma unroll
        for (int n = 0; n < 4; ++n) { f32x4 z = {0.f, 0.f, 0.f, 0.f}; acc[m][n] = z; }

    for (int kk = 0; kk < HS; kk += BK) {
        __syncthreads();
        #pragma unroll
        for (int q = 0; q < 4; ++q) {
            int i = wv * 4 + q;
            gl_lds16(XB  + baseA[q] + kk, (char*)As + i * 1024);
            gl_lds16(W1T + baseB[q] + kk, (char*)Bs + i * 1024);
        }
        __syncthreads();
        #pragma unroll
        for (int ks = 0; ks < 2; ++ks) {
            bf16x8 a[4], b[4];
            #pragma unroll
            for (int m = 0; m < 4; ++m) {
                a[m] = *(const bf16x8*)((const char*)As + offA[ks][m]);
                b[m] = *(const bf16x8*)((const char*)Bs + offB[ks][m]);
            }
            #pragma unroll
            for (int m = 0; m < 4; ++m)
                #pragma unroll
                for (int n = 0; n < 4; ++n)
                    acc[m][n] = __builtin_amdgcn_mfma_f32_16x16x32_bf16(a[m], b[n], acc[m][n], 0, 0, 0);
        }
    }

    // epilogue: LDS transpose -> coalesced bf16x8 stores (fast gelu in read phase)
    #pragma unroll
    for (int half = 0; half < 2; ++half) {
        __syncthreads();
        if (wn == half) {
            #pragma unroll
            for (int m = 0; m < 4; ++m)
                #pragma unroll
                for (int n = 0; n < 4; ++n)
                    #pragma unroll
                    for (int j = 0; j < 4; ++j)
                        Pf[(wm * 64 + m * 16 + q4 * 4 + j) * PSTR + n * 16 + l15] = acc[m][n][j];
        }
        __syncthreads();
        #pragma unroll
        for (int q = 0; q < 4; ++q) {
            int seg = q * 256 + t, row = seg >> 3, c8 = (seg & 7) << 3;
            const float* p = Pf + row * PSTR + c8;
            float4 a = *(const float4*)p, b = *(const float4*)(p + 4);
            float va[8] = {a.x, a.y, a.z, a.w, b.x, b.y, b.z, b.w};
            bf16x8 ph;
            #pragma unroll
            for (int i = 0; i < 8; ++i) ph[i] = (short)f2bf(gelu_fast(va[i]));
            *(bf16x8*)(HB + (size_t)(mt * MT + row) * FFN + nt * MT + half * 64 + c8) = ph;
        }
    }
}

// ---------------- grouped GEMM2: Y = H @ W2, split-K=2, bf16 partials ----------------
__global__ __launch_bounds__(256, 4) void moe_gemm2(
    const unsigned short* __restrict__ HB, const unsigned short* __restrict__ W2T,
    const int* __restrict__ offp, const int* __restrict__ mexp,
    unsigned short* __restrict__ YPB0, unsigned short* __restrict__ YPB1)
{
    const int xcd = blockIdx.x & 7;
    const int part = blockIdx.x >> 3;     // 0..71
    const int mtg = part % 9;
    const int sub = part / 9;             // 0..7
    const int mt  = xcd * 9 + mtg;
    const int nt  = sub >> 1, kpart = sub & 1;
    if (mt * MT >= offp[NE]) return;
    const int e = mexp[mt];
    const int t = threadIdx.x, lane = t & 63, wv = t >> 6;

    __shared__ __align__(16) char POOL[MT * PSTR * 4];
    short* As = (short*)POOL;
    short* Bs = (short*)(POOL + 16384);
    float* Pf = (float*)POOL;

    int baseA[4], baseB[4];
    #pragma unroll
    for (int q = 0; q < 4; ++q) {
        int i = wv * 4 + q;
        int row = i * 8 + (lane >> 3);
        int sg = (lane & 7) ^ (row & 7);
        baseA[q] = (mt * MT + row) * FFN + sg * 8;
        baseB[q] = (e * HS + nt * MT + row) * FFN + sg * 8;
    }

    const int wm = wv >> 1, wn = wv & 1, q4 = lane >> 4, l15 = lane & 15;
    int offA[2][4], offB[2][4];
    #pragma unroll
    for (int m = 0; m < 4; ++m) {
        int r  = wm * 64 + m * 16 + l15;
        int rb = wn * 64 + m * 16 + l15;
        #pragma unroll
        for (int ks = 0; ks < 2; ++ks) {
            offA[ks][m] = r  * 128 + ((((ks << 2) | q4) ^ (r  & 7)) << 4);
            offB[ks][m] = rb * 128 + ((((ks << 2) | q4) ^ (rb & 7)) << 4);
        }
    }

    f32x4 acc[4][4];
    #pragma unroll
    for (int m = 0; m < 4; ++m)
        #pragma unroll
        for (int n = 0; n < 4; ++n) { f32x4 z = {0.f, 0.f, 0.f, 0.f}; acc[m][n] = z; }

    const int k0 = kpart * (FFN / 2), k1 = k0 + FFN / 2;
    for (int kk = k0; kk < k1; kk += BK) {
        __syncthreads();
        #pragma unroll
        for (int q = 0; q < 4; ++q) {
            int i = wv * 4 + q;
            gl_lds16(HB  + baseA[q] + kk, (char*)As + i * 1024);
            gl_lds16(W2T + baseB[q] + kk, (char*)Bs + i * 1024);
        }
        __syncthreads();
        #pragma unroll
        for (int ks = 0; ks < 2; ++ks) {
            bf16x8 a[4], b[4];
            #pragma unroll
            for (int m = 0; m < 4; ++m) {
                a[m] = *(const bf16x8*)((const char*)As + offA[ks][m]);
                b[m] = *(const bf16x8*)((const char*)Bs + offB[ks][m]);
            }
            #pragma unroll
            for (int m = 0; m < 4; ++m)
                #pragma unroll
                for (int n = 0; n < 4; ++n)
                    acc[m][n] = __builtin_amdgcn_mfma_f32_16x16x32_bf16(a[m], b[n], acc[m][n], 0, 0, 0);
        }
    }

    unsigned short* YP = kpart ? YPB1 : YPB0;
    #pragma unroll
    for (int half = 0; half < 2; ++half) {
        __syncthreads();
        if (wn == half) {
            #pragma unroll
            for (int m = 0; m < 4; ++m)
                #pragma unroll
                for (int n = 0; n < 4; ++n)
                    #pragma unroll
                    for (int j = 0; j < 4; ++j)
                        Pf[(wm * 64 + m * 16 + q4 * 4 + j) * PSTR + n * 16 + l15] = acc[m][n][j];
        }
        __syncthreads();
        #pragma unroll
        for (int q = 0; q < 4; ++q) {
            int seg = q * 256 + t, row = seg >> 3, c8 = (seg & 7) << 3;
            const float* p = Pf + row * PSTR + c8;
            float4 a = *(const float4*)p, b = *(const float4*)(p + 4);
            float va[8] = {a.x, a.y, a.z, a.w, b.x, b.y, b.z, b.w};
            bf16x8 ph;
            #pragma unroll
            for (int i = 0; i < 8; ++i) ph[i] = (short)f2bf(va[i]);
            *(bf16x8*)(YP + (size_t)(mt * MT + row) * HS + nt * MT + half * 64 + c8) = ph;
        }
    }
}

// ---------------- combine (bf16 partials) ----------------
__global__ void moe_combine2(const unsigned short* __restrict__ YPB0,
                             const unsigned short* __restrict__ YPB1,
                             const int* __restrict__ inv, const float* __restrict__ ew,
                             float* __restrict__ out) {
    int i = blockIdx.x * 256 + threadIdx.x;      // over T*HS/8 groups of 8
    if (i >= T_TOK * HS / 8) return;
    int tk = i >> 6, c8 = (i & 63) << 3;
    int s0 = inv[2 * tk], s1 = inv[2 * tk + 1];
    float w0 = ew[2 * tk], w1 = ew[2 * tk + 1];
    bf16x8 a0 = *(const bf16x8*)(YPB0 + (size_t)s0 * HS + c8);
    bf16x8 b0 = *(const bf16x8*)(YPB1 + (size_t)s0 * HS + c8);
    bf16x8 a1 = *(const bf16x8*)(YPB0 + (size_t)s1 * HS + c8);
    bf16x8 b1 = *(const bf16x8*)(YPB1 + (size_t)s1 * HS + c8);
    float o[8];
    #pragma unroll
    for (int j = 0; j < 8; ++j)
        o[j] = w0 * (bf2f((unsigned short)a0[j]) + bf2f((unsigned short)b0[j]))
             + w1 * (bf2f((unsigned short)a1[j]) + bf2f((unsigned short)b1[j]));
    float4* d = reinterpret_cast<float4*>(out + (size_t)i * 8);
    d[0] = make_float4(o[0], o[1], o[2], o[3]);
    d[1] = make_float4(o[4], o[5], o[6], o[7]);
}

// ================= fallback VALU path (proven baseline) =================
#define FB_BM 32
#define FB_BJ 128
#define FB_CK 256
#define FB_XSTR (FB_CK+4)
#define FB_HSTR (FB_BJ+4)

__device__ __forceinline__ float fb_gelu(float v) {
    return 0.5f * v * (1.0f + erff(v * 0.70710678118654752f));
}

__global__ void fb_init(int* cnt) { int i = threadIdx.x; if (i < NE) cnt[i] = 0; }

__global__ void fb_scatter(const int* __restrict__ eidx, int* cnt, int* bucket) {
    int a = blockIdx.x * 256 + threadIdx.x;
    if (a < NA) { int e = eidx[a]; int p = atomicAdd(&cnt[e], 1); bucket[e * NA + p] = a; }
}

__global__ __launch_bounds__(256, 1) void fb_fused(
    const float* __restrict__ x, const float* __restrict__ w1, const float* __restrict__ w2,
    const int* __restrict__ cnt, const int* __restrict__ bucket, float* __restrict__ ybuf)
{
    const int bid = blockIdx.x;
    const int e = bid & (NE - 1), tr = bid >> 3;
    const int n_e = cnt[e], rbase = tr * FB_BM;
    if (rbase >= n_e) return;
    const int t = threadIdx.x;
    __shared__ __align__(16) float Xc[FB_BM][FB_XSTR];
    __shared__ __align__(16) float Hsh[FB_BM][FB_HSTR];
    __shared__ int rowa[FB_BM];
    if (t < FB_BM) { int r = rbase + t; rowa[t] = (r < n_e) ? bucket[e * NA + r] : -1; }
    __syncthreads();
    const int cg = t & 15, rg = t >> 4, r0 = rg * 2;
    float yac[2][32];
    #pragma unroll
    for (int u = 0; u < 2; ++u)
        #pragma unroll
        for (int v = 0; v < 32; ++v) yac[u][v] = 0.0f;
    const float* w1e = w1 + (size_t)e * HS * FFN;
    const float* w2e = w2 + (size_t)e * FFN * HS;
    for (int jp = 0; jp < FFN; jp += FB_BJ) {
        float hac[2][8];
        #pragma unroll
        for (int u = 0; u < 2; ++u)
            #pragma unroll
            for (int v = 0; v < 8; ++v) hac[u][v] = 0.0f;
        for (int ic = 0; ic < HS; ic += FB_CK) {
            __syncthreads();
            #pragma unroll
            for (int q = 0; q < (FB_BM * FB_CK / 4) / 256; ++q) {
                int id = t + 256 * q, rr = id >> 6, c4 = id & 63;
                int a = rowa[rr];
                float4 val = make_float4(0.f, 0.f, 0.f, 0.f);
                if (a >= 0) val = *reinterpret_cast<const float4*>(x + (size_t)(a >> 1) * HS + ic + c4 * 4);
                *reinterpret_cast<float4*>(&Xc[rr][c4 * 4]) = val;
            }
            __syncthreads();
            const float* w1p = w1e + (size_t)ic * FFN + jp + cg * 8;
            #pragma unroll 2
            for (int i4 = 0; i4 < FB_CK; i4 += 4) {
                float4 xa = *reinterpret_cast<const float4*>(&Xc[r0][i4]);
                float4 xb = *reinterpret_cast<const float4*>(&Xc[r0 + 1][i4]);
                const float* wr0 = w1p + (size_t)i4 * FFN;
                #pragma unroll
                for (int ii = 0; ii < 4; ++ii) {
                    float4 wa = *reinterpret_cast<const float4*>(wr0 + (size_t)ii * FFN);
                    float4 wb = *reinterpret_cast<const float4*>(wr0 + (size_t)ii * FFN + 4);
                    float x0 = (ii == 0) ? xa.x : (ii == 1) ? xa.y : (ii == 2) ? xa.z : xa.w;
                    float x1 = (ii == 0) ? xb.x : (ii == 1) ? xb.y : (ii == 2) ? xb.z : xb.w;
                    hac[0][0] = fmaf(x0, wa.x, hac[0][0]); hac[0][1] = fmaf(x0, wa.y, hac[0][1]);
                    hac[0][2] = fmaf(x0, wa.z, hac[0][2]); hac[0][3] = fmaf(x0, wa.w, hac[0][3]);
                    hac[0][4] = fmaf(x0, wb.x, hac[0][4]); hac[0][5] = fmaf(x0, wb.y, hac[0][5]);
                    hac[0][6] = fmaf(x0, wb.z, hac[0][6]); hac[0][7] = fmaf(x0, wb.w, hac[0][7]);
                    hac[1][0] = fmaf(x1, wa.x, hac[1][0]); hac[1][1] = fmaf(x1, wa.y, hac[1][1]);
                    hac[1][2] = fmaf(x1, wa.z, hac[1][2]); hac[1][3] = fmaf(x1, wa.w, hac[1][3]);
                    hac[1][4] = fmaf(x1, wb.x, hac[1][4]); hac[1][5] = fmaf(x1, wb.y, hac[1][5]);
                    hac[1][6] = fmaf(x1, wb.z, hac[1][6]); hac[1][7] = fmaf(x1, wb.w, hac[1][7]);
                }
            }
        }
        #pragma unroll
        for (int u = 0; u < 2; ++u)
            #pragma unroll
            for (int v = 0; v < 8; ++v) Hsh[r0 + u][cg * 8 + v] = fb_gelu(hac[u][v]);
        __syncthreads();
        const float* w2p = w2e + (size_t)jp * HS + cg * 32;
        #pragma unroll 2
        for (int j = 0; j < FB_BJ; ++j) {
            float h0 = Hsh[r0][j], h1 = Hsh[r0 + 1][j];
            const float* wr = w2p + (size_t)j * HS;
            #pragma unroll
            for (int q = 0; q < 8; ++q) {
                float4 w4 = *reinterpret_cast<const float4*>(wr + q * 4);
                yac[0][q * 4 + 0] = fmaf(h0, w4.x, yac[0][q * 4 + 0]);
                yac[0][q * 4 + 1] = fmaf(h0, w4.y, yac[0][q * 4 + 1]);
                yac[0][q * 4 + 2] = fmaf(h0, w4.z, yac[0][q * 4 + 2]);
                yac[0][q * 4 + 3] = fmaf(h0, w4.w, yac[0][q * 4 + 3]);
                yac[1][q * 4 + 0] = fmaf(h1, w4.x, yac[1][q * 4 + 0]);
                yac[1][q * 4 + 1] = fmaf(h1, w4.y, yac[1][q * 4 + 1]);
                yac[1][q * 4 + 2] = fmaf(h1, w4.z, yac[1][q * 4 + 2]);
                yac[1][q * 4 + 3] = fmaf(h1, w4.w, yac[1][q * 4 + 3]);
            }
        }
    }
    #pragma unroll
    for (int u = 0; u < 2; ++u) {
        int a = rowa[r0 + u];
        if (a >= 0) {
            float* yp = ybuf + (size_t)a * HS + cg * 32;
            #pragma unroll
            for (int q = 0; q < 8; ++q) {
                float4 o = make_float4(yac[u][q * 4 + 0], yac[u][q * 4 + 1],
                                       yac[u][q * 4 + 2], yac[u][q * 4 + 3]);
                *reinterpret_cast<float4*>(yp + q * 4) = o;
            }
        }
    }
}

__global__ void fb_combine(const float* __restrict__ ybuf, const float* __restrict__ ew,
                           float* __restrict__ out) {
    int i = blockIdx.x * 256 + threadIdx.x;
    if (i >= T_TOK * HS / 4) return;
    int tk = i >> 7, c4 = i & 127;
    float wA = ew[2 * tk], wB = ew[2 * tk + 1];
    const float4* y4 = reinterpret_cast<const float4*>(ybuf);
    float4 a = y4[(size_t)(2 * tk) * (HS / 4) + c4];
    float4 b = y4[(size_t)(2 * tk + 1) * (HS / 4) + c4];
    float4 o;
    o.x = wA * a.x + wB * b.x; o.y = wA * a.y + wB * b.y;
    o.z = wA * a.z + wB * b.z; o.w = wA * a.w + wB * b.w;
    reinterpret_cast<float4*>(out)[i] = o;
}

// ================= launch =================
extern "C" void kernel_launch(void* const* d_in, const int* in_sizes, int n_in,
                              void* d_out, int out_size, void* d_ws, size_t ws_size,
                              hipStream_t stream) {
    const float* x  = (const float*)d_in[0];
    const float* ew = (const float*)d_in[1];
    const int*   ei = (const int*)d_in[2];
    const float* w1 = (const float*)d_in[3];
    const float* w2 = (const float*)d_in[4];
    float* out = (float*)d_out;
    char* W = (char*)d_ws;

    if (ws_size < WS_NEED) {
        int* cnt = (int*)d_ws;
        int* bucket = cnt + 64;
        float* ybuf = (float*)(W + (1 << 19));
        fb_init<<<1, 64, 0, stream>>>(cnt);
        fb_scatter<<<NA / 256, 256, 0, stream>>>(ei, cnt, bucket);
        fb_fused<<<NE * (NA / FB_BM), 256, 0, stream>>>(x, w1, w2, cnt, bucket, ybuf);
        fb_combine<<<(T_TOK * HS / 4 + 255) / 256, 256, 0, stream>>>(ybuf, ew, out);
        return;
    }

    int* cnt2  = (int*)(W + WS_CNT2);
    int* offp  = (int*)(W + WS_OFF);
    int* mexp  = (int*)(W + WS_MEXP);
    int* slots = (int*)(W + WS_SLOTS);
    int* inv   = (int*)(W + WS_INV);
    unsigned short* XB   = (unsigned short*)(W + WS_XB);
    unsigned short* W1T  = (unsigned short*)(W + WS_W1T);
    unsigned short* W2T  = (unsigned short*)(W + WS_W2T);
    unsigned short* HB   = (unsigned short*)(W + WS_HB);
    unsigned short* YPB0 = (unsigned short*)(W + WS_YPB0);
    unsigned short* YPB1 = (unsigned short*)(W + WS_YPB1);

    moe_prep<<<18468, 256, 0, stream>>>(slots, cnt2, x, XB, w1, W1T, w2, W2T);
    moe_fill<<<NA / 256, 256, 0, stream>>>(ei, cnt2, slots, inv, offp, mexp);
    moe_gemm1<<<8 * 9 * 16, 256, 0, stream>>>(XB, W1T, offp, mexp, slots, HB);
    moe_gemm2<<<8 * 9 * 8, 256, 0, stream>>>(HB, W2T, offp, mexp, YPB0, YPB1);
    moe_combine2<<<(T_TOK * HS / 8) / 256, 256, 0, stream>>>(YPB0, YPB1, inv, ew, out);
}

// Round 10
// 101.249 us; speedup vs baseline: 49.2466x; 1.0021x over previous
//
#include <hip/hip_runtime.h>
#include <stdint.h>

#define T_TOK 4096
#define KTOP  2
#define HS    512
#define FFN   2048
#define NE    8
#define NA    (T_TOK*KTOP)     // 8192 assignments
#define MT    128              // M-tile
#define BK    64               // K-step
#define MT_MAX 72              // 8 XCD chunks x 9
#define SLOT_CAP (MT_MAX*MT)   // 9216
#define PSTR 68                // epilogue LDS f32 stride

// ---------------- workspace layout (bytes) ----------------
#define MB_ (1024ull*1024ull)
#define WS_OFF   1024u         // 9 ints
#define WS_MEXP  1088u         // 72 ints
#define WS_SLOTS 2048u         // 9216 ints
#define WS_INV   40960u        // 8192 ints
#define WS_XB   (1*MB_)        // 4MB  bf16 [4096][512]
#define WS_W1T  (5*MB_)        // 16MB bf16 [8][2048][512]
#define WS_W2T  (21*MB_)       // 16MB bf16 [8][512][2048]
#define WS_HB   (37*MB_)       // 36MB bf16 [9216][2048]
#define WS_YPB0 (73*MB_)       // 9MB bf16 [9216][512]
#define WS_YPB1 (82*MB_)       // 9MB
#define WS_NEED (91*MB_)

typedef short bf16x8 __attribute__((ext_vector_type(8)));
typedef float f32x4  __attribute__((ext_vector_type(4)));

__device__ __forceinline__ unsigned short f2bf(float f) {
    unsigned u = __builtin_bit_cast(unsigned, f);
    u += 0x7fffu + ((u >> 16) & 1u);          // RNE
    return (unsigned short)(u >> 16);
}
__device__ __forceinline__ float bf2f(unsigned short h) {
    return __builtin_bit_cast(float, (unsigned)h << 16);
}
// tanh-approx gelu (~10 VALU ops vs erff ~30; |err| <= ~3e-3; inf-safe both tails)
__device__ __forceinline__ float gelu_fast(float x) {
    float x2 = x * x;
    float inner = fmaf(0.044715f * x2, x, x);
    float E = __expf(1.5957691216057308f * inner);
    return x - x / (1.0f + E);
}
__device__ __forceinline__ void gl_lds16(const void* g, void* l) {
    __builtin_amdgcn_global_load_lds(
        (const __attribute__((address_space(1))) unsigned int*)g,
        (__attribute__((address_space(3))) unsigned int*)l, 16, 0, 0);
}

// ---------------- merged prep: cvt_x + w1T + w2T + deterministic routing ----------------
// ranges: [0,2048) x->bf16 | [2048,10240) w1T | [10240,18432) w2T |
//         [18432,18464) fill (256 assignments each, rank-based, NO atomics on global) |
//         [18464] pads + offp + mexp.
// Every range writes disjoint data consumed only by LATER kernels (R5 lesson).
// Routing is fully deterministic: slot = off[e] + prefix_count + local_rank.
__device__ __forceinline__ void transpose_cvt_body(
    const float* __restrict__ src, unsigned short* __restrict__ dh,
    int R, int C, int e, int kb, int nb, int t, float (*tile)[33])
{
    const int k0 = kb * 32, n0 = nb * 32;
    #pragma unroll
    for (int q = 0; q < 4; ++q) {
        int idx = t + q * 256, kk = idx >> 5, nn = idx & 31;
        tile[kk][nn] = src[((size_t)e * R + k0 + kk) * C + n0 + nn];
    }
    __syncthreads();
    #pragma unroll
    for (int q = 0; q < 4; ++q) {
        int idx = t + q * 256, nn = idx >> 5, kk = idx & 31;
        dh[((size_t)e * C + n0 + nn) * R + k0 + kk] = f2bf(tile[kk][nn]);
    }
}

__global__ void moe_prep(const int* __restrict__ eidx,
                         int* slots, int* inv, int* offp, int* mexp,
                         const float* __restrict__ x, unsigned short* __restrict__ xb,
                         const float* __restrict__ w1, unsigned short* __restrict__ w1t,
                         const float* __restrict__ w2, unsigned short* __restrict__ w2t)
{
    __shared__ float tile[32][33];
    const int bid = blockIdx.x, t = threadIdx.x;
    if (bid < 2048) {                         // x -> bf16
        int i = bid * 256 + t;
        float4 v = reinterpret_cast<const float4*>(x)[i];
        uint2 p = { (unsigned)f2bf(v.x) | ((unsigned)f2bf(v.y) << 16),
                    (unsigned)f2bf(v.z) | ((unsigned)f2bf(v.w) << 16) };
        reinterpret_cast<uint2*>(xb)[i] = p;
    } else if (bid < 10240) {                 // w1 [e][HS][FFN] -> [e][FFN][HS]
        int lin = bid - 2048, e = lin >> 10, rem = lin & 1023;
        transpose_cvt_body(w1, w1t, HS, FFN, e, rem & 15, rem >> 4, t, tile);
    } else if (bid < 18432) {                 // w2 [e][FFN][HS] -> [e][HS][FFN]
        int lin = bid - 10240, e = lin >> 10, rem = lin & 1023;
        transpose_cvt_body(w2, w2t, FFN, HS, e, rem & 63, rem >> 6, t, tile);
    } else {                                  // deterministic routing
        __shared__ int hfull[NE], hpre[NE], elocal[256];
        __shared__ int off_l[NE + 1];
        const int f = bid - 18432;            // 0..32
        if (t < NE) { hfull[t] = 0; hpre[t] = 0; }
        __syncthreads();
        const int base = f * 256;             // f==32 -> base==NA (no local slice)
        for (int i = t; i < NA; i += 256) {
            int ee = eidx[i];
            atomicAdd(&hfull[ee], 1);         // LDS atomics: cheap
            if (i < base) atomicAdd(&hpre[ee], 1);
        }
        if (f < 32) elocal[t] = eidx[base + t];
        __syncthreads();
        if (t == 0) {
            int run = 0;
            for (int q = 0; q < NE; ++q) { off_l[q] = run; run += ((hfull[q] + MT - 1) / MT) * MT; }
            off_l[NE] = run;
        }
        __syncthreads();
        if (f < 32) {
            int a = base + t, e = elocal[t];
            int rank = 0;
            for (int j = 0; j < t; ++j) rank += (elocal[j] == e) ? 1 : 0;
            int s = off_l[e] + hpre[e] + rank;
            slots[s] = a;                     // deterministic (stable order)
            inv[a] = s;
        } else {
            for (int e = 0; e < NE; ++e)
                for (int s = off_l[e] + hfull[e] + t; s < off_l[e + 1]; s += 256)
                    slots[s] = -1;            // pads (poison-safe each call)
            for (int s = off_l[NE] + t; s < SLOT_CAP; s += 256) slots[s] = -1;
            if (t <= NE) offp[t] = off_l[t];
            if (t < MT_MAX) {                 // mexp[t]: expert owning tile t
                int m0 = t * MT, ee = 0;
                #pragma unroll
                for (int q = 0; q < NE; ++q)
                    if (m0 >= off_l[q] && m0 < off_l[q + 1]) ee = q;
                mexp[t] = ee;
            }
        }
    }
}

// ---------------- grouped GEMM1: H = gelu(X @ W1), single-pass bf16 ----------------
// Grid 1152, chunked XCD affinity (mt = xcd*9 + part%9) -> expert weights L2-resident
// (R6: FETCH 149->49MB). mtg-fast is right here: per-XCD A set 1.15MB fits L2.
__global__ __launch_bounds__(256, 4) void moe_gemm1(
    const unsigned short* __restrict__ XB, const unsigned short* __restrict__ W1T,
    const int* __restrict__ offp, const int* __restrict__ mexp,
    const int* __restrict__ slots, unsigned short* __restrict__ HB)
{
    const int xcd = blockIdx.x & 7;
    const int part = blockIdx.x >> 3;     // 0..143
    const int mtg = part % 9;
    const int nt  = part / 9;             // 0..15
    const int mt  = xcd * 9 + mtg;
    if (mt * MT >= offp[NE]) return;
    const int e = mexp[mt];
    const int t = threadIdx.x, lane = t & 63, wv = t >> 6;

    __shared__ __align__(16) char POOL[MT * PSTR * 4];
    __shared__ int srow[MT];
    short* As = (short*)POOL;                 // 16KB [128][64] bf16, 8-group XOR swz
    short* Bs = (short*)(POOL + 16384);       // 16KB
    float* Pf = (float*)POOL;                 // epilogue overlay

    if (t < MT) { int s = slots[mt * MT + t]; srow[t] = (s < 0) ? 0 : (s >> 1); }
    __syncthreads();

    int baseA[4], baseB[4];
    #pragma unroll
    for (int q = 0; q < 4; ++q) {
        int i = wv * 4 + q;
        int row = i * 8 + (lane >> 3);
        int sg = (lane & 7) ^ (row & 7);      // source swz [rule 21: both sides]
        baseA[q] = srow[row] * HS + sg * 8;
        baseB[q] = (e * FFN + nt * MT + row) * HS + sg * 8;
    }

    const int wm = wv >> 1, wn = wv & 1, q4 = lane >> 4, l15 = lane & 15;
    int offA[2][4], offB[2][4];
    #pragma unroll
    for (int m = 0; m < 4; ++m) {
        int r  = wm * 64 + m * 16 + l15;
        int rb = wn * 64 + m * 16 + l15;
        #pragma unroll
        for (int ks = 0; ks < 2; ++ks) {
            offA[ks][m] = r  * 128 + ((((ks << 2) | q4) ^ (r  & 7)) << 4);
            offB[ks][m] = rb * 128 + ((((ks << 2) | q4) ^ (rb & 7)) << 4);
        }
    }

    f32x4 acc[4][4];
    #pragma unroll
    for (int m = 0; m < 4; ++m)
        #pragma unroll
        for (int n = 0; n < 4; ++n) { f32x4 z = {0.f, 0.f, 0.f, 0.f}; acc[m][n] = z; }

    for (int kk = 0; kk < HS; kk += BK) {
        __syncthreads();
        #pragma unroll
        for (int q = 0; q < 4; ++q) {
            int i = wv * 4 + q;
            gl_lds16(XB  + baseA[q] + kk, (char*)As + i * 1024);
            gl_lds16(W1T + baseB[q] + kk, (char*)Bs + i * 1024);
        }
        __syncthreads();
        #pragma unroll
        for (int ks = 0; ks < 2; ++ks) {
            bf16x8 a[4], b[4];
            #pragma unroll
            for (int m = 0; m < 4; ++m) {
                a[m] = *(const bf16x8*)((const char*)As + offA[ks][m]);
                b[m] = *(const bf16x8*)((const char*)Bs + offB[ks][m]);
            }
            #pragma unroll
            for (int m = 0; m < 4; ++m)
                #pragma unroll
                for (int n = 0; n < 4; ++n)
                    acc[m][n] = __builtin_amdgcn_mfma_f32_16x16x32_bf16(a[m], b[n], acc[m][n], 0, 0, 0);
        }
    }

    // epilogue: LDS transpose -> coalesced bf16x8 stores (fast gelu in read phase)
    #pragma unroll
    for (int half = 0; half < 2; ++half) {
        __syncthreads();
        if (wn == half) {
            #pragma unroll
            for (int m = 0; m < 4; ++m)
                #pragma unroll
                for (int n = 0; n < 4; ++n)
                    #pragma unroll
                    for (int j = 0; j < 4; ++j)
                        Pf[(wm * 64 + m * 16 + q4 * 4 + j) * PSTR + n * 16 + l15] = acc[m][n][j];
        }
        __syncthreads();
        #pragma unroll
        for (int q = 0; q < 4; ++q) {
            int seg = q * 256 + t, row = seg >> 3, c8 = (seg & 7) << 3;
            const float* p = Pf + row * PSTR + c8;
            float4 a = *(const float4*)p, b = *(const float4*)(p + 4);
            float va[8] = {a.x, a.y, a.z, a.w, b.x, b.y, b.z, b.w};
            bf16x8 ph;
            #pragma unroll
            for (int i = 0; i < 8; ++i) ph[i] = (short)f2bf(gelu_fast(va[i]));
            *(bf16x8*)(HB + (size_t)(mt * MT + row) * FFN + nt * MT + half * 64 + c8) = ph;
        }
    }
}

// ---------------- grouped GEMM2: Y = H @ W2, split-K=2, bf16 partials ----------------
// Grid 576. sub-FAST decode: the 8 concurrent blocks on one XCD are all (nt,kpart)
// jobs of ONE mt -> A panel (512KB) fetched once, B (<=2.2MB/XCD) survives L2
// across mtg rounds (round set 2.5MB < 4MB). Fixes the A-panel L2 thrash of the
// old mtg-fast decode (per-XCD A set 4.5MB > 4MB -> ~8x refetch).
__global__ __launch_bounds__(256, 4) void moe_gemm2(
    const unsigned short* __restrict__ HB, const unsigned short* __restrict__ W2T,
    const int* __restrict__ offp, const int* __restrict__ mexp,
    unsigned short* __restrict__ YPB0, unsigned short* __restrict__ YPB1)
{
    const int xcd = blockIdx.x & 7;
    const int part = blockIdx.x >> 3;     // 0..71
    const int sub = part % 8;             // FAST: share one mt's A panel
    const int mtg = part / 8;             // 0..8
    const int mt  = xcd * 9 + mtg;
    const int nt  = sub >> 1, kpart = sub & 1;
    if (mt * MT >= offp[NE]) return;
    const int e = mexp[mt];
    const int t = threadIdx.x, lane = t & 63, wv = t >> 6;

    __shared__ __align__(16) char POOL[MT * PSTR * 4];
    short* As = (short*)POOL;
    short* Bs = (short*)(POOL + 16384);
    float* Pf = (float*)POOL;

    int baseA[4], baseB[4];
    #pragma unroll
    for (int q = 0; q < 4; ++q) {
        int i = wv * 4 + q;
        int row = i * 8 + (lane >> 3);
        int sg = (lane & 7) ^ (row & 7);
        baseA[q] = (mt * MT + row) * FFN + sg * 8;
        baseB[q] = (e * HS + nt * MT + row) * FFN + sg * 8;
    }

    const int wm = wv >> 1, wn = wv & 1, q4 = lane >> 4, l15 = lane & 15;
    int offA[2][4], offB[2][4];
    #pragma unroll
    for (int m = 0; m < 4; ++m) {
        int r  = wm * 64 + m * 16 + l15;
        int rb = wn * 64 + m * 16 + l15;
        #pragma unroll
        for (int ks = 0; ks < 2; ++ks) {
            offA[ks][m] = r  * 128 + ((((ks << 2) | q4) ^ (r  & 7)) << 4);
            offB[ks][m] = rb * 128 + ((((ks << 2) | q4) ^ (rb & 7)) << 4);
        }
    }

    f32x4 acc[4][4];
    #pragma unroll
    for (int m = 0; m < 4; ++m)
        #pragma unroll
        for (int n = 0; n < 4; ++n) { f32x4 z = {0.f, 0.f, 0.f, 0.f}; acc[m][n] = z; }

    const int k0 = kpart * (FFN / 2), k1 = k0 + FFN / 2;
    for (int kk = k0; kk < k1; kk += BK) {
        __syncthreads();
        #pragma unroll
        for (int q = 0; q < 4; ++q) {
            int i = wv * 4 + q;
            gl_lds16(HB  + baseA[q] + kk, (char*)As + i * 1024);
            gl_lds16(W2T + baseB[q] + kk, (char*)Bs + i * 1024);
        }
        __syncthreads();
        #pragma unroll
        for (int ks = 0; ks < 2; ++ks) {
            bf16x8 a[4], b[4];
            #pragma unroll
            for (int m = 0; m < 4; ++m) {
                a[m] = *(const bf16x8*)((const char*)As + offA[ks][m]);
                b[m] = *(const bf16x8*)((const char*)Bs + offB[ks][m]);
            }
            #pragma unroll
            for (int m = 0; m < 4; ++m)
                #pragma unroll
                for (int n = 0; n < 4; ++n)
                    acc[m][n] = __builtin_amdgcn_mfma_f32_16x16x32_bf16(a[m], b[n], acc[m][n], 0, 0, 0);
        }
    }

    unsigned short* YP = kpart ? YPB1 : YPB0;
    #pragma unroll
    for (int half = 0; half < 2; ++half) {
        __syncthreads();
        if (wn == half) {
            #pragma unroll
            for (int m = 0; m < 4; ++m)
                #pragma unroll
                for (int n = 0; n < 4; ++n)
                    #pragma unroll
                    for (int j = 0; j < 4; ++j)
                        Pf[(wm * 64 + m * 16 + q4 * 4 + j) * PSTR + n * 16 + l15] = acc[m][n][j];
        }
        __syncthreads();
        #pragma unroll
        for (int q = 0; q < 4; ++q) {
            int seg = q * 256 + t, row = seg >> 3, c8 = (seg & 7) << 3;
            const float* p = Pf + row * PSTR + c8;
            float4 a = *(const float4*)p, b = *(const float4*)(p + 4);
            float va[8] = {a.x, a.y, a.z, a.w, b.x, b.y, b.z, b.w};
            bf16x8 ph;
            #pragma unroll
            for (int i = 0; i < 8; ++i) ph[i] = (short)f2bf(va[i]);
            *(bf16x8*)(YP + (size_t)(mt * MT + row) * HS + nt * MT + half * 64 + c8) = ph;
        }
    }
}

// ---------------- combine (bf16 partials) ----------------
__global__ void moe_combine2(const unsigned short* __restrict__ YPB0,
                             const unsigned short* __restrict__ YPB1,
                             const int* __restrict__ inv, const float* __restrict__ ew,
                             float* __restrict__ out) {
    int i = blockIdx.x * 256 + threadIdx.x;      // over T*HS/8 groups of 8
    if (i >= T_TOK * HS / 8) return;
    int tk = i >> 6, c8 = (i & 63) << 3;
    int s0 = inv[2 * tk], s1 = inv[2 * tk + 1];
    float w0 = ew[2 * tk], w1 = ew[2 * tk + 1];
    bf16x8 a0 = *(const bf16x8*)(YPB0 + (size_t)s0 * HS + c8);
    bf16x8 b0 = *(const bf16x8*)(YPB1 + (size_t)s0 * HS + c8);
    bf16x8 a1 = *(const bf16x8*)(YPB0 + (size_t)s1 * HS + c8);
    bf16x8 b1 = *(const bf16x8*)(YPB1 + (size_t)s1 * HS + c8);
    float o[8];
    #pragma unroll
    for (int j = 0; j < 8; ++j)
        o[j] = w0 * (bf2f((unsigned short)a0[j]) + bf2f((unsigned short)b0[j]))
             + w1 * (bf2f((unsigned short)a1[j]) + bf2f((unsigned short)b1[j]));
    float4* d = reinterpret_cast<float4*>(out + (size_t)i * 8);
    d[0] = make_float4(o[0], o[1], o[2], o[3]);
    d[1] = make_float4(o[4], o[5], o[6], o[7]);
}

// ================= fallback VALU path (proven baseline) =================
#define FB_BM 32
#define FB_BJ 128
#define FB_CK 256
#define FB_XSTR (FB_CK+4)
#define FB_HSTR (FB_BJ+4)

__device__ __forceinline__ float fb_gelu(float v) {
    return 0.5f * v * (1.0f + erff(v * 0.70710678118654752f));
}

__global__ void fb_init(int* cnt) { int i = threadIdx.x; if (i < NE) cnt[i] = 0; }

__global__ void fb_scatter(const int* __restrict__ eidx, int* cnt, int* bucket) {
    int a = blockIdx.x * 256 + threadIdx.x;
    if (a < NA) { int e = eidx[a]; int p = atomicAdd(&cnt[e], 1); bucket[e * NA + p] = a; }
}

__global__ __launch_bounds__(256, 1) void fb_fused(
    const float* __restrict__ x, const float* __restrict__ w1, const float* __restrict__ w2,
    const int* __restrict__ cnt, const int* __restrict__ bucket, float* __restrict__ ybuf)
{
    const int bid = blockIdx.x;
    const int e = bid & (NE - 1), tr = bid >> 3;
    const int n_e = cnt[e], rbase = tr * FB_BM;
    if (rbase >= n_e) return;
    const int t = threadIdx.x;
    __shared__ __align__(16) float Xc[FB_BM][FB_XSTR];
    __shared__ __align__(16) float Hsh[FB_BM][FB_HSTR];
    __shared__ int rowa[FB_BM];
    if (t < FB_BM) { int r = rbase + t; rowa[t] = (r < n_e) ? bucket[e * NA + r] : -1; }
    __syncthreads();
    const int cg = t & 15, rg = t >> 4, r0 = rg * 2;
    float yac[2][32];
    #pragma unroll
    for (int u = 0; u < 2; ++u)
        #pragma unroll
        for (int v = 0; v < 32; ++v) yac[u][v] = 0.0f;
    const float* w1e = w1 + (size_t)e * HS * FFN;
    const float* w2e = w2 + (size_t)e * FFN * HS;
    for (int jp = 0; jp < FFN; jp += FB_BJ) {
        float hac[2][8];
        #pragma unroll
        for (int u = 0; u < 2; ++u)
            #pragma unroll
            for (int v = 0; v < 8; ++v) hac[u][v] = 0.0f;
        for (int ic = 0; ic < HS; ic += FB_CK) {
            __syncthreads();
            #pragma unroll
            for (int q = 0; q < (FB_BM * FB_CK / 4) / 256; ++q) {
                int id = t + 256 * q, rr = id >> 6, c4 = id & 63;
                int a = rowa[rr];
                float4 val = make_float4(0.f, 0.f, 0.f, 0.f);
                if (a >= 0) val = *reinterpret_cast<const float4*>(x + (size_t)(a >> 1) * HS + ic + c4 * 4);
                *reinterpret_cast<float4*>(&Xc[rr][c4 * 4]) = val;
            }
            __syncthreads();
            const float* w1p = w1e + (size_t)ic * FFN + jp + cg * 8;
            #pragma unroll 2
            for (int i4 = 0; i4 < FB_CK; i4 += 4) {
                float4 xa = *reinterpret_cast<const float4*>(&Xc[r0][i4]);
                float4 xb = *reinterpret_cast<const float4*>(&Xc[r0 + 1][i4]);
                const float* wr0 = w1p + (size_t)i4 * FFN;
                #pragma unroll
                for (int ii = 0; ii < 4; ++ii) {
                    float4 wa = *reinterpret_cast<const float4*>(wr0 + (size_t)ii * FFN);
                    float4 wb = *reinterpret_cast<const float4*>(wr0 + (size_t)ii * FFN + 4);
                    float x0 = (ii == 0) ? xa.x : (ii == 1) ? xa.y : (ii == 2) ? xa.z : xa.w;
                    float x1 = (ii == 0) ? xb.x : (ii == 1) ? xb.y : (ii == 2) ? xb.z : xb.w;
                    hac[0][0] = fmaf(x0, wa.x, hac[0][0]); hac[0][1] = fmaf(x0, wa.y, hac[0][1]);
                    hac[0][2] = fmaf(x0, wa.z, hac[0][2]); hac[0][3] = fmaf(x0, wa.w, hac[0][3]);
                    hac[0][4] = fmaf(x0, wb.x, hac[0][4]); hac[0][5] = fmaf(x0, wb.y, hac[0][5]);
                    hac[0][6] = fmaf(x0, wb.z, hac[0][6]); hac[0][7] = fmaf(x0, wb.w, hac[0][7]);
                    hac[1][0] = fmaf(x1, wa.x, hac[1][0]); hac[1][1] = fmaf(x1, wa.y, hac[1][1]);
                    hac[1][2] = fmaf(x1, wa.z, hac[1][2]); hac[1][3] = fmaf(x1, wa.w, hac[1][3]);
                    hac[1][4] = fmaf(x1, wb.x, hac[1][4]); hac[1][5] = fmaf(x1, wb.y, hac[1][5]);
                    hac[1][6] = fmaf(x1, wb.z, hac[1][6]); hac[1][7] = fmaf(x1, wb.w, hac[1][7]);
                }
            }
        }
        #pragma unroll
        for (int u = 0; u < 2; ++u)
            #pragma unroll
            for (int v = 0; v < 8; ++v) Hsh[r0 + u][cg * 8 + v] = fb_gelu(hac[u][v]);
        __syncthreads();
        const float* w2p = w2e + (size_t)jp * HS + cg * 32;
        #pragma unroll 2
        for (int j = 0; j < FB_BJ; ++j) {
            float h0 = Hsh[r0][j], h1 = Hsh[r0 + 1][j];
            const float* wr = w2p + (size_t)j * HS;
            #pragma unroll
            for (int q = 0; q < 8; ++q) {
                float4 w4 = *reinterpret_cast<const float4*>(wr + q * 4);
                yac[0][q * 4 + 0] = fmaf(h0, w4.x, yac[0][q * 4 + 0]);
                yac[0][q * 4 + 1] = fmaf(h0, w4.y, yac[0][q * 4 + 1]);
                yac[0][q * 4 + 2] = fmaf(h0, w4.z, yac[0][q * 4 + 2]);
                yac[0][q * 4 + 3] = fmaf(h0, w4.w, yac[0][q * 4 + 3]);
                yac[1][q * 4 + 0] = fmaf(h1, w4.x, yac[1][q * 4 + 0]);
                yac[1][q * 4 + 1] = fmaf(h1, w4.y, yac[1][q * 4 + 1]);
                yac[1][q * 4 + 2] = fmaf(h1, w4.z, yac[1][q * 4 + 2]);
                yac[1][q * 4 + 3] = fmaf(h1, w4.w, yac[1][q * 4 + 3]);
            }
        }
    }
    #pragma unroll
    for (int u = 0; u < 2; ++u) {
        int a = rowa[r0 + u];
        if (a >= 0) {
            float* yp = ybuf + (size_t)a * HS + cg * 32;
            #pragma unroll
            for (int q = 0; q < 8; ++q) {
                float4 o = make_float4(yac[u][q * 4 + 0], yac[u][q * 4 + 1],
                                       yac[u][q * 4 + 2], yac[u][q * 4 + 3]);
                *reinterpret_cast<float4*>(yp + q * 4) = o;
            }
        }
    }
}

__global__ void fb_combine(const float* __restrict__ ybuf, const float* __restrict__ ew,
                           float* __restrict__ out) {
    int i = blockIdx.x * 256 + threadIdx.x;
    if (i >= T_TOK * HS / 4) return;
    int tk = i >> 7, c4 = i & 127;
    float wA = ew[2 * tk], wB = ew[2 * tk + 1];
    const float4* y4 = reinterpret_cast<const float4*>(ybuf);
    float4 a = y4[(size_t)(2 * tk) * (HS / 4) + c4];
    float4 b = y4[(size_t)(2 * tk + 1) * (HS / 4) + c4];
    float4 o;
    o.x = wA * a.x + wB * b.x; o.y = wA * a.y + wB * b.y;
    o.z = wA * a.z + wB * b.z; o.w = wA * a.w + wB * b.w;
    reinterpret_cast<float4*>(out)[i] = o;
}

// ================= launch =================
extern "C" void kernel_launch(void* const* d_in, const int* in_sizes, int n_in,
                              void* d_out, int out_size, void* d_ws, size_t ws_size,
                              hipStream_t stream) {
    const float* x  = (const float*)d_in[0];
    const float* ew = (const float*)d_in[1];
    const int*   ei = (const int*)d_in[2];
    const float* w1 = (const float*)d_in[3];
    const float* w2 = (const float*)d_in[4];
    float* out = (float*)d_out;
    char* W = (char*)d_ws;

    if (ws_size < WS_NEED) {
        int* cnt = (int*)d_ws;
        int* bucket = cnt + 64;
        float* ybuf = (float*)(W + (1 << 19));
        fb_init<<<1, 64, 0, stream>>>(cnt);
        fb_scatter<<<NA / 256, 256, 0, stream>>>(ei, cnt, bucket);
        fb_fused<<<NE * (NA / FB_BM), 256, 0, stream>>>(x, w1, w2, cnt, bucket, ybuf);
        fb_combine<<<(T_TOK * HS / 4 + 255) / 256, 256, 0, stream>>>(ybuf, ew, out);
        return;
    }

    int* offp  = (int*)(W + WS_OFF);
    int* mexp  = (int*)(W + WS_MEXP);
    int* slots = (int*)(W + WS_SLOTS);
    int* inv   = (int*)(W + WS_INV);
    unsigned short* XB   = (unsigned short*)(W + WS_XB);
    unsigned short* W1T  = (unsigned short*)(W + WS_W1T);
    unsigned short* W2T  = (unsigned short*)(W + WS_W2T);
    unsigned short* HB   = (unsigned short*)(W + WS_HB);
    unsigned short* YPB0 = (unsigned short*)(W + WS_YPB0);
    unsigned short* YPB1 = (unsigned short*)(W + WS_YPB1);

    moe_prep<<<18465, 256, 0, stream>>>(ei, slots, inv, offp, mexp,
                                        x, XB, w1, W1T, w2, W2T);
    moe_gemm1<<<8 * 9 * 16, 256, 0, stream>>>(XB, W1T, offp, mexp, slots, HB);
    moe_gemm2<<<8 * 9 * 8, 256, 0, stream>>>(HB, W2T, offp, mexp, YPB0, YPB1);
    moe_combine2<<<(T_TOK * HS / 8) / 256, 256, 0, stream>>>(YPB0, YPB1, inv, ew, out);
}

// Round 11
// 99.923 us; speedup vs baseline: 49.8999x; 1.0133x over previous
//
#include <hip/hip_runtime.h>
#include <stdint.h>

#define T_TOK 4096
#define KTOP  2
#define HS    512
#define FFN   2048
#define NE    8
#define NA    (T_TOK*KTOP)     // 8192 assignments
#define MT    128              // M-tile
#define BK    64               // K-step
#define MT_MAX 72              // 8 XCD chunks x 9
#define SLOT_CAP (MT_MAX*MT)   // 9216
#define PSTR 68                // epilogue LDS f32 stride

// ---------------- workspace layout (bytes) ----------------
#define MB_ (1024ull*1024ull)
#define WS_OFF   1024u         // 9 ints
#define WS_MEXP  1088u         // 72 ints
#define WS_SLOTS 2048u         // 9216 ints
#define WS_INV   40960u        // 8192 ints
#define WS_XB   (1*MB_)        // 4MB  bf16 [4096][512]
#define WS_W1T  (5*MB_)        // 16MB bf16 [8][2048][512]
#define WS_W2T  (21*MB_)       // 16MB bf16 [8][512][2048]
#define WS_HB   (37*MB_)       // 36MB bf16 [9216][2048]
#define WS_YPB0 (73*MB_)       // 9MB bf16 [9216][512]
#define WS_YPB1 (82*MB_)       // 9MB
#define WS_NEED (91*MB_)

typedef short bf16x8 __attribute__((ext_vector_type(8)));
typedef float f32x4  __attribute__((ext_vector_type(4)));

__device__ __forceinline__ unsigned short f2bf(float f) {
    unsigned u = __builtin_bit_cast(unsigned, f);
    u += 0x7fffu + ((u >> 16) & 1u);          // RNE
    return (unsigned short)(u >> 16);
}
__device__ __forceinline__ float bf2f(unsigned short h) {
    return __builtin_bit_cast(float, (unsigned)h << 16);
}
// tanh-approx gelu (~10 VALU ops vs erff ~30; |err| <= ~3e-3; inf-safe both tails)
__device__ __forceinline__ float gelu_fast(float x) {
    float x2 = x * x;
    float inner = fmaf(0.044715f * x2, x, x);
    float E = __expf(1.5957691216057308f * inner);
    return x - x / (1.0f + E);
}
__device__ __forceinline__ void gl_lds16(const void* g, void* l) {
    __builtin_amdgcn_global_load_lds(
        (const __attribute__((address_space(1))) unsigned int*)g,
        (__attribute__((address_space(3))) unsigned int*)l, 16, 0, 0);
}

// ---------------- merged prep: cvt_x + w1T + w2T + deterministic routing ----------------
// ranges: [0,2048) x->bf16 | [2048,4096) w1T | [4096,6144) w2T |
//         [6144,6176) fill (rank-based, no global atomics) | [6176] publish.
// Every range writes disjoint data consumed only by LATER kernels (R5 lesson).
// 64x64 transpose tiles: float4 global reads (1KB/inst), ushort4 bf16 writes
// (512B/inst); LDS [64][65] scalar ops are <=2-way bank aliasing (free, m136).
__device__ __forceinline__ void transpose_cvt64(
    const float* __restrict__ src, unsigned short* __restrict__ dh,
    int R, int C, int e, int kb, int nb, int t, float (*tile)[65])
{
    const int k0 = kb * 64, n0 = nb * 64;
    #pragma unroll
    for (int q = 0; q < 4; ++q) {
        int f4 = t + q * 256;          // 1024 float4s = 64x64 tile
        int kk = f4 >> 4;              // 64 rows
        int nn4 = f4 & 15;             // 16 float4 per row
        float4 v = *reinterpret_cast<const float4*>(
            &src[((size_t)e * R + k0 + kk) * C + n0 + nn4 * 4]);
        tile[kk][nn4 * 4 + 0] = v.x; tile[kk][nn4 * 4 + 1] = v.y;
        tile[kk][nn4 * 4 + 2] = v.z; tile[kk][nn4 * 4 + 3] = v.w;
    }
    __syncthreads();
    #pragma unroll
    for (int q = 0; q < 4; ++q) {
        int wid = t + q * 256;
        int nn = wid >> 4;             // 64 output rows (n)
        int kk4 = wid & 15;            // 16 ushort4 per row
        ushort4 o;
        o.x = f2bf(tile[kk4 * 4 + 0][nn]);
        o.y = f2bf(tile[kk4 * 4 + 1][nn]);
        o.z = f2bf(tile[kk4 * 4 + 2][nn]);
        o.w = f2bf(tile[kk4 * 4 + 3][nn]);
        *reinterpret_cast<ushort4*>(&dh[((size_t)e * C + n0 + nn) * R + k0 + kk4 * 4]) = o;
    }
}

__global__ void moe_prep(const int* __restrict__ eidx,
                         int* slots, int* inv, int* offp, int* mexp,
                         const float* __restrict__ x, unsigned short* __restrict__ xb,
                         const float* __restrict__ w1, unsigned short* __restrict__ w1t,
                         const float* __restrict__ w2, unsigned short* __restrict__ w2t)
{
    __shared__ float tile[64][65];
    const int bid = blockIdx.x, t = threadIdx.x;
    if (bid < 2048) {                         // x -> bf16
        int i = bid * 256 + t;
        float4 v = reinterpret_cast<const float4*>(x)[i];
        uint2 p = { (unsigned)f2bf(v.x) | ((unsigned)f2bf(v.y) << 16),
                    (unsigned)f2bf(v.z) | ((unsigned)f2bf(v.w) << 16) };
        reinterpret_cast<uint2*>(xb)[i] = p;
    } else if (bid < 4096) {                  // w1 [e][HS][FFN] -> [e][FFN][HS]
        int lin = bid - 2048, e = lin >> 8, rem = lin & 255;
        transpose_cvt64(w1, w1t, HS, FFN, e, rem & 7, rem >> 3, t, tile);
    } else if (bid < 6144) {                  // w2 [e][FFN][HS] -> [e][HS][FFN]
        int lin = bid - 4096, e = lin >> 8, rem = lin & 255;
        transpose_cvt64(w2, w2t, FFN, HS, e, rem & 31, rem >> 5, t, tile);
    } else {                                  // deterministic routing
        __shared__ int hfull[NE], hpre[NE], elocal[256];
        __shared__ int off_l[NE + 1];
        const int f = bid - 6144;             // 0..32
        if (t < NE) { hfull[t] = 0; hpre[t] = 0; }
        __syncthreads();
        const int base = f * 256;             // f==32 -> base==NA (no local slice)
        for (int i = t; i < NA; i += 256) {
            int ee = eidx[i];
            atomicAdd(&hfull[ee], 1);         // LDS atomics: cheap
            if (i < base) atomicAdd(&hpre[ee], 1);
        }
        if (f < 32) elocal[t] = eidx[base + t];
        __syncthreads();
        if (t == 0) {
            int run = 0;
            for (int q = 0; q < NE; ++q) { off_l[q] = run; run += ((hfull[q] + MT - 1) / MT) * MT; }
            off_l[NE] = run;
        }
        __syncthreads();
        if (f < 32) {
            int a = base + t, e = elocal[t];
            int rank = 0;
            for (int j = 0; j < t; ++j) rank += (elocal[j] == e) ? 1 : 0;
            int s = off_l[e] + hpre[e] + rank;
            slots[s] = a;                     // deterministic (stable order)
            inv[a] = s;
        } else {
            for (int e = 0; e < NE; ++e)
                for (int s = off_l[e] + hfull[e] + t; s < off_l[e + 1]; s += 256)
                    slots[s] = -1;            // pads (poison-safe each call)
            for (int s = off_l[NE] + t; s < SLOT_CAP; s += 256) slots[s] = -1;
            if (t <= NE) offp[t] = off_l[t];
            if (t < MT_MAX) {                 // mexp[t]: expert owning tile t
                int m0 = t * MT, ee = 0;
                #pragma unroll
                for (int q = 0; q < NE; ++q)
                    if (m0 >= off_l[q] && m0 < off_l[q + 1]) ee = q;
                mexp[t] = ee;
            }
        }
    }
}

// ---------------- grouped GEMM1: H = gelu(X @ W1), single-pass bf16 ----------------
// Grid 1152, chunked XCD affinity (mt = xcd*9 + part%9) -> expert weights L2-resident
// (R6: FETCH 149->49MB). mtg-fast is right here: per-XCD A set 1.15MB fits L2.
__global__ __launch_bounds__(256, 4) void moe_gemm1(
    const unsigned short* __restrict__ XB, const unsigned short* __restrict__ W1T,
    const int* __restrict__ offp, const int* __restrict__ mexp,
    const int* __restrict__ slots, unsigned short* __restrict__ HB)
{
    const int xcd = blockIdx.x & 7;
    const int part = blockIdx.x >> 3;     // 0..143
    const int mtg = part % 9;
    const int nt  = part / 9;             // 0..15
    const int mt  = xcd * 9 + mtg;
    if (mt * MT >= offp[NE]) return;
    const int e = mexp[mt];
    const int t = threadIdx.x, lane = t & 63, wv = t >> 6;

    __shared__ __align__(16) char POOL[MT * PSTR * 4];
    __shared__ int srow[MT];
    short* As = (short*)POOL;                 // 16KB [128][64] bf16, 8-group XOR swz
    short* Bs = (short*)(POOL + 16384);       // 16KB
    float* Pf = (float*)POOL;                 // epilogue overlay

    if (t < MT) { int s = slots[mt * MT + t]; srow[t] = (s < 0) ? 0 : (s >> 1); }
    __syncthreads();

    int baseA[4], baseB[4];
    #pragma unroll
    for (int q = 0; q < 4; ++q) {
        int i = wv * 4 + q;
        int row = i * 8 + (lane >> 3);
        int sg = (lane & 7) ^ (row & 7);      // source swz [rule 21: both sides]
        baseA[q] = srow[row] * HS + sg * 8;
        baseB[q] = (e * FFN + nt * MT + row) * HS + sg * 8;
    }

    const int wm = wv >> 1, wn = wv & 1, q4 = lane >> 4, l15 = lane & 15;
    int offA[2][4], offB[2][4];
    #pragma unroll
    for (int m = 0; m < 4; ++m) {
        int r  = wm * 64 + m * 16 + l15;
        int rb = wn * 64 + m * 16 + l15;
        #pragma unroll
        for (int ks = 0; ks < 2; ++ks) {
            offA[ks][m] = r  * 128 + ((((ks << 2) | q4) ^ (r  & 7)) << 4);
            offB[ks][m] = rb * 128 + ((((ks << 2) | q4) ^ (rb & 7)) << 4);
        }
    }

    f32x4 acc[4][4];
    #pragma unroll
    for (int m = 0; m < 4; ++m)
        #pragma unroll
        for (int n = 0; n < 4; ++n) { f32x4 z = {0.f, 0.f, 0.f, 0.f}; acc[m][n] = z; }

    for (int kk = 0; kk < HS; kk += BK) {
        __syncthreads();
        #pragma unroll
        for (int q = 0; q < 4; ++q) {
            int i = wv * 4 + q;
            gl_lds16(XB  + baseA[q] + kk, (char*)As + i * 1024);
            gl_lds16(W1T + baseB[q] + kk, (char*)Bs + i * 1024);
        }
        __syncthreads();
        #pragma unroll
        for (int ks = 0; ks < 2; ++ks) {
            bf16x8 a[4], b[4];
            #pragma unroll
            for (int m = 0; m < 4; ++m) {
                a[m] = *(const bf16x8*)((const char*)As + offA[ks][m]);
                b[m] = *(const bf16x8*)((const char*)Bs + offB[ks][m]);
            }
            #pragma unroll
            for (int m = 0; m < 4; ++m)
                #pragma unroll
                for (int n = 0; n < 4; ++n)
                    acc[m][n] = __builtin_amdgcn_mfma_f32_16x16x32_bf16(a[m], b[n], acc[m][n], 0, 0, 0);
        }
    }

    // epilogue: LDS transpose -> coalesced bf16x8 stores (fast gelu in read phase)
    #pragma unroll
    for (int half = 0; half < 2; ++half) {
        __syncthreads();
        if (wn == half) {
            #pragma unroll
            for (int m = 0; m < 4; ++m)
                #pragma unroll
                for (int n = 0; n < 4; ++n)
                    #pragma unroll
                    for (int j = 0; j < 4; ++j)
                        Pf[(wm * 64 + m * 16 + q4 * 4 + j) * PSTR + n * 16 + l15] = acc[m][n][j];
        }
        __syncthreads();
        #pragma unroll
        for (int q = 0; q < 4; ++q) {
            int seg = q * 256 + t, row = seg >> 3, c8 = (seg & 7) << 3;
            const float* p = Pf + row * PSTR + c8;
            float4 a = *(const float4*)p, b = *(const float4*)(p + 4);
            float va[8] = {a.x, a.y, a.z, a.w, b.x, b.y, b.z, b.w};
            bf16x8 ph;
            #pragma unroll
            for (int i = 0; i < 8; ++i) ph[i] = (short)f2bf(gelu_fast(va[i]));
            *(bf16x8*)(HB + (size_t)(mt * MT + row) * FFN + nt * MT + half * 64 + c8) = ph;
        }
    }
}

// ---------------- grouped GEMM2: Y = H @ W2, split-K=2, bf16 partials ----------------
// Grid 576. sub-FAST decode: the 8 concurrent blocks on one XCD are all (nt,kpart)
// jobs of ONE mt -> A panel fetched once; B survives L2 across mtg rounds.
__global__ __launch_bounds__(256, 4) void moe_gemm2(
    const unsigned short* __restrict__ HB, const unsigned short* __restrict__ W2T,
    const int* __restrict__ offp, const int* __restrict__ mexp,
    unsigned short* __restrict__ YPB0, unsigned short* __restrict__ YPB1)
{
    const int xcd = blockIdx.x & 7;
    const int part = blockIdx.x >> 3;     // 0..71
    const int sub = part % 8;             // FAST: share one mt's A panel
    const int mtg = part / 8;             // 0..8
    const int mt  = xcd * 9 + mtg;
    const int nt  = sub >> 1, kpart = sub & 1;
    if (mt * MT >= offp[NE]) return;
    const int e = mexp[mt];
    const int t = threadIdx.x, lane = t & 63, wv = t >> 6;

    __shared__ __align__(16) char POOL[MT * PSTR * 4];
    short* As = (short*)POOL;
    short* Bs = (short*)(POOL + 16384);
    float* Pf = (float*)POOL;

    int baseA[4], baseB[4];
    #pragma unroll
    for (int q = 0; q < 4; ++q) {
        int i = wv * 4 + q;
        int row = i * 8 + (lane >> 3);
        int sg = (lane & 7) ^ (row & 7);
        baseA[q] = (mt * MT + row) * FFN + sg * 8;
        baseB[q] = (e * HS + nt * MT + row) * FFN + sg * 8;
    }

    const int wm = wv >> 1, wn = wv & 1, q4 = lane >> 4, l15 = lane & 15;
    int offA[2][4], offB[2][4];
    #pragma unroll
    for (int m = 0; m < 4; ++m) {
        int r  = wm * 64 + m * 16 + l15;
        int rb = wn * 64 + m * 16 + l15;
        #pragma unroll
        for (int ks = 0; ks < 2; ++ks) {
            offA[ks][m] = r  * 128 + ((((ks << 2) | q4) ^ (r  & 7)) << 4);
            offB[ks][m] = rb * 128 + ((((ks << 2) | q4) ^ (rb & 7)) << 4);
        }
    }

    f32x4 acc[4][4];
    #pragma unroll
    for (int m = 0; m < 4; ++m)
        #pragma unroll
        for (int n = 0; n < 4; ++n) { f32x4 z = {0.f, 0.f, 0.f, 0.f}; acc[m][n] = z; }

    const int k0 = kpart * (FFN / 2), k1 = k0 + FFN / 2;
    for (int kk = k0; kk < k1; kk += BK) {
        __syncthreads();
        #pragma unroll
        for (int q = 0; q < 4; ++q) {
            int i = wv * 4 + q;
            gl_lds16(HB  + baseA[q] + kk, (char*)As + i * 1024);
            gl_lds16(W2T + baseB[q] + kk, (char*)Bs + i * 1024);
        }
        __syncthreads();
        #pragma unroll
        for (int ks = 0; ks < 2; ++ks) {
            bf16x8 a[4], b[4];
            #pragma unroll
            for (int m = 0; m < 4; ++m) {
                a[m] = *(const bf16x8*)((const char*)As + offA[ks][m]);
                b[m] = *(const bf16x8*)((const char*)Bs + offB[ks][m]);
            }
            #pragma unroll
            for (int m = 0; m < 4; ++m)
                #pragma unroll
                for (int n = 0; n < 4; ++n)
                    acc[m][n] = __builtin_amdgcn_mfma_f32_16x16x32_bf16(a[m], b[n], acc[m][n], 0, 0, 0);
        }
    }

    unsigned short* YP = kpart ? YPB1 : YPB0;
    #pragma unroll
    for (int half = 0; half < 2; ++half) {
        __syncthreads();
        if (wn == half) {
            #pragma unroll
            for (int m = 0; m < 4; ++m)
                #pragma unroll
                for (int n = 0; n < 4; ++n)
                    #pragma unroll
                    for (int j = 0; j < 4; ++j)
                        Pf[(wm * 64 + m * 16 + q4 * 4 + j) * PSTR + n * 16 + l15] = acc[m][n][j];
        }
        __syncthreads();
        #pragma unroll
        for (int q = 0; q < 4; ++q) {
            int seg = q * 256 + t, row = seg >> 3, c8 = (seg & 7) << 3;
            const float* p = Pf + row * PSTR + c8;
            float4 a = *(const float4*)p, b = *(const float4*)(p + 4);
            float va[8] = {a.x, a.y, a.z, a.w, b.x, b.y, b.z, b.w};
            bf16x8 ph;
            #pragma unroll
            for (int i = 0; i < 8; ++i) ph[i] = (short)f2bf(va[i]);
            *(bf16x8*)(YP + (size_t)(mt * MT + row) * HS + nt * MT + half * 64 + c8) = ph;
        }
    }
}

// ---------------- combine (bf16 partials) ----------------
__global__ void moe_combine2(const unsigned short* __restrict__ YPB0,
                             const unsigned short* __restrict__ YPB1,
                             const int* __restrict__ inv, const float* __restrict__ ew,
                             float* __restrict__ out) {
    int i = blockIdx.x * 256 + threadIdx.x;      // over T*HS/8 groups of 8
    if (i >= T_TOK * HS / 8) return;
    int tk = i >> 6, c8 = (i & 63) << 3;
    int s0 = inv[2 * tk], s1 = inv[2 * tk + 1];
    float w0 = ew[2 * tk], w1 = ew[2 * tk + 1];
    bf16x8 a0 = *(const bf16x8*)(YPB0 + (size_t)s0 * HS + c8);
    bf16x8 b0 = *(const bf16x8*)(YPB1 + (size_t)s0 * HS + c8);
    bf16x8 a1 = *(const bf16x8*)(YPB0 + (size_t)s1 * HS + c8);
    bf16x8 b1 = *(const bf16x8*)(YPB1 + (size_t)s1 * HS + c8);
    float o[8];
    #pragma unroll
    for (int j = 0; j < 8; ++j)
        o[j] = w0 * (bf2f((unsigned short)a0[j]) + bf2f((unsigned short)b0[j]))
             + w1 * (bf2f((unsigned short)a1[j]) + bf2f((unsigned short)b1[j]));
    float4* d = reinterpret_cast<float4*>(out + (size_t)i * 8);
    d[0] = make_float4(o[0], o[1], o[2], o[3]);
    d[1] = make_float4(o[4], o[5], o[6], o[7]);
}

// ================= fallback VALU path (proven baseline) =================
#define FB_BM 32
#define FB_BJ 128
#define FB_CK 256
#define FB_XSTR (FB_CK+4)
#define FB_HSTR (FB_BJ+4)

__device__ __forceinline__ float fb_gelu(float v) {
    return 0.5f * v * (1.0f + erff(v * 0.70710678118654752f));
}

__global__ void fb_init(int* cnt) { int i = threadIdx.x; if (i < NE) cnt[i] = 0; }

__global__ void fb_scatter(const int* __restrict__ eidx, int* cnt, int* bucket) {
    int a = blockIdx.x * 256 + threadIdx.x;
    if (a < NA) { int e = eidx[a]; int p = atomicAdd(&cnt[e], 1); bucket[e * NA + p] = a; }
}

__global__ __launch_bounds__(256, 1) void fb_fused(
    const float* __restrict__ x, const float* __restrict__ w1, const float* __restrict__ w2,
    const int* __restrict__ cnt, const int* __restrict__ bucket, float* __restrict__ ybuf)
{
    const int bid = blockIdx.x;
    const int e = bid & (NE - 1), tr = bid >> 3;
    const int n_e = cnt[e], rbase = tr * FB_BM;
    if (rbase >= n_e) return;
    const int t = threadIdx.x;
    __shared__ __align__(16) float Xc[FB_BM][FB_XSTR];
    __shared__ __align__(16) float Hsh[FB_BM][FB_HSTR];
    __shared__ int rowa[FB_BM];
    if (t < FB_BM) { int r = rbase + t; rowa[t] = (r < n_e) ? bucket[e * NA + r] : -1; }
    __syncthreads();
    const int cg = t & 15, rg = t >> 4, r0 = rg * 2;
    float yac[2][32];
    #pragma unroll
    for (int u = 0; u < 2; ++u)
        #pragma unroll
        for (int v = 0; v < 32; ++v) yac[u][v] = 0.0f;
    const float* w1e = w1 + (size_t)e * HS * FFN;
    const float* w2e = w2 + (size_t)e * FFN * HS;
    for (int jp = 0; jp < FFN; jp += FB_BJ) {
        float hac[2][8];
        #pragma unroll
        for (int u = 0; u < 2; ++u)
            #pragma unroll
            for (int v = 0; v < 8; ++v) hac[u][v] = 0.0f;
        for (int ic = 0; ic < HS; ic += FB_CK) {
            __syncthreads();
            #pragma unroll
            for (int q = 0; q < (FB_BM * FB_CK / 4) / 256; ++q) {
                int id = t + 256 * q, rr = id >> 6, c4 = id & 63;
                int a = rowa[rr];
                float4 val = make_float4(0.f, 0.f, 0.f, 0.f);
                if (a >= 0) val = *reinterpret_cast<const float4*>(x + (size_t)(a >> 1) * HS + ic + c4 * 4);
                *reinterpret_cast<float4*>(&Xc[rr][c4 * 4]) = val;
            }
            __syncthreads();
            const float* w1p = w1e + (size_t)ic * FFN + jp + cg * 8;
            #pragma unroll 2
            for (int i4 = 0; i4 < FB_CK; i4 += 4) {
                float4 xa = *reinterpret_cast<const float4*>(&Xc[r0][i4]);
                float4 xb = *reinterpret_cast<const float4*>(&Xc[r0 + 1][i4]);
                const float* wr0 = w1p + (size_t)i4 * FFN;
                #pragma unroll
                for (int ii = 0; ii < 4; ++ii) {
                    float4 wa = *reinterpret_cast<const float4*>(wr0 + (size_t)ii * FFN);
                    float4 wb = *reinterpret_cast<const float4*>(wr0 + (size_t)ii * FFN + 4);
                    float x0 = (ii == 0) ? xa.x : (ii == 1) ? xa.y : (ii == 2) ? xa.z : xa.w;
                    float x1 = (ii == 0) ? xb.x : (ii == 1) ? xb.y : (ii == 2) ? xb.z : xb.w;
                    hac[0][0] = fmaf(x0, wa.x, hac[0][0]); hac[0][1] = fmaf(x0, wa.y, hac[0][1]);
                    hac[0][2] = fmaf(x0, wa.z, hac[0][2]); hac[0][3] = fmaf(x0, wa.w, hac[0][3]);
                    hac[0][4] = fmaf(x0, wb.x, hac[0][4]); hac[0][5] = fmaf(x0, wb.y, hac[0][5]);
                    hac[0][6] = fmaf(x0, wb.z, hac[0][6]); hac[0][7] = fmaf(x0, wb.w, hac[0][7]);
                    hac[1][0] = fmaf(x1, wa.x, hac[1][0]); hac[1][1] = fmaf(x1, wa.y, hac[1][1]);
                    hac[1][2] = fmaf(x1, wa.z, hac[1][2]); hac[1][3] = fmaf(x1, wa.w, hac[1][3]);
                    hac[1][4] = fmaf(x1, wb.x, hac[1][4]); hac[1][5] = fmaf(x1, wb.y, hac[1][5]);
                    hac[1][6] = fmaf(x1, wb.z, hac[1][6]); hac[1][7] = fmaf(x1, wb.w, hac[1][7]);
                }
            }
        }
        #pragma unroll
        for (int u = 0; u < 2; ++u)
            #pragma unroll
            for (int v = 0; v < 8; ++v) Hsh[r0 + u][cg * 8 + v] = fb_gelu(hac[u][v]);
        __syncthreads();
        const float* w2p = w2e + (size_t)jp * HS + cg * 32;
        #pragma unroll 2
        for (int j = 0; j < FB_BJ; ++j) {
            float h0 = Hsh[r0][j], h1 = Hsh[r0 + 1][j];
            const float* wr = w2p + (size_t)j * HS;
            #pragma unroll
            for (int q = 0; q < 8; ++q) {
                float4 w4 = *reinterpret_cast<const float4*>(wr + q * 4);
                yac[0][q * 4 + 0] = fmaf(h0, w4.x, yac[0][q * 4 + 0]);
                yac[0][q * 4 + 1] = fmaf(h0, w4.y, yac[0][q * 4 + 1]);
                yac[0][q * 4 + 2] = fmaf(h0, w4.z, yac[0][q * 4 + 2]);
                yac[0][q * 4 + 3] = fmaf(h0, w4.w, yac[0][q * 4 + 3]);
                yac[1][q * 4 + 0] = fmaf(h1, w4.x, yac[1][q * 4 + 0]);
                yac[1][q * 4 + 1] = fmaf(h1, w4.y, yac[1][q * 4 + 1]);
                yac[1][q * 4 + 2] = fmaf(h1, w4.z, yac[1][q * 4 + 2]);
                yac[1][q * 4 + 3] = fmaf(h1, w4.w, yac[1][q * 4 + 3]);
            }
        }
    }
    #pragma unroll
    for (int u = 0; u < 2; ++u) {
        int a = rowa[r0 + u];
        if (a >= 0) {
            float* yp = ybuf + (size_t)a * HS + cg * 32;
            #pragma unroll
            for (int q = 0; q < 8; ++q) {
                float4 o = make_float4(yac[u][q * 4 + 0], yac[u][q * 4 + 1],
                                       yac[u][q * 4 + 2], yac[u][q * 4 + 3]);
                *reinterpret_cast<float4*>(yp + q * 4) = o;
            }
        }
    }
}

__global__ void fb_combine(const float* __restrict__ ybuf, const float* __restrict__ ew,
                           float* __restrict__ out) {
    int i = blockIdx.x * 256 + threadIdx.x;
    if (i >= T_TOK * HS / 4) return;
    int tk = i >> 7, c4 = i & 127;
    float wA = ew[2 * tk], wB = ew[2 * tk + 1];
    const float4* y4 = reinterpret_cast<const float4*>(ybuf);
    float4 a = y4[(size_t)(2 * tk) * (HS / 4) + c4];
    float4 b = y4[(size_t)(2 * tk + 1) * (HS / 4) + c4];
    float4 o;
    o.x = wA * a.x + wB * b.x; o.y = wA * a.y + wB * b.y;
    o.z = wA * a.z + wB * b.z; o.w = wA * a.w + wB * b.w;
    reinterpret_cast<float4*>(out)[i] = o;
}

// ================= launch =================
extern "C" void kernel_launch(void* const* d_in, const int* in_sizes, int n_in,
                              void* d_out, int out_size, void* d_ws, size_t ws_size,
                              hipStream_t stream) {
    const float* x  = (const float*)d_in[0];
    const float* ew = (const float*)d_in[1];
    const int*   ei = (const int*)d_in[2];
    const float* w1 = (const float*)d_in[3];
    const float* w2 = (const float*)d_in[4];
    float* out = (float*)d_out;
    char* W = (char*)d_ws;

    if (ws_size < WS_NEED) {
        int* cnt = (int*)d_ws;
        int* bucket = cnt + 64;
        float* ybuf = (float*)(W + (1 << 19));
        fb_init<<<1, 64, 0, stream>>>(cnt);
        fb_scatter<<<NA / 256, 256, 0, stream>>>(ei, cnt, bucket);
        fb_fused<<<NE * (NA / FB_BM), 256, 0, stream>>>(x, w1, w2, cnt, bucket, ybuf);
        fb_combine<<<(T_TOK * HS / 4 + 255) / 256, 256, 0, stream>>>(ybuf, ew, out);
        return;
    }

    int* offp  = (int*)(W + WS_OFF);
    int* mexp  = (int*)(W + WS_MEXP);
    int* slots = (int*)(W + WS_SLOTS);
    int* inv   = (int*)(W + WS_INV);
    unsigned short* XB   = (unsigned short*)(W + WS_XB);
    unsigned short* W1T  = (unsigned short*)(W + WS_W1T);
    unsigned short* W2T  = (unsigned short*)(W + WS_W2T);
    unsigned short* HB   = (unsigned short*)(W + WS_HB);
    unsigned short* YPB0 = (unsigned short*)(W + WS_YPB0);
    unsigned short* YPB1 = (unsigned short*)(W + WS_YPB1);

    moe_prep<<<6177, 256, 0, stream>>>(ei, slots, inv, offp, mexp,
                                       x, XB, w1, W1T, w2, W2T);
    moe_gemm1<<<8 * 9 * 16, 256, 0, stream>>>(XB, W1T, offp, mexp, slots, HB);
    moe_gemm2<<<8 * 9 * 8, 256, 0, stream>>>(HB, W2T, offp, mexp, YPB0, YPB1);
    moe_combine2<<<(T_TOK * HS / 8) / 256, 256, 0, stream>>>(YPB0, YPB1, inv, ew, out);
}

// Round 13
// 96.656 us; speedup vs baseline: 51.5866x; 1.0338x over previous
//
#include <hip/hip_runtime.h>
#include <stdint.h>

#define T_TOK 4096
#define KTOP  2
#define HS    512
#define FFN   2048
#define NE    8
#define NA    (T_TOK*KTOP)     // 8192 assignments
#define MT    128              // M-tile
#define BK    64               // K-step
#define MT_MAX 72              // 8 XCD chunks x 9
#define SLOT_CAP (MT_MAX*MT)   // 9216
#define PSTR 68                // epilogue LDS f32 stride
#define NB_G1 1152             // gemm1 blocks in fused launch

// ---------------- workspace layout (bytes) ----------------
#define MB_ (1024ull*1024ull)
#define WS_OFF   1024u         // 9 ints
#define WS_MEXP  1088u         // 72 ints
#define WS_SLOTS 2048u         // 9216 ints
#define WS_INV   40960u        // 8192 ints
#define WS_XB   (1*MB_)        // 4MB  bf16 [4096][512]
#define WS_W1T  (5*MB_)        // 16MB bf16 [8][2048][512]
#define WS_W2T  (21*MB_)       // 16MB bf16 [8][512][2048]
#define WS_HB   (37*MB_)       // 36MB bf16 [9216][2048]
#define WS_YPB0 (73*MB_)       // 9MB bf16 [9216][512]
#define WS_YPB1 (82*MB_)       // 9MB
#define WS_NEED (91*MB_)

typedef short bf16x8 __attribute__((ext_vector_type(8)));
typedef float f32x4  __attribute__((ext_vector_type(4)));

__device__ __forceinline__ unsigned short f2bf(float f) {
    unsigned u = __builtin_bit_cast(unsigned, f);
    u += 0x7fffu + ((u >> 16) & 1u);          // RNE
    return (unsigned short)(u >> 16);
}
__device__ __forceinline__ float bf2f(unsigned short h) {
    return __builtin_bit_cast(float, (unsigned)h << 16);
}
// tanh-approx gelu (~10 VALU ops vs erff ~30; |err| <= ~3e-3; inf-safe both tails)
__device__ __forceinline__ float gelu_fast(float x) {
    float x2 = x * x;
    float inner = fmaf(0.044715f * x2, x, x);
    float E = __expf(1.5957691216057308f * inner);
    return x - x / (1.0f + E);
}
__device__ __forceinline__ void gl_lds16(const void* g, void* l) {
    __builtin_amdgcn_global_load_lds(
        (const __attribute__((address_space(1))) unsigned int*)g,
        (__attribute__((address_space(3))) unsigned int*)l, 16, 0, 0);
}

// 64x64 transpose+cvt tile: float4 global reads (1KB/inst), ushort4 writes.
__device__ __forceinline__ void transpose_cvt64(
    const float* __restrict__ src, unsigned short* __restrict__ dh,
    int R, int C, int e, int kb, int nb, int t, float (*tile)[65])
{
    const int k0 = kb * 64, n0 = nb * 64;
    #pragma unroll
    for (int q = 0; q < 4; ++q) {
        int f4 = t + q * 256;
        int kk = f4 >> 4, nn4 = f4 & 15;
        float4 v = *reinterpret_cast<const float4*>(
            &src[((size_t)e * R + k0 + kk) * C + n0 + nn4 * 4]);
        tile[kk][nn4 * 4 + 0] = v.x; tile[kk][nn4 * 4 + 1] = v.y;
        tile[kk][nn4 * 4 + 2] = v.z; tile[kk][nn4 * 4 + 3] = v.w;
    }
    __syncthreads();
    #pragma unroll
    for (int q = 0; q < 4; ++q) {
        int wid = t + q * 256;
        int nn = wid >> 4, kk4 = wid & 15;
        ushort4 o;
        o.x = f2bf(tile[kk4 * 4 + 0][nn]);
        o.y = f2bf(tile[kk4 * 4 + 1][nn]);
        o.z = f2bf(tile[kk4 * 4 + 2][nn]);
        o.w = f2bf(tile[kk4 * 4 + 3][nn]);
        *reinterpret_cast<ushort4*>(&dh[((size_t)e * C + n0 + nn) * R + k0 + kk4 * 4]) = o;
    }
}

// ---------------- prep1: cvt_x + w1T + deterministic routing ----------------
// ranges: [0,2048) x->bf16 | [2048,4096) w1T | [4096,4129) routing.
// Every range writes disjoint data consumed only by LATER kernels (R5 lesson).
// (w2T moved into the fused gemm1 launch -- only gemm2 needs it.)
__global__ void moe_prep1(const int* __restrict__ eidx,
                          int* slots, int* inv, int* offp, int* mexp,
                          const float* __restrict__ x, unsigned short* __restrict__ xb,
                          const float* __restrict__ w1, unsigned short* __restrict__ w1t)
{
    __shared__ float tile[64][65];
    const int bid = blockIdx.x, t = threadIdx.x;
    if (bid < 2048) {                         // x -> bf16
        int i = bid * 256 + t;
        float4 v = reinterpret_cast<const float4*>(x)[i];
        uint2 p = { (unsigned)f2bf(v.x) | ((unsigned)f2bf(v.y) << 16),
                    (unsigned)f2bf(v.z) | ((unsigned)f2bf(v.w) << 16) };
        reinterpret_cast<uint2*>(xb)[i] = p;
    } else if (bid < 4096) {                  // w1 [e][HS][FFN] -> [e][FFN][HS]
        int lin = bid - 2048, e = lin >> 8, rem = lin & 255;
        transpose_cvt64(w1, w1t, HS, FFN, e, rem & 7, rem >> 3, t, tile);
    } else {                                  // deterministic routing
        __shared__ int hfull[NE], hpre[NE], elocal[256];
        __shared__ int off_l[NE + 1];
        const int f = bid - 4096;             // 0..32
        if (t < NE) { hfull[t] = 0; hpre[t] = 0; }
        __syncthreads();
        const int base = f * 256;             // f==32 -> base==NA (no local slice)
        for (int i = t; i < NA; i += 256) {
            int ee = eidx[i];
            atomicAdd(&hfull[ee], 1);         // LDS atomics: cheap
            if (i < base) atomicAdd(&hpre[ee], 1);
        }
        if (f < 32) elocal[t] = eidx[base + t];
        __syncthreads();
        if (t == 0) {
            int run = 0;
            for (int q = 0; q < NE; ++q) { off_l[q] = run; run += ((hfull[q] + MT - 1) / MT) * MT; }
            off_l[NE] = run;
        }
        __syncthreads();
        if (f < 32) {
            int a = base + t, e = elocal[t];
            int rank = 0;
            for (int j = 0; j < t; ++j) rank += (elocal[j] == e) ? 1 : 0;
            int s = off_l[e] + hpre[e] + rank;
            slots[s] = a;                     // deterministic (stable order)
            inv[a] = s;
        } else {
            for (int e = 0; e < NE; ++e)
                for (int s = off_l[e] + hfull[e] + t; s < off_l[e + 1]; s += 256)
                    slots[s] = -1;            // pads (poison-safe each call)
            for (int s = off_l[NE] + t; s < SLOT_CAP; s += 256) slots[s] = -1;
            if (t <= NE) offp[t] = off_l[t];
            if (t < MT_MAX) {                 // mexp[t]: expert owning tile t
                int m0 = t * MT, ee = 0;
                #pragma unroll
                for (int q = 0; q < NE; ++q)
                    if (m0 >= off_l[q] && m0 < off_l[q + 1]) ee = q;
                mexp[t] = ee;
            }
        }
    }
}

// ---------------- fused: gemm1 (bid<1152) + w2T transpose (bid>=1152) ----------------
// gemm1: H = gelu(X @ W1), single-pass bf16, chunked XCD affinity, unchanged.
// w2T blocks fill gemm1's stall cycles / tail CUs (independent work; W2T is
// consumed only by the NEXT kernel -- no intra-launch dependency, R5 rule).
__global__ __launch_bounds__(256, 4) void moe_g1w2(
    const unsigned short* __restrict__ XB, const unsigned short* __restrict__ W1T,
    const int* __restrict__ offp, const int* __restrict__ mexp,
    const int* __restrict__ slots, unsigned short* __restrict__ HB,
    const float* __restrict__ w2, unsigned short* __restrict__ w2t)
{
    __shared__ __align__(16) char POOL[MT * PSTR * 4];
    __shared__ int srow[MT];
    const int t = threadIdx.x;

    if (blockIdx.x >= NB_G1) {                // ---- w2T path ----
        int lin = blockIdx.x - NB_G1;         // 0..2047
        int e = lin >> 8, rem = lin & 255;
        transpose_cvt64(w2, w2t, FFN, HS, e, rem & 31, rem >> 5, t,
                        reinterpret_cast<float(*)[65]>(POOL));
        return;
    }

    // ---- gemm1 path (unchanged) ----
    const int xcd = blockIdx.x & 7;
    const int part = blockIdx.x >> 3;     // 0..143
    const int mtg = part % 9;
    const int nt  = part / 9;             // 0..15
    const int mt  = xcd * 9 + mtg;
    if (mt * MT >= offp[NE]) return;
    const int e = mexp[mt];
    const int lane = t & 63, wv = t >> 6;

    short* As = (short*)POOL;                 // 16KB [128][64] bf16, 8-group XOR swz
    short* Bs = (short*)(POOL + 16384);       // 16KB
    float* Pf = (float*)POOL;                 // epilogue overlay

    if (t < MT) { int s = slots[mt * MT + t]; srow[t] = (s < 0) ? 0 : (s >> 1); }
    __syncthreads();

    int baseA[4], baseB[4];
    #pragma unroll
    for (int q = 0; q < 4; ++q) {
        int i = wv * 4 + q;
        int row = i * 8 + (lane >> 3);
        int sg = (lane & 7) ^ (row & 7);      // source swz [rule 21: both sides]
        baseA[q] = srow[row] * HS + sg * 8;
        baseB[q] = (e * FFN + nt * MT + row) * HS + sg * 8;
    }

    const int wm = wv >> 1, wn = wv & 1, q4 = lane >> 4, l15 = lane & 15;
    int offA[2][4], offB[2][4];
    #pragma unroll
    for (int m = 0; m < 4; ++m) {
        int r  = wm * 64 + m * 16 + l15;
        int rb = wn * 64 + m * 16 + l15;
        #pragma unroll
        for (int ks = 0; ks < 2; ++ks) {
            offA[ks][m] = r  * 128 + ((((ks << 2) | q4) ^ (r  & 7)) << 4);
            offB[ks][m] = rb * 128 + ((((ks << 2) | q4) ^ (rb & 7)) << 4);
        }
    }

    f32x4 acc[4][4];
    #pragma unroll
    for (int m = 0; m < 4; ++m)
        #pragma unroll
        for (int n = 0; n < 4; ++n) { f32x4 z = {0.f, 0.f, 0.f, 0.f}; acc[m][n] = z; }

    for (int kk = 0; kk < HS; kk += BK) {
        __syncthreads();
        #pragma unroll
        for (int q = 0; q < 4; ++q) {
            int i = wv * 4 + q;
            gl_lds16(XB  + baseA[q] + kk, (char*)As + i * 1024);
            gl_lds16(W1T + baseB[q] + kk, (char*)Bs + i * 1024);
        }
        __syncthreads();
        #pragma unroll
        for (int ks = 0; ks < 2; ++ks) {
            bf16x8 a[4], b[4];
            #pragma unroll
            for (int m = 0; m < 4; ++m) {
                a[m] = *(const bf16x8*)((const char*)As + offA[ks][m]);
                b[m] = *(const bf16x8*)((const char*)Bs + offB[ks][m]);
            }
            #pragma unroll
            for (int m = 0; m < 4; ++m)
                #pragma unroll
                for (int n = 0; n < 4; ++n)
                    acc[m][n] = __builtin_amdgcn_mfma_f32_16x16x32_bf16(a[m], b[n], acc[m][n], 0, 0, 0);
        }
    }

    // epilogue: LDS transpose -> coalesced bf16x8 stores (fast gelu in read phase)
    #pragma unroll
    for (int half = 0; half < 2; ++half) {
        __syncthreads();
        if (wn == half) {
            #pragma unroll
            for (int m = 0; m < 4; ++m)
                #pragma unroll
                for (int n = 0; n < 4; ++n)
                    #pragma unroll
                    for (int j = 0; j < 4; ++j)
                        Pf[(wm * 64 + m * 16 + q4 * 4 + j) * PSTR + n * 16 + l15] = acc[m][n][j];
        }
        __syncthreads();
        #pragma unroll
        for (int q = 0; q < 4; ++q) {
            int seg = q * 256 + t, row = seg >> 3, c8 = (seg & 7) << 3;
            const float* p = Pf + row * PSTR + c8;
            float4 a = *(const float4*)p, b = *(const float4*)(p + 4);
            float va[8] = {a.x, a.y, a.z, a.w, b.x, b.y, b.z, b.w};
            bf16x8 ph;
            #pragma unroll
            for (int i = 0; i < 8; ++i) ph[i] = (short)f2bf(gelu_fast(va[i]));
            *(bf16x8*)(HB + (size_t)(mt * MT + row) * FFN + nt * MT + half * 64 + c8) = ph;
        }
    }
}

// ---------------- grouped GEMM2: Y = H @ W2, split-K=2, bf16 partials ----------------
// Grid 576. sub-FAST decode: the 8 concurrent blocks on one XCD are all (nt,kpart)
// jobs of ONE mt -> A panel fetched once; B survives L2 across mtg rounds.
__global__ __launch_bounds__(256, 4) void moe_gemm2(
    const unsigned short* __restrict__ HB, const unsigned short* __restrict__ W2T,
    const int* __restrict__ offp, const int* __restrict__ mexp,
    unsigned short* __restrict__ YPB0, unsigned short* __restrict__ YPB1)
{
    const int xcd = blockIdx.x & 7;
    const int part = blockIdx.x >> 3;     // 0..71
    const int sub = part % 8;             // FAST: share one mt's A panel
    const int mtg = part / 8;             // 0..8
    const int mt  = xcd * 9 + mtg;
    const int nt  = sub >> 1, kpart = sub & 1;
    if (mt * MT >= offp[NE]) return;
    const int e = mexp[mt];
    const int t = threadIdx.x, lane = t & 63, wv = t >> 6;

    __shared__ __align__(16) char POOL[MT * PSTR * 4];
    short* As = (short*)POOL;
    short* Bs = (short*)(POOL + 16384);
    float* Pf = (float*)POOL;

    int baseA[4], baseB[4];
    #pragma unroll
    for (int q = 0; q < 4; ++q) {
        int i = wv * 4 + q;
        int row = i * 8 + (lane >> 3);
        int sg = (lane & 7) ^ (row & 7);
        baseA[q] = (mt * MT + row) * FFN + sg * 8;
        baseB[q] = (e * HS + nt * MT + row) * FFN + sg * 8;
    }

    const int wm = wv >> 1, wn = wv & 1, q4 = lane >> 4, l15 = lane & 15;
    int offA[2][4], offB[2][4];
    #pragma unroll
    for (int m = 0; m < 4; ++m) {
        int r  = wm * 64 + m * 16 + l15;
        int rb = wn * 64 + m * 16 + l15;
        #pragma unroll
        for (int ks = 0; ks < 2; ++ks) {
            offA[ks][m] = r  * 128 + ((((ks << 2) | q4) ^ (r  & 7)) << 4);
            offB[ks][m] = rb * 128 + ((((ks << 2) | q4) ^ (rb & 7)) << 4);
        }
    }

    f32x4 acc[4][4];
    #pragma unroll
    for (int m = 0; m < 4; ++m)
        #pragma unroll
        for (int n = 0; n < 4; ++n) { f32x4 z = {0.f, 0.f, 0.f, 0.f}; acc[m][n] = z; }

    const int k0 = kpart * (FFN / 2), k1 = k0 + FFN / 2;
    for (int kk = k0; kk < k1; kk += BK) {
        __syncthreads();
        #pragma unroll
        for (int q = 0; q < 4; ++q) {
            int i = wv * 4 + q;
            gl_lds16(HB  + baseA[q] + kk, (char*)As + i * 1024);
            gl_lds16(W2T + baseB[q] + kk, (char*)Bs + i * 1024);
        }
        __syncthreads();
        #pragma unroll
        for (int ks = 0; ks < 2; ++ks) {
            bf16x8 a[4], b[4];
            #pragma unroll
            for (int m = 0; m < 4; ++m) {
                a[m] = *(const bf16x8*)((const char*)As + offA[ks][m]);
                b[m] = *(const bf16x8*)((const char*)Bs + offB[ks][m]);
            }
            #pragma unroll
            for (int m = 0; m < 4; ++m)
                #pragma unroll
                for (int n = 0; n < 4; ++n)
                    acc[m][n] = __builtin_amdgcn_mfma_f32_16x16x32_bf16(a[m], b[n], acc[m][n], 0, 0, 0);
        }
    }

    unsigned short* YP = kpart ? YPB1 : YPB0;
    #pragma unroll
    for (int half = 0; half < 2; ++half) {
        __syncthreads();
        if (wn == half) {
            #pragma unroll
            for (int m = 0; m < 4; ++m)
                #pragma unroll
                for (int n = 0; n < 4; ++n)
                    #pragma unroll
                    for (int j = 0; j < 4; ++j)
                        Pf[(wm * 64 + m * 16 + q4 * 4 + j) * PSTR + n * 16 + l15] = acc[m][n][j];
        }
        __syncthreads();
        #pragma unroll
        for (int q = 0; q < 4; ++q) {
            int seg = q * 256 + t, row = seg >> 3, c8 = (seg & 7) << 3;
            const float* p = Pf + row * PSTR + c8;
            float4 a = *(const float4*)p, b = *(const float4*)(p + 4);
            float va[8] = {a.x, a.y, a.z, a.w, b.x, b.y, b.z, b.w};
            bf16x8 ph;
            #pragma unroll
            for (int i = 0; i < 8; ++i) ph[i] = (short)f2bf(va[i]);
            *(bf16x8*)(YP + (size_t)(mt * MT + row) * HS + nt * MT + half * 64 + c8) = ph;
        }
    }
}

// ---------------- combine (bf16 partials) ----------------
__global__ void moe_combine2(const unsigned short* __restrict__ YPB0,
                             const unsigned short* __restrict__ YPB1,
                             const int* __restrict__ inv, const float* __restrict__ ew,
                             float* __restrict__ out) {
    int i = blockIdx.x * 256 + threadIdx.x;      // over T*HS/8 groups of 8
    if (i >= T_TOK * HS / 8) return;
    int tk = i >> 6, c8 = (i & 63) << 3;
    int s0 = inv[2 * tk], s1 = inv[2 * tk + 1];
    float w0 = ew[2 * tk], w1 = ew[2 * tk + 1];
    bf16x8 a0 = *(const bf16x8*)(YPB0 + (size_t)s0 * HS + c8);
    bf16x8 b0 = *(const bf16x8*)(YPB1 + (size_t)s0 * HS + c8);
    bf16x8 a1 = *(const bf16x8*)(YPB0 + (size_t)s1 * HS + c8);
    bf16x8 b1 = *(const bf16x8*)(YPB1 + (size_t)s1 * HS + c8);
    float o[8];
    #pragma unroll
    for (int j = 0; j < 8; ++j)
        o[j] = w0 * (bf2f((unsigned short)a0[j]) + bf2f((unsigned short)b0[j]))
             + w1 * (bf2f((unsigned short)a1[j]) + bf2f((unsigned short)b1[j]));
    float4* d = reinterpret_cast<float4*>(out + (size_t)i * 8);
    d[0] = make_float4(o[0], o[1], o[2], o[3]);
    d[1] = make_float4(o[4], o[5], o[6], o[7]);
}

// ================= fallback VALU path (proven baseline) =================
#define FB_BM 32
#define FB_BJ 128
#define FB_CK 256
#define FB_XSTR (FB_CK+4)
#define FB_HSTR (FB_BJ+4)

__device__ __forceinline__ float fb_gelu(float v) {
    return 0.5f * v * (1.0f + erff(v * 0.70710678118654752f));
}

__global__ void fb_init(int* cnt) { int i = threadIdx.x; if (i < NE) cnt[i] = 0; }

__global__ void fb_scatter(const int* __restrict__ eidx, int* cnt, int* bucket) {
    int a = blockIdx.x * 256 + threadIdx.x;
    if (a < NA) { int e = eidx[a]; int p = atomicAdd(&cnt[e], 1); bucket[e * NA + p] = a; }
}

__global__ __launch_bounds__(256, 1) void fb_fused(
    const float* __restrict__ x, const float* __restrict__ w1, const float* __restrict__ w2,
    const int* __restrict__ cnt, const int* __restrict__ bucket, float* __restrict__ ybuf)
{
    const int bid = blockIdx.x;
    const int e = bid & (NE - 1), tr = bid >> 3;
    const int n_e = cnt[e], rbase = tr * FB_BM;
    if (rbase >= n_e) return;
    const int t = threadIdx.x;
    __shared__ __align__(16) float Xc[FB_BM][FB_XSTR];
    __shared__ __align__(16) float Hsh[FB_BM][FB_HSTR];
    __shared__ int rowa[FB_BM];
    if (t < FB_BM) { int r = rbase + t; rowa[t] = (r < n_e) ? bucket[e * NA + r] : -1; }
    __syncthreads();
    const int cg = t & 15, rg = t >> 4, r0 = rg * 2;
    float yac[2][32];
    #pragma unroll
    for (int u = 0; u < 2; ++u)
        #pragma unroll
        for (int v = 0; v < 32; ++v) yac[u][v] = 0.0f;
    const float* w1e = w1 + (size_t)e * HS * FFN;
    const float* w2e = w2 + (size_t)e * FFN * HS;
    for (int jp = 0; jp < FFN; jp += FB_BJ) {
        float hac[2][8];
        #pragma unroll
        for (int u = 0; u < 2; ++u)
            #pragma unroll
            for (int v = 0; v < 8; ++v) hac[u][v] = 0.0f;
        for (int ic = 0; ic < HS; ic += FB_CK) {
            __syncthreads();
            #pragma unroll
            for (int q = 0; q < (FB_BM * FB_CK / 4) / 256; ++q) {
                int id = t + 256 * q, rr = id >> 6, c4 = id & 63;
                int a = rowa[rr];
                float4 val = make_float4(0.f, 0.f, 0.f, 0.f);
                if (a >= 0) val = *reinterpret_cast<const float4*>(x + (size_t)(a >> 1) * HS + ic + c4 * 4);
                *reinterpret_cast<float4*>(&Xc[rr][c4 * 4]) = val;
            }
            __syncthreads();
            const float* w1p = w1e + (size_t)ic * FFN + jp + cg * 8;
            #pragma unroll 2
            for (int i4 = 0; i4 < FB_CK; i4 += 4) {
                float4 xa = *reinterpret_cast<const float4*>(&Xc[r0][i4]);
                float4 xb = *reinterpret_cast<const float4*>(&Xc[r0 + 1][i4]);
                const float* wr0 = w1p + (size_t)i4 * FFN;
                #pragma unroll
                for (int ii = 0; ii < 4; ++ii) {
                    float4 wa = *reinterpret_cast<const float4*>(wr0 + (size_t)ii * FFN);
                    float4 wb = *reinterpret_cast<const float4*>(wr0 + (size_t)ii * FFN + 4);
                    float x0 = (ii == 0) ? xa.x : (ii == 1) ? xa.y : (ii == 2) ? xa.z : xa.w;
                    float x1 = (ii == 0) ? xb.x : (ii == 1) ? xb.y : (ii == 2) ? xb.z : xb.w;
                    hac[0][0] = fmaf(x0, wa.x, hac[0][0]); hac[0][1] = fmaf(x0, wa.y, hac[0][1]);
                    hac[0][2] = fmaf(x0, wa.z, hac[0][2]); hac[0][3] = fmaf(x0, wa.w, hac[0][3]);
                    hac[0][4] = fmaf(x0, wb.x, hac[0][4]); hac[0][5] = fmaf(x0, wb.y, hac[0][5]);
                    hac[0][6] = fmaf(x0, wb.z, hac[0][6]); hac[0][7] = fmaf(x0, wb.w, hac[0][7]);
                    hac[1][0] = fmaf(x1, wa.x, hac[1][0]); hac[1][1] = fmaf(x1, wa.y, hac[1][1]);
                    hac[1][2] = fmaf(x1, wa.z, hac[1][2]); hac[1][3] = fmaf(x1, wa.w, hac[1][3]);
                    hac[1][4] = fmaf(x1, wb.x, hac[1][4]); hac[1][5] = fmaf(x1, wb.y, hac[1][5]);
                    hac[1][6] = fmaf(x1, wb.z, hac[1][6]); hac[1][7] = fmaf(x1, wb.w, hac[1][7]);
                }
            }
        }
        #pragma unroll
        for (int u = 0; u < 2; ++u)
            #pragma unroll
            for (int v = 0; v < 8; ++v) Hsh[r0 + u][cg * 8 + v] = fb_gelu(hac[u][v]);
        __syncthreads();
        const float* w2p = w2e + (size_t)jp * HS + cg * 32;
        #pragma unroll 2
        for (int j = 0; j < FB_BJ; ++j) {
            float h0 = Hsh[r0][j], h1 = Hsh[r0 + 1][j];
            const float* wr = w2p + (size_t)j * HS;
            #pragma unroll
            for (int q = 0; q < 8; ++q) {
                float4 w4 = *reinterpret_cast<const float4*>(wr + q * 4);
                yac[0][q * 4 + 0] = fmaf(h0, w4.x, yac[0][q * 4 + 0]);
                yac[0][q * 4 + 1] = fmaf(h0, w4.y, yac[0][q * 4 + 1]);
                yac[0][q * 4 + 2] = fmaf(h0, w4.z, yac[0][q * 4 + 2]);
                yac[0][q * 4 + 3] = fmaf(h0, w4.w, yac[0][q * 4 + 3]);
                yac[1][q * 4 + 0] = fmaf(h1, w4.x, yac[1][q * 4 + 0]);
                yac[1][q * 4 + 1] = fmaf(h1, w4.y, yac[1][q * 4 + 1]);
                yac[1][q * 4 + 2] = fmaf(h1, w4.z, yac[1][q * 4 + 2]);
                yac[1][q * 4 + 3] = fmaf(h1, w4.w, yac[1][q * 4 + 3]);
            }
        }
    }
    #pragma unroll
    for (int u = 0; u < 2; ++u) {
        int a = rowa[r0 + u];
        if (a >= 0) {
            float* yp = ybuf + (size_t)a * HS + cg * 32;
            #pragma unroll
            for (int q = 0; q < 8; ++q) {
                float4 o = make_float4(yac[u][q * 4 + 0], yac[u][q * 4 + 1],
                                       yac[u][q * 4 + 2], yac[u][q * 4 + 3]);
                *reinterpret_cast<float4*>(yp + q * 4) = o;
            }
        }
    }
}

__global__ void fb_combine(const float* __restrict__ ybuf, const float* __restrict__ ew,
                           float* __restrict__ out) {
    int i = blockIdx.x * 256 + threadIdx.x;
    if (i >= T_TOK * HS / 4) return;
    int tk = i >> 7, c4 = i & 127;
    float wA = ew[2 * tk], wB = ew[2 * tk + 1];
    const float4* y4 = reinterpret_cast<const float4*>(ybuf);
    float4 a = y4[(size_t)(2 * tk) * (HS / 4) + c4];
    float4 b = y4[(size_t)(2 * tk + 1) * (HS / 4) + c4];
    float4 o;
    o.x = wA * a.x + wB * b.x; o.y = wA * a.y + wB * b.y;
    o.z = wA * a.z + wB * b.z; o.w = wA * a.w + wB * b.w;
    reinterpret_cast<float4*>(out)[i] = o;
}

// ================= launch =================
extern "C" void kernel_launch(void* const* d_in, const int* in_sizes, int n_in,
                              void* d_out, int out_size, void* d_ws, size_t ws_size,
                              hipStream_t stream) {
    const float* x  = (const float*)d_in[0];
    const float* ew = (const float*)d_in[1];
    const int*   ei = (const int*)d_in[2];
    const float* w1 = (const float*)d_in[3];
    const float* w2 = (const float*)d_in[4];
    float* out = (float*)d_out;
    char* W = (char*)d_ws;

    if (ws_size < WS_NEED) {
        int* cnt = (int*)d_ws;
        int* bucket = cnt + 64;
        float* ybuf = (float*)(W + (1 << 19));
        fb_init<<<1, 64, 0, stream>>>(cnt);
        fb_scatter<<<NA / 256, 256, 0, stream>>>(ei, cnt, bucket);
        fb_fused<<<NE * (NA / FB_BM), 256, 0, stream>>>(x, w1, w2, cnt, bucket, ybuf);
        fb_combine<<<(T_TOK * HS / 4 + 255) / 256, 256, 0, stream>>>(ybuf, ew, out);
        return;
    }

    int* offp  = (int*)(W + WS_OFF);
    int* mexp  = (int*)(W + WS_MEXP);
    int* slots = (int*)(W + WS_SLOTS);
    int* inv   = (int*)(W + WS_INV);
    unsigned short* XB   = (unsigned short*)(W + WS_XB);
    unsigned short* W1T  = (unsigned short*)(W + WS_W1T);
    unsigned short* W2T  = (unsigned short*)(W + WS_W2T);
    unsigned short* HB   = (unsigned short*)(W + WS_HB);
    unsigned short* YPB0 = (unsigned short*)(W + WS_YPB0);
    unsigned short* YPB1 = (unsigned short*)(W + WS_YPB1);

    moe_prep1<<<4129, 256, 0, stream>>>(ei, slots, inv, offp, mexp, x, XB, w1, W1T);
    moe_g1w2<<<NB_G1 + 2048, 256, 0, stream>>>(XB, W1T, offp, mexp, slots, HB, w2, W2T);
    moe_gemm2<<<8 * 9 * 8, 256, 0, stream>>>(HB, W2T, offp, mexp, YPB0, YPB1);
    moe_combine2<<<(T_TOK * HS / 8) / 256, 256, 0, stream>>>(YPB0, YPB1, inv, ew, out);
}